// Round 8
// baseline (242.151 us; speedup 1.0000x reference)
//
#include <hip/hip_runtime.h>
#include <hip/hip_bf16.h>
#include <math.h>

// Model constants (fixed by the reference)
#define NN   4096   // nodes
#define INC  256
#define HIDF 128
#define H1H  4
#define DM   128    // transformer d_model
#define THD  4      // transformer heads (head dim 32)
#define FFD  512

typedef __attribute__((ext_vector_type(8))) short bf16x8;
typedef __attribute__((ext_vector_type(4))) float f32x4;

__device__ __forceinline__ float leaky(float x){ return x > 0.f ? x : 0.2f*x; }

// fp32 -> bf16 bits via HW convert (RNE)
__device__ __forceinline__ ushort f2b(float f){
  __hip_bfloat16 h = __float2bfloat16(f);
  return __builtin_bit_cast(ushort, h);
}
__device__ __forceinline__ unsigned pk2(float a, float b){
  return (unsigned)f2b(a) | ((unsigned)f2b(b) << 16);
}
// bf16 bits -> fp32
__device__ __forceinline__ float b2f(unsigned u){ return __uint_as_float(u << 16); }
__device__ __forceinline__ float b2flo(unsigned u){ return __uint_as_float(u << 16); }
__device__ __forceinline__ float b2fhi(unsigned u){ return __uint_as_float(u & 0xffff0000u); }

// kv bit-permutation within 32-blocks: {b4,b3,b2,b1,b0} -> {b3,b2,b4,b1,b0}
__device__ __forceinline__ int kvperm(int kv){
  return (kv & ~31) | ((kv & 12) << 1) | ((kv >> 2) & 4) | (kv & 3);
}

// ---------------------------------------------------------------------------
// bf16 MFMA GEMM: C[M,N] = A[M,K] @ Wb[N,ldw](bf16)^T (+bias)(+relu)
// 64x64 tile, BK=64, 256 threads = 4 waves (2x2 of 32x32).
// ---------------------------------------------------------------------------
template<bool BIAS, bool RELU, bool OUTBF, bool ABF>
__global__ __launch_bounds__(256) void gemm_mf(
    const void* __restrict__ Av, const ushort* __restrict__ Wb,
    const float* __restrict__ bias, void* __restrict__ Cv,
    int M, int N, int K, int ldw)
{
  __shared__ uint4 As4[512];   // [ko 0..7][m 0..63] : 8 bf16 each
  __shared__ uint4 Bs4[512];
  int tid = threadIdx.x;
  int row0 = blockIdx.y * 64, col0 = blockIdx.x * 64;
  int wid = tid >> 6, lane = tid & 63;
  int wm = wid >> 1, wn = wid & 1;
  int ql = lane & 15, g = lane >> 4;
  const f32x4 z4 = {0.f,0.f,0.f,0.f};
  f32x4 acc[2][2] = {z4,z4,z4,z4};

  for (int k0 = 0; k0 < K; k0 += 64) {
    #pragma unroll
    for (int p = 0; p < 2; p++) {
      int idx = tid + p*256;         // 0..511
      int ko = idx & 7, mm = idx >> 3;
      if constexpr (ABF) {
        As4[ko*64 + mm] = *(const uint4*)((const ushort*)Av + (size_t)(row0 + mm)*K + k0 + ko*8);
      } else {
        const float* sa = (const float*)Av + (size_t)(row0 + mm)*K + k0 + ko*8;
        float4 a0 = *(const float4*)sa;
        float4 a1 = *(const float4*)(sa + 4);
        uint4 av;
        av.x = pk2(a0.x, a0.y); av.y = pk2(a0.z, a0.w);
        av.z = pk2(a1.x, a1.y); av.w = pk2(a1.z, a1.w);
        As4[ko*64 + mm] = av;
      }
      Bs4[ko*64 + mm] = *(const uint4*)(Wb + (size_t)(col0 + mm)*ldw + k0 + ko*8);
    }
    __syncthreads();
    #pragma unroll
    for (int kk = 0; kk < 2; kk++) {
      int ko = kk*4 + g;
      bf16x8 a0 = *((const bf16x8*)As4 + ko*64 + wm*32 + ql);
      bf16x8 a1 = *((const bf16x8*)As4 + ko*64 + wm*32 + 16 + ql);
      bf16x8 b0 = *((const bf16x8*)Bs4 + ko*64 + wn*32 + ql);
      bf16x8 b1 = *((const bf16x8*)Bs4 + ko*64 + wn*32 + 16 + ql);
      acc[0][0] = __builtin_amdgcn_mfma_f32_16x16x32_bf16(a0, b0, acc[0][0], 0,0,0);
      acc[0][1] = __builtin_amdgcn_mfma_f32_16x16x32_bf16(a0, b1, acc[0][1], 0,0,0);
      acc[1][0] = __builtin_amdgcn_mfma_f32_16x16x32_bf16(a1, b0, acc[1][0], 0,0,0);
      acc[1][1] = __builtin_amdgcn_mfma_f32_16x16x32_bf16(a1, b1, acc[1][1], 0,0,0);
    }
    __syncthreads();
  }
  float bvs[2] = {0.f, 0.f};
  if (BIAS) {
    bvs[0] = bias[col0 + wn*32 + ql];
    bvs[1] = bias[col0 + wn*32 + 16 + ql];
  }
  #pragma unroll
  for (int fm = 0; fm < 2; fm++)
    #pragma unroll
    for (int fn = 0; fn < 2; fn++) {
      int row = row0 + wm*32 + fm*16 + g*4;
      int col = col0 + wn*32 + fn*16 + ql;
      #pragma unroll
      for (int r = 0; r < 4; r++) {
        float v = acc[fm][fn][r];
        if (BIAS) v += bvs[fn];
        if (RELU) v = fmaxf(v, 0.f);
        if (OUTBF) ((ushort*)Cv)[(size_t)(row + r)*N + col] = f2b(v);
        else       ((float*)Cv)[(size_t)(row + r)*N + col] = v;
      }
    }
}

// ---------------------------------------------------------------------------
// qkv GEMM with fused Q-scale + K/V tile scatter.
// ---------------------------------------------------------------------------
__global__ __launch_bounds__(256) void gemm_qkv(
    const ushort* __restrict__ Ab, const ushort* __restrict__ Wb,
    const float* __restrict__ bias,
    ushort* __restrict__ qb, ushort* __restrict__ kt, ushort* __restrict__ vt)
{
  __shared__ uint4 As4[512];
  __shared__ uint4 Bs4[512];
  int tid = threadIdx.x;
  int row0 = blockIdx.y * 64, col0 = blockIdx.x * 64;
  int wid = tid >> 6, lane = tid & 63;
  int wm = wid >> 1, wn = wid & 1;
  int ql = lane & 15, g = lane >> 4;
  const f32x4 z4 = {0.f,0.f,0.f,0.f};
  f32x4 acc[2][2] = {z4,z4,z4,z4};

  for (int k0 = 0; k0 < 128; k0 += 64) {
    #pragma unroll
    for (int p = 0; p < 2; p++) {
      int idx = tid + p*256;
      int ko = idx & 7, mm = idx >> 3;
      As4[ko*64 + mm] = *(const uint4*)(Ab + (size_t)(row0 + mm)*128 + k0 + ko*8);
      Bs4[ko*64 + mm] = *(const uint4*)(Wb + (size_t)(col0 + mm)*128 + k0 + ko*8);
    }
    __syncthreads();
    #pragma unroll
    for (int kk = 0; kk < 2; kk++) {
      int ko = kk*4 + g;
      bf16x8 a0 = *((const bf16x8*)As4 + ko*64 + wm*32 + ql);
      bf16x8 a1 = *((const bf16x8*)As4 + ko*64 + wm*32 + 16 + ql);
      bf16x8 b0 = *((const bf16x8*)Bs4 + ko*64 + wn*32 + ql);
      bf16x8 b1 = *((const bf16x8*)Bs4 + ko*64 + wn*32 + 16 + ql);
      acc[0][0] = __builtin_amdgcn_mfma_f32_16x16x32_bf16(a0, b0, acc[0][0], 0,0,0);
      acc[0][1] = __builtin_amdgcn_mfma_f32_16x16x32_bf16(a0, b1, acc[0][1], 0,0,0);
      acc[1][0] = __builtin_amdgcn_mfma_f32_16x16x32_bf16(a1, b0, acc[1][0], 0,0,0);
      acc[1][1] = __builtin_amdgcn_mfma_f32_16x16x32_bf16(a1, b1, acc[1][1], 0,0,0);
    }
    __syncthreads();
  }
  float bvs[2];
  bvs[0] = bias[col0 + wn*32 + ql];
  bvs[1] = bias[col0 + wn*32 + 16 + ql];
  #pragma unroll
  for (int fm = 0; fm < 2; fm++)
    #pragma unroll
    for (int fn = 0; fn < 2; fn++) {
      int row = row0 + wm*32 + fm*16 + g*4;
      int col = col0 + wn*32 + fn*16 + ql;
      #pragma unroll
      for (int r = 0; r < 4; r++) {
        float v = acc[fm][fn][r] + bvs[fn];
        int kv = row + r;
        if (col < 128) {
          qb[(size_t)kv*128 + col] = f2b(v * 0.25505654708f);  // 1/sqrt(32)*log2e
        } else if (col < 256) {
          int hh = (col - 128) >> 5, d = (col - 128) & 31;
          kt[(size_t)hh*131072 + (size_t)kv*32 + d] = f2b(v);
        } else {
          int hh = (col - 256) >> 5, d = (col - 256) & 31;
          vt[(size_t)hh*131072 + (size_t)(kv >> 5)*1024 + (d >> 4)*512
             + (d & 15)*32 + kvperm(kv & 31)] = f2b(v);
        }
      }
    }
}

// ---------------------------------------------------------------------------
// Fused bf16 GEMM (N=128) + residual + LayerNorm, in-place on bf16 h.
// BM=16 rows/block -> grid 256 (full machine). 4 waves, wave w = cols w*32..+31.
// ---------------------------------------------------------------------------
__global__ __launch_bounds__(256) void gemm_ln(
    const ushort* __restrict__ Ab, const ushort* __restrict__ Wb,
    const float* __restrict__ bias, ushort* __restrict__ h,
    const float* __restrict__ lng, const float* __restrict__ lnb, int K)
{
  __shared__ uint4 As4[128];    // [ko 0..7][m 0..15]
  __shared__ uint4 Bs4[1024];   // [ko 0..7][n 0..127]
  __shared__ float xs[16][132];
  int tid = threadIdx.x;
  int row0 = blockIdx.x * 16;
  int wv = tid >> 6, lane = tid & 63;
  int ql = lane & 15, g = lane >> 4;
  const f32x4 z4 = {0.f,0.f,0.f,0.f};
  f32x4 acc[2] = {z4, z4};

  for (int k0 = 0; k0 < K; k0 += 64) {
    if (tid < 128) {
      int ko = tid & 7, mm = tid >> 3;
      As4[ko*16 + mm] = *(const uint4*)(Ab + (size_t)(row0 + mm)*K + k0 + ko*8);
    }
    #pragma unroll
    for (int p = 0; p < 4; p++) {
      int idx = tid + p*256;     // 0..1023
      int ko = idx & 7, nn = idx >> 3;
      Bs4[ko*128 + nn] = *(const uint4*)(Wb + (size_t)nn*K + k0 + ko*8);
    }
    __syncthreads();
    #pragma unroll
    for (int kk = 0; kk < 2; kk++) {
      int ko = kk*4 + g;
      bf16x8 a = *((const bf16x8*)As4 + ko*16 + ql);
      #pragma unroll
      for (int fn = 0; fn < 2; fn++) {
        bf16x8 b = *((const bf16x8*)Bs4 + ko*128 + wv*32 + fn*16 + ql);
        acc[fn] = __builtin_amdgcn_mfma_f32_16x16x32_bf16(a, b, acc[fn], 0,0,0);
      }
    }
    __syncthreads();
  }
  // stage gemm+bias into LDS
  #pragma unroll
  for (int fn = 0; fn < 2; fn++) {
    int col = wv*32 + fn*16 + ql;
    float bv = bias[col];
    #pragma unroll
    for (int r = 0; r < 4; r++) xs[g*4 + r][col] = acc[fn][r] + bv;
  }
  __syncthreads();
  // residual + LN: 16 lanes per row, 8 cols each
  int rl = tid >> 4, cl = tid & 15, c0 = cl * 8;
  ushort* hrow = h + (size_t)(row0 + rl)*128;
  uint4 rv = *(const uint4*)(hrow + c0);
  float x[8];
  x[0] = xs[rl][c0+0] + b2flo(rv.x); x[1] = xs[rl][c0+1] + b2fhi(rv.x);
  x[2] = xs[rl][c0+2] + b2flo(rv.y); x[3] = xs[rl][c0+3] + b2fhi(rv.y);
  x[4] = xs[rl][c0+4] + b2flo(rv.z); x[5] = xs[rl][c0+5] + b2fhi(rv.z);
  x[6] = xs[rl][c0+6] + b2flo(rv.w); x[7] = xs[rl][c0+7] + b2fhi(rv.w);
  float s1 = 0.f, s2 = 0.f;
  #pragma unroll
  for (int i = 0; i < 8; i++) { s1 += x[i]; s2 += x[i]*x[i]; }
  #pragma unroll
  for (int st = 1; st < 16; st <<= 1) {
    s1 += __shfl_xor(s1, st); s2 += __shfl_xor(s2, st);
  }
  float mean = s1 * (1.f/128.f);
  float var  = s2 * (1.f/128.f) - mean*mean;
  float rstd = rsqrtf(var + 1e-5f);
  float o[8];
  #pragma unroll
  for (int i = 0; i < 8; i += 4) {
    float4 g4 = *(const float4*)(lng + c0 + i);
    float4 b4 = *(const float4*)(lnb + c0 + i);
    o[i+0] = (x[i+0]-mean)*rstd*g4.x + b4.x;
    o[i+1] = (x[i+1]-mean)*rstd*g4.y + b4.y;
    o[i+2] = (x[i+2]-mean)*rstd*g4.z + b4.z;
    o[i+3] = (x[i+3]-mean)*rstd*g4.w + b4.w;
  }
  uint4 ov; ov.x = pk2(o[0],o[1]); ov.y = pk2(o[2],o[3]);
  ov.z = pk2(o[4],o[5]); ov.w = pk2(o[6],o[7]);
  *(uint4*)(hrow + c0) = ov;
}

// ---------------------------------------------------------------------------
// one-shot weight fp32->bf16 conversion; fc1 re-packed to [256][128].
// ---------------------------------------------------------------------------
__global__ __launch_bounds__(256) void cvt_weights(
    const float* __restrict__ W1, const float* __restrict__ W2,
    const float* __restrict__ qkv, const float* __restrict__ o,
    const float* __restrict__ ff1, const float* __restrict__ ff2,
    const float* __restrict__ fc1, const float* __restrict__ fc1b,
    ushort* __restrict__ out, float* __restrict__ bias256)
{
  if (blockIdx.x == 608) {
    int t = threadIdx.x;
    bias256[t] = (t < 128) ? fc1b[t] : 0.f;
    return;
  }
  int i4 = (blockIdx.x*256 + threadIdx.x) * 4;
  const float* s; int loc;
  size_t dst = i4;
  if      (i4 < 131072) { s = W1;  loc = i4; }
  else if (i4 < 196608) { s = W2;  loc = i4 - 131072; }
  else if (i4 < 294912) { s = qkv; loc = i4 - 196608; }
  else if (i4 < 327680) { s = o;   loc = i4 - 294912; }
  else if (i4 < 458752) { s = ff1; loc = i4 - 327680; }
  else if (i4 < 589824) { s = ff2; loc = i4 - 458752; }
  else {
    s = fc1; loc = i4 - 589824;
    int j = loc >> 8, k2 = loc & 255;
    dst = 589824 + ((k2 >= 128) ? 16384 : 0) + j*128 + (k2 & 127);
  }
  float4 v = *(const float4*)(s + loc);
  uint2 w; w.x = pk2(v.x, v.y); w.y = pk2(v.z, v.w);
  *(uint2*)(out + dst) = w;
}

// ---------------------------------------------------------------------------
// Fused CSR count+scan: one block, LDS-atomic degree count + in-LDS scan.
// ---------------------------------------------------------------------------
__global__ __launch_bounds__(1024) void csr_build(
    const int* __restrict__ dst, int* __restrict__ rowstart,
    int* __restrict__ cursor, int E)
{
  __shared__ int sdeg[4096];
  __shared__ int ssum[1024];
  int t = threadIdx.x;
  #pragma unroll
  for (int i = 0; i < 4; i++) sdeg[t + i*1024] = 0;
  __syncthreads();
  for (int e = t; e < E; e += 1024) atomicAdd(&sdeg[dst[e]], 1);
  __syncthreads();
  int base = t * 4;
  int v0 = sdeg[base], v1 = sdeg[base+1], v2 = sdeg[base+2], v3 = sdeg[base+3];
  int tot = v0 + v1 + v2 + v3;
  ssum[t] = tot;
  __syncthreads();
  for (int off = 1; off < 1024; off <<= 1) {
    int x = (t >= off) ? ssum[t - off] : 0;
    __syncthreads();
    ssum[t] += x;
    __syncthreads();
  }
  int run = ssum[t] - tot;  // exclusive
  rowstart[base]   = run; cursor[base]   = run; run += v0;
  rowstart[base+1] = run; cursor[base+1] = run; run += v1;
  rowstart[base+2] = run; cursor[base+2] = run; run += v2;
  rowstart[base+3] = run; cursor[base+3] = run; run += v3;
  if (t == 1023) rowstart[4096] = run;
}
__global__ void fill_kernel(const int* __restrict__ src, const int* __restrict__ dst,
                            int* __restrict__ cursor, int* __restrict__ nbr, int E) {
  int e = blockIdx.x * blockDim.x + threadIdx.x;
  if (e < E) {
    int p = atomicAdd(&cursor[dst[e]], 1);
    nbr[p] = src[e];
  }
}

// ---------------------------------------------------------------------------
// el/er attention coefficients (bf16 h input); one wave per node.
// ---------------------------------------------------------------------------
template<int H>
__global__ __launch_bounds__(256) void elr_kernel(
    const ushort* __restrict__ hmat, const float* __restrict__ al,
    const float* __restrict__ ar, float* __restrict__ el, float* __restrict__ er)
{
  int w = threadIdx.x >> 6, lane = threadIdx.x & 63;
  int n = blockIdx.x * 4 + w;
  if constexpr (H == 4) {
    int hh = lane >> 4, f0 = (lane & 15) * 8;
    bf16x8 hv = *(const bf16x8*)(hmat + (size_t)n*512 + hh*128 + f0);
    float4 a0 = *(const float4*)(al + hh*128 + f0);
    float4 a1 = *(const float4*)(al + hh*128 + f0 + 4);
    float4 r0 = *(const float4*)(ar + hh*128 + f0);
    float4 r1 = *(const float4*)(ar + hh*128 + f0 + 4);
    float x[8];
    #pragma unroll
    for (int i = 0; i < 8; i++) x[i] = b2f((ushort)hv[i]);
    float e1 = x[0]*a0.x + x[1]*a0.y + x[2]*a0.z + x[3]*a0.w
             + x[4]*a1.x + x[5]*a1.y + x[6]*a1.z + x[7]*a1.w;
    float e2 = x[0]*r0.x + x[1]*r0.y + x[2]*r0.z + x[3]*r0.w
             + x[4]*r1.x + x[5]*r1.y + x[6]*r1.z + x[7]*r1.w;
    #pragma unroll
    for (int s = 1; s < 16; s <<= 1) { e1 += __shfl_xor(e1, s); e2 += __shfl_xor(e2, s); }
    if ((lane & 15) == 0) { el[n*4 + hh] = e1; er[n*4 + hh] = e2; }
  } else {
    int f0 = lane * 2;
    unsigned u = *(const unsigned*)(hmat + (size_t)n*128 + f0);
    float x0 = b2flo(u), x1 = b2fhi(u);
    float2 av = *(const float2*)(al + f0);
    float2 rv = *(const float2*)(ar + f0);
    float e1 = x0*av.x + x1*av.y;
    float e2 = x0*rv.x + x1*rv.y;
    #pragma unroll
    for (int s = 1; s < 64; s <<= 1) { e1 += __shfl_xor(e1, s); e2 += __shfl_xor(e2, s); }
    if (lane == 0) { el[n] = e1; er[n] = e2; }
  }
}

// ---------------------------------------------------------------------------
// GAT aggregation H=4: ONE WAVE PER NODE (4 waves/block, no barriers).
// Softmax phases: lane=edge + shuffle reduce. Gather: lane = 8 feats (uint4).
// ---------------------------------------------------------------------------
__global__ __launch_bounds__(256) void gat_agg4(
    const ushort* __restrict__ hsrc, const float* __restrict__ el, const float* __restrict__ er,
    const int* __restrict__ rowstart, const int* __restrict__ nbr,
    const float* __restrict__ bias, ushort* __restrict__ out)
{
  __shared__ float s_alpha[4][256][4];
  __shared__ int   s_nbr[4][256];
  int wv = threadIdx.x >> 6, lane = threadIdx.x & 63;
  int n = blockIdx.x * 4 + wv;
  int e0 = rowstart[n];
  int deg = rowstart[n+1] - e0;
  float4 ern = *(const float4*)(er + (size_t)n*4);
  int hh = lane >> 4;   // head for gather (8 feats: lane*8 covers head lane/16)
  float acc[8] = {};
  if (deg > 0) {
    // pass 1: max (lane = edge)
    float m0=-1e30f, m1=-1e30f, m2=-1e30f, m3=-1e30f;
    for (int i = lane; i < deg; i += 64) {
      int s = nbr[e0 + i];
      float4 ev = *(const float4*)(el + (size_t)s*4);
      m0 = fmaxf(m0, leaky(ev.x + ern.x));
      m1 = fmaxf(m1, leaky(ev.y + ern.y));
      m2 = fmaxf(m2, leaky(ev.z + ern.z));
      m3 = fmaxf(m3, leaky(ev.w + ern.w));
    }
    #pragma unroll
    for (int st = 1; st < 64; st <<= 1) {
      m0 = fmaxf(m0, __shfl_xor(m0, st)); m1 = fmaxf(m1, __shfl_xor(m1, st));
      m2 = fmaxf(m2, __shfl_xor(m2, st)); m3 = fmaxf(m3, __shfl_xor(m3, st));
    }
    // pass 2: sumexp
    float se0=0.f, se1=0.f, se2=0.f, se3=0.f;
    for (int i = lane; i < deg; i += 64) {
      int s = nbr[e0 + i];
      float4 ev = *(const float4*)(el + (size_t)s*4);
      se0 += __expf(leaky(ev.x + ern.x) - m0);
      se1 += __expf(leaky(ev.y + ern.y) - m1);
      se2 += __expf(leaky(ev.z + ern.z) - m2);
      se3 += __expf(leaky(ev.w + ern.w) - m3);
    }
    #pragma unroll
    for (int st = 1; st < 64; st <<= 1) {
      se0 += __shfl_xor(se0, st); se1 += __shfl_xor(se1, st);
      se2 += __shfl_xor(se2, st); se3 += __shfl_xor(se3, st);
    }
    float si0 = 1.f/se0, si1 = 1.f/se1, si2 = 1.f/se2, si3 = 1.f/se3;
    // pass 3: gather in chunks of 256 edges
    for (int c = 0; c < deg; c += 256) {
      int cn = min(256, deg - c);
      for (int i = lane; i < cn; i += 64) {
        int s = nbr[e0 + c + i];
        s_nbr[wv][i] = s;
        float4 ev = *(const float4*)(el + (size_t)s*4);
        s_alpha[wv][i][0] = __expf(leaky(ev.x + ern.x) - m0) * si0;
        s_alpha[wv][i][1] = __expf(leaky(ev.y + ern.y) - m1) * si1;
        s_alpha[wv][i][2] = __expf(leaky(ev.z + ern.z) - m2) * si2;
        s_alpha[wv][i][3] = __expf(leaky(ev.w + ern.w) - m3) * si3;
      }
      // same wave wrote: LDS dependence handled by compiler waitcnt
      #pragma unroll 4
      for (int i = 0; i < cn; i++) {
        float a = s_alpha[wv][i][hh];
        int s = s_nbr[wv][i];
        uint4 hv = *(const uint4*)(hsrc + (size_t)s*512 + lane*8);
        acc[0] += a * b2flo(hv.x); acc[1] += a * b2fhi(hv.x);
        acc[2] += a * b2flo(hv.y); acc[3] += a * b2fhi(hv.y);
        acc[4] += a * b2flo(hv.z); acc[5] += a * b2fhi(hv.z);
        acc[6] += a * b2flo(hv.w); acc[7] += a * b2fhi(hv.w);
      }
    }
  }
  const float* bp = bias + lane*8;
  float4 b0 = *(const float4*)(bp);
  float4 b1 = *(const float4*)(bp + 4);
  float v0 = fmaxf(acc[0]+b0.x, 0.f), v1 = fmaxf(acc[1]+b0.y, 0.f);
  float v2 = fmaxf(acc[2]+b0.z, 0.f), v3 = fmaxf(acc[3]+b0.w, 0.f);
  float v4 = fmaxf(acc[4]+b1.x, 0.f), v5 = fmaxf(acc[5]+b1.y, 0.f);
  float v6 = fmaxf(acc[6]+b1.z, 0.f), v7 = fmaxf(acc[7]+b1.w, 0.f);
  uint4 ov; ov.x = pk2(v0,v1); ov.y = pk2(v2,v3); ov.z = pk2(v4,v5); ov.w = pk2(v6,v7);
  *(uint4*)(out + (size_t)n*512 + lane*8) = ov;
}

// ---------------------------------------------------------------------------
// GAT aggregation H=1: one wave per node; lane = 2 feats (dword gather).
// ---------------------------------------------------------------------------
__global__ __launch_bounds__(256) void gat_agg1(
    const ushort* __restrict__ hsrc, const float* __restrict__ el, const float* __restrict__ er,
    const int* __restrict__ rowstart, const int* __restrict__ nbr,
    const float* __restrict__ bias, ushort* __restrict__ out)
{
  __shared__ float s_alpha[4][256];
  __shared__ int   s_nbr[4][256];
  int wv = threadIdx.x >> 6, lane = threadIdx.x & 63;
  int n = blockIdx.x * 4 + wv;
  int e0 = rowstart[n];
  int deg = rowstart[n+1] - e0;
  float ern = er[n];
  float a0 = 0.f, a1 = 0.f;
  if (deg > 0) {
    float mx = -1e30f;
    for (int i = lane; i < deg; i += 64)
      mx = fmaxf(mx, leaky(el[nbr[e0 + i]] + ern));
    #pragma unroll
    for (int st = 1; st < 64; st <<= 1) mx = fmaxf(mx, __shfl_xor(mx, st));
    float se = 0.f;
    for (int i = lane; i < deg; i += 64)
      se += __expf(leaky(el[nbr[e0 + i]] + ern) - mx);
    #pragma unroll
    for (int st = 1; st < 64; st <<= 1) se += __shfl_xor(se, st);
    float si = 1.f / se;
    for (int c = 0; c < deg; c += 256) {
      int cn = min(256, deg - c);
      for (int i = lane; i < cn; i += 64) {
        int s = nbr[e0 + c + i];
        s_nbr[wv][i] = s;
        s_alpha[wv][i] = __expf(leaky(el[s] + ern) - mx) * si;
      }
      #pragma unroll 4
      for (int i = 0; i < cn; i++) {
        float a = s_alpha[wv][i];
        int s = s_nbr[wv][i];
        unsigned u = *(const unsigned*)(hsrc + (size_t)s*128 + lane*2);
        a0 += a * b2flo(u);
        a1 += a * b2fhi(u);
      }
    }
  }
  float v0 = a0 + bias[lane*2], v1 = a1 + bias[lane*2 + 1];
  *(unsigned*)(out + (size_t)n*128 + lane*2) = pk2(v0, v1);
}

// ---------------------------------------------------------------------------
// MFMA flash attention (unchanged from round 7)
// ---------------------------------------------------------------------------
#define LOADFRAGS(KF, VF, KV)                                              \
  {                                                                        \
    int _kv = (KV);                                                        \
    if (_kv < 1024) {                                                      \
      const ushort* _kp = kptr + (size_t)_kv * 32;                         \
      const ushort* _vp = vptr + (size_t)_kv * 32;                         \
      KF[0] = *(const bf16x8*)(_kp);                                       \
      KF[1] = *(const bf16x8*)(_kp + 512);                                 \
      KF[2] = *(const bf16x8*)(_kp + 1024);                                \
      KF[3] = *(const bf16x8*)(_kp + 1536);                                \
      VF[0] = *(const bf16x8*)(_vp);                                       \
      VF[1] = *(const bf16x8*)(_vp + 1024);                                \
      VF[2] = *(const bf16x8*)(_vp + 512);                                 \
      VF[3] = *(const bf16x8*)(_vp + 1536);                                \
    }                                                                      \
  }

#define QPASS(QF, LS, OA, OB, KF, VF)                                      \
  {                                                                        \
    f32x4 st0 = __builtin_amdgcn_mfma_f32_16x16x32_bf16(KF[0], QF, z4, 0, 0, 0); \
    f32x4 st1 = __builtin_amdgcn_mfma_f32_16x16x32_bf16(KF[1], QF, z4, 0, 0, 0); \
    f32x4 st2 = __builtin_amdgcn_mfma_f32_16x16x32_bf16(KF[2], QF, z4, 0, 0, 0); \
    f32x4 st3 = __builtin_amdgcn_mfma_f32_16x16x32_bf16(KF[3], QF, z4, 0, 0, 0); \
    float pvv[16];                                                         \
    _Pragma("unroll")                                                      \
    for (int i = 0; i < 4; i++) {                                          \
      pvv[i] = st0[i]; pvv[4+i] = st1[i]; pvv[8+i] = st2[i]; pvv[12+i] = st3[i]; \
    }                                                                      \
    _Pragma("unroll")                                                      \
    for (int i = 0; i < 16; i++) { pvv[i] = exp2f(pvv[i]); LS += pvv[i]; } \
    bf16x8 pf0 = { (short)f2b(pvv[0]),  (short)f2b(pvv[1]),  (short)f2b(pvv[2]),  (short)f2b(pvv[3]),   \
                   (short)f2b(pvv[4]),  (short)f2b(pvv[5]),  (short)f2b(pvv[6]),  (short)f2b(pvv[7]) }; \
    bf16x8 pf1 = { (short)f2b(pvv[8]),  (short)f2b(pvv[9]),  (short)f2b(pvv[10]), (short)f2b(pvv[11]),  \
                   (short)f2b(pvv[12]), (short)f2b(pvv[13]), (short)f2b(pvv[14]), (short)f2b(pvv[15]) };\
    OA = __builtin_amdgcn_mfma_f32_16x16x32_bf16(VF[0], pf0, OA, 0, 0, 0); \
    OA = __builtin_amdgcn_mfma_f32_16x16x32_bf16(VF[1], pf1, OA, 0, 0, 0); \
    OB = __builtin_amdgcn_mfma_f32_16x16x32_bf16(VF[2], pf0, OB, 0, 0, 0); \
    OB = __builtin_amdgcn_mfma_f32_16x16x32_bf16(VF[3], pf1, OB, 0, 0, 0); \
  }

#define ATTN_BODY(KF, VF, KN, VN, KV)                                      \
  {                                                                        \
    LOADFRAGS(KN, VN, (KV) + 64);                                          \
    QPASS(qf0, ls0, o00, o01, KF, VF);                                     \
    QPASS(qf1, ls1, o10, o11, KF, VF);                                     \
  }

__global__ __launch_bounds__(256) void attn_mfma(
    const ushort* __restrict__ qb,    // [4096][128] bf16, pre-scaled
    const ushort* __restrict__ kt,    // [4][256][16][32] bf16 tiles
    const ushort* __restrict__ vt,    // [4][128][2][16][32] bf16 tiles (kvperm'd)
    ushort* __restrict__ attnout)     // [4096][128] bf16
{
  int lane = threadIdx.x & 63;
  int w    = threadIdx.x >> 6;         // kv partition 0..3
  int head = blockIdx.x >> 7;
  int q0   = (blockIdx.x & 127) * 32;
  int ql = lane & 15;
  int g  = lane >> 4;
  const f32x4 z4 = {0.f, 0.f, 0.f, 0.f};
  int kvbase = w * 1024;

  bf16x8 qf0 = *(const bf16x8*)(qb + (size_t)(q0 + ql)*128      + head*32 + g*8);
  bf16x8 qf1 = *(const bf16x8*)(qb + (size_t)(q0 + 16 + ql)*128 + head*32 + g*8);
  const ushort* kptr = kt + (size_t)head*131072 + (size_t)kvbase*32 + ql*32 + g*8;
  const ushort* vptr = vt + (size_t)head*131072 + (size_t)kvbase*32 + ql*32 + g*8;

  float ls0 = 0.f, ls1 = 0.f;
  f32x4 o00 = z4, o01 = z4, o10 = z4, o11 = z4;

  bf16x8 kfA[4], vfA[4], kfB[4], vfB[4];
  LOADFRAGS(kfA, vfA, 0);
  for (int kv0 = 0; kv0 < 1024; kv0 += 128) {
    ATTN_BODY(kfA, vfA, kfB, vfB, kv0);
    ATTN_BODY(kfB, vfB, kfA, vfA, kv0 + 64);
  }

  ls0 += __shfl_xor(ls0, 16); ls0 += __shfl_xor(ls0, 32);
  ls1 += __shfl_xor(ls1, 16); ls1 += __shfl_xor(ls1, 32);

  __shared__ float so[4][32][36];
  __shared__ float sl[4][32];
  if (g == 0) { sl[w][ql] = ls0; sl[w][16 + ql] = ls1; }
  #pragma unroll
  for (int r = 0; r < 4; r++) {
    so[w][ql][g*4 + r]           = o00[r];
    so[w][ql][16 + g*4 + r]      = o01[r];
    so[w][16 + ql][g*4 + r]      = o10[r];
    so[w][16 + ql][16 + g*4 + r] = o11[r];
  }
  __syncthreads();
  int q  = threadIdx.x >> 3;         // 0..31
  int d0 = (threadIdx.x & 7) * 4;    // 0..28
  float L = 0.f, O0 = 0.f, O1 = 0.f, O2 = 0.f, O3 = 0.f;
  #pragma unroll
  for (int w2 = 0; w2 < 4; w2++) {
    L  += sl[w2][q];
    O0 += so[w2][q][d0];
    O1 += so[w2][q][d0+1];
    O2 += so[w2][q][d0+2];
    O3 += so[w2][q][d0+3];
  }
  float rl = 1.f / L;
  uint2 w2v; w2v.x = pk2(O0*rl, O1*rl); w2v.y = pk2(O2*rl, O3*rl);
  *(uint2*)(attnout + (size_t)(q0 + q)*128 + head*32 + d0) = w2v;
}

// ---------------------------------------------------------------------------
// decoder pairs: ABp [N][256] bf16 rows = [Ap | Bp]
// ---------------------------------------------------------------------------
__global__ __launch_bounds__(256) void pair_kernel(
    const ushort* __restrict__ ABp,
    const int* __restrict__ ps, const int* __restrict__ pd,
    const float* __restrict__ fc2w, const float* __restrict__ fc2b,
    float* __restrict__ out, int EP)
{
  int gw = (blockIdx.x * blockDim.x + threadIdx.x) >> 6;
  int lane = threadIdx.x & 63;
  int nw = (gridDim.x * blockDim.x) >> 6;
  float w0 = fc2w[2*lane], w1 = fc2w[2*lane + 1];
  float bb = fc2b[0];
  for (int p = gw; p < EP; p += nw) {
    int s = ps[p], d = pd[p];
    unsigned av = *(const unsigned*)(ABp + (size_t)s*256 + 2*lane);
    unsigned bv = *(const unsigned*)(ABp + (size_t)d*256 + 128 + 2*lane);
    float a0 = b2flo(av), a1 = b2fhi(av);
    float b0 = b2flo(bv), b1 = b2fhi(bv);
    float acc = fmaxf(a0 + b0, 0.f)*w0 + fmaxf(a1 + b1, 0.f)*w1;
    #pragma unroll
    for (int off = 32; off > 0; off >>= 1) acc += __shfl_down(acc, off);
    if (lane == 0) out[p] = 1.f / (1.f + __expf(-(acc + bb)));
  }
}

// ---------------------------------------------------------------------------
extern "C" void kernel_launch(void* const* d_in, const int* in_sizes, int n_in,
                              void* d_out, int out_size, void* d_ws, size_t ws_size,
                              hipStream_t stream)
{
  const float* features = (const float*)d_in[0];
  const int*   src      = (const int*)d_in[1];
  const int*   dst      = (const int*)d_in[2];
  const int*   psrc     = (const int*)d_in[3];
  const int*   pdst     = (const int*)d_in[4];
  const float* W1   = (const float*)d_in[5];
  const float* al1  = (const float*)d_in[6];
  const float* ar1  = (const float*)d_in[7];
  const float* b1   = (const float*)d_in[8];
  const float* W2   = (const float*)d_in[9];
  const float* al2  = (const float*)d_in[10];
  const float* ar2  = (const float*)d_in[11];
  const float* b2   = (const float*)d_in[12];
  const float* tw_qkv = (const float*)d_in[13];
  const float* tb_qkv = (const float*)d_in[14];
  const float* tw_o   = (const float*)d_in[15];
  const float* tb_o   = (const float*)d_in[16];
  const float* ln1_g  = (const float*)d_in[17];
  const float* ln1_b  = (const float*)d_in[18];
  const float* tw_ff1 = (const float*)d_in[19];
  const float* tb_ff1 = (const float*)d_in[20];
  const float* tw_ff2 = (const float*)d_in[21];
  const float* tb_ff2 = (const float*)d_in[22];
  const float* ln2_g  = (const float*)d_in[23];
  const float* ln2_b  = (const float*)d_in[24];
  const float* fc1_w  = (const float*)d_in[25];
  const float* fc1_b  = (const float*)d_in[26];
  const float* fc2_w  = (const float*)d_in[27];
  const float* fc2_b  = (const float*)d_in[28];
  int E  = in_sizes[1];
  int EP = in_sizes[3];

  float* ws = (float*)d_ws;
  size_t off = 0;
  auto alloc = [&](size_t n) { float* p = ws + off; off += n; return p; };
  ushort* hb    = (ushort*)alloc((size_t)NN * 64);    // [4096][128] bf16 state
  ushort* h1b   = (ushort*)alloc((size_t)NN * 256);   // [4096][512] bf16
  ushort* h2b   = (ushort*)alloc((size_t)NN * 256);   // [4096][512] bf16
  ushort* bigb  = (ushort*)alloc((size_t)NN * 256);   // [4096][512] bf16
  ushort* hgb   = (ushort*)alloc((size_t)NN * 64);    // [4096][128] bf16
  ushort* qb    = (ushort*)alloc((size_t)NN * 64);    // [4096][128] bf16
  ushort* attnb = (ushort*)alloc((size_t)NN * 64);    // [4096][128] bf16
  ushort* kt    = (ushort*)alloc((size_t)NN * 64);    // [4][256][16][32]
  ushort* vt    = (ushort*)alloc((size_t)NN * 64);    // [4][128][2][16][32]
  ushort* wbf   = (ushort*)alloc(622592/2);           // all weights bf16
  ushort* ABp   = (ushort*)alloc((size_t)NN * 128);   // [4096][256] bf16
  float*  bias256 = alloc(256);
  float*  el1   = alloc((size_t)NN * 4);
  float*  er1   = alloc((size_t)NN * 4);
  float*  el2   = alloc((size_t)NN);
  float*  er2   = alloc((size_t)NN);
  int* ibase    = (int*)(ws + off);
  int* rowstart = ibase;
  int* cursor   = ibase + 4097;
  int* nbr      = cursor + 4096;

  // bf16 weight offsets
  const size_t oW1 = 0, oW2 = 131072, oQKV = 196608, oO = 294912,
               oFF1 = 327680, oFF2 = 458752, oFC1 = 589824;

  cvt_weights<<<609, 256, 0, stream>>>(W1, W2, tw_qkv, tw_o, tw_ff1, tw_ff2,
                                       fc1_w, fc1_b, wbf, bias256);

  // CSR build over dst (2 dispatches)
  csr_build<<<1, 1024, 0, stream>>>(dst, rowstart, cursor, E);
  fill_kernel<<<(E + 255)/256, 256, 0, stream>>>(src, dst, cursor, nbr, E);

  // GAT layer 1
  gemm_mf<false,false,true,false><<<dim3(8, 64), 256, 0, stream>>>(
      features, wbf + oW1, nullptr, h1b, NN, 512, 256, 256);
  elr_kernel<4><<<1024, 256, 0, stream>>>(h1b, al1, ar1, el1, er1);
  gat_agg4<<<1024, 256, 0, stream>>>(h1b, el1, er1, rowstart, nbr, b1, h2b);

  // GAT layer 2
  gemm_mf<false,false,true,true><<<dim3(2, 64), 256, 0, stream>>>(
      h2b, wbf + oW2, nullptr, hgb, NN, 128, 512, 512);
  elr_kernel<1><<<1024, 256, 0, stream>>>(hgb, al2, ar2, el2, er2);
  gat_agg1<<<1024, 256, 0, stream>>>(hgb, el2, er2, rowstart, nbr, b2, hb);

  // Transformer encoder (2 layers)
  for (int l = 0; l < 2; l++) {
    gemm_qkv<<<dim3(6, 64), 256, 0, stream>>>(
        hb, wbf + oQKV + (size_t)l*49152, tb_qkv + l*384, qb, kt, vt);
    attn_mfma<<<512, 256, 0, stream>>>(qb, kt, vt, attnb);
    gemm_ln<<<256, 256, 0, stream>>>(
        attnb, wbf + oO + (size_t)l*16384, tb_o + l*128, hb,
        ln1_g + l*128, ln1_b + l*128, 128);
    gemm_mf<true,true,true,true><<<dim3(8, 64), 256, 0, stream>>>(
        hb, wbf + oFF1 + (size_t)l*65536, tb_ff1 + l*512, bigb, NN, 512, 128, 128);
    gemm_ln<<<256, 256, 0, stream>>>(
        bigb, wbf + oFF2 + (size_t)l*65536, tb_ff2 + l*128, hb,
        ln2_g + l*128, ln2_b + l*128, 512);
  }

  // Decoder: one N=256 gemm (re-packed fc1) -> [Ap|Bp] bf16, then pairs
  gemm_mf<true,false,true,true><<<dim3(4, 64), 256, 0, stream>>>(
      hb, wbf + oFC1, bias256, ABp, NN, 256, 128, 128);
  pair_kernel<<<1024, 256, 0, stream>>>(ABp, psrc, pdst, fc2_w, fc2_b, (float*)d_out, EP);
}

// Round 9
// 218.767 us; speedup vs baseline: 1.1069x; 1.1069x over previous
//
#include <hip/hip_runtime.h>
#include <hip/hip_bf16.h>
#include <math.h>

// Model constants (fixed by the reference)
#define NN   4096   // nodes
#define INC  256
#define HIDF 128
#define H1H  4
#define DM   128    // transformer d_model
#define THD  4      // transformer heads (head dim 32)
#define FFD  512

typedef __attribute__((ext_vector_type(8))) short bf16x8;
typedef __attribute__((ext_vector_type(4))) float f32x4;

__device__ __forceinline__ float leaky(float x){ return x > 0.f ? x : 0.2f*x; }

// fp32 -> bf16 bits via HW convert (RNE)
__device__ __forceinline__ ushort f2b(float f){
  __hip_bfloat16 h = __float2bfloat16(f);
  return __builtin_bit_cast(ushort, h);
}
__device__ __forceinline__ unsigned pk2(float a, float b){
  return (unsigned)f2b(a) | ((unsigned)f2b(b) << 16);
}
// bf16 bits -> fp32
__device__ __forceinline__ float b2f(unsigned u){ return __uint_as_float(u << 16); }
__device__ __forceinline__ float b2flo(unsigned u){ return __uint_as_float(u << 16); }
__device__ __forceinline__ float b2fhi(unsigned u){ return __uint_as_float(u & 0xffff0000u); }

// kv bit-permutation within 32-blocks: {b4,b3,b2,b1,b0} -> {b3,b2,b4,b1,b0}
__device__ __forceinline__ int kvperm(int kv){
  return (kv & ~31) | ((kv & 12) << 1) | ((kv >> 2) & 4) | (kv & 3);
}

// ---------------------------------------------------------------------------
// bf16 MFMA GEMM: C[M,N] = A[M,K] @ Wb[N,ldw](bf16)^T (+bias)(+relu)
// 64x64 tile, BK=64, 256 threads = 4 waves (2x2 of 32x32).
// ---------------------------------------------------------------------------
template<bool BIAS, bool RELU, bool OUTBF, bool ABF>
__global__ __launch_bounds__(256) void gemm_mf(
    const void* __restrict__ Av, const ushort* __restrict__ Wb,
    const float* __restrict__ bias, void* __restrict__ Cv,
    int M, int N, int K, int ldw)
{
  __shared__ uint4 As4[512];   // [ko 0..7][m 0..63] : 8 bf16 each
  __shared__ uint4 Bs4[512];
  int tid = threadIdx.x;
  int row0 = blockIdx.y * 64, col0 = blockIdx.x * 64;
  int wid = tid >> 6, lane = tid & 63;
  int wm = wid >> 1, wn = wid & 1;
  int ql = lane & 15, g = lane >> 4;
  const f32x4 z4 = {0.f,0.f,0.f,0.f};
  f32x4 acc[2][2] = {z4,z4,z4,z4};

  for (int k0 = 0; k0 < K; k0 += 64) {
    #pragma unroll
    for (int p = 0; p < 2; p++) {
      int idx = tid + p*256;         // 0..511
      int ko = idx & 7, mm = idx >> 3;
      if constexpr (ABF) {
        As4[ko*64 + mm] = *(const uint4*)((const ushort*)Av + (size_t)(row0 + mm)*K + k0 + ko*8);
      } else {
        const float* sa = (const float*)Av + (size_t)(row0 + mm)*K + k0 + ko*8;
        float4 a0 = *(const float4*)sa;
        float4 a1 = *(const float4*)(sa + 4);
        uint4 av;
        av.x = pk2(a0.x, a0.y); av.y = pk2(a0.z, a0.w);
        av.z = pk2(a1.x, a1.y); av.w = pk2(a1.z, a1.w);
        As4[ko*64 + mm] = av;
      }
      Bs4[ko*64 + mm] = *(const uint4*)(Wb + (size_t)(col0 + mm)*ldw + k0 + ko*8);
    }
    __syncthreads();
    #pragma unroll
    for (int kk = 0; kk < 2; kk++) {
      int ko = kk*4 + g;
      bf16x8 a0 = *((const bf16x8*)As4 + ko*64 + wm*32 + ql);
      bf16x8 a1 = *((const bf16x8*)As4 + ko*64 + wm*32 + 16 + ql);
      bf16x8 b0 = *((const bf16x8*)Bs4 + ko*64 + wn*32 + ql);
      bf16x8 b1 = *((const bf16x8*)Bs4 + ko*64 + wn*32 + 16 + ql);
      acc[0][0] = __builtin_amdgcn_mfma_f32_16x16x32_bf16(a0, b0, acc[0][0], 0,0,0);
      acc[0][1] = __builtin_amdgcn_mfma_f32_16x16x32_bf16(a0, b1, acc[0][1], 0,0,0);
      acc[1][0] = __builtin_amdgcn_mfma_f32_16x16x32_bf16(a1, b0, acc[1][0], 0,0,0);
      acc[1][1] = __builtin_amdgcn_mfma_f32_16x16x32_bf16(a1, b1, acc[1][1], 0,0,0);
    }
    __syncthreads();
  }
  float bvs[2] = {0.f, 0.f};
  if (BIAS) {
    bvs[0] = bias[col0 + wn*32 + ql];
    bvs[1] = bias[col0 + wn*32 + 16 + ql];
  }
  #pragma unroll
  for (int fm = 0; fm < 2; fm++)
    #pragma unroll
    for (int fn = 0; fn < 2; fn++) {
      int row = row0 + wm*32 + fm*16 + g*4;
      int col = col0 + wn*32 + fn*16 + ql;
      #pragma unroll
      for (int r = 0; r < 4; r++) {
        float v = acc[fm][fn][r];
        if (BIAS) v += bvs[fn];
        if (RELU) v = fmaxf(v, 0.f);
        if (OUTBF) ((ushort*)Cv)[(size_t)(row + r)*N + col] = f2b(v);
        else       ((float*)Cv)[(size_t)(row + r)*N + col] = v;
      }
    }
}

// ---------------------------------------------------------------------------
// qkv GEMM with fused Q-scale + K/V tile scatter.
// ---------------------------------------------------------------------------
__global__ __launch_bounds__(256) void gemm_qkv(
    const ushort* __restrict__ Ab, const ushort* __restrict__ Wb,
    const float* __restrict__ bias,
    ushort* __restrict__ qb, ushort* __restrict__ kt, ushort* __restrict__ vt)
{
  __shared__ uint4 As4[512];
  __shared__ uint4 Bs4[512];
  int tid = threadIdx.x;
  int row0 = blockIdx.y * 64, col0 = blockIdx.x * 64;
  int wid = tid >> 6, lane = tid & 63;
  int wm = wid >> 1, wn = wid & 1;
  int ql = lane & 15, g = lane >> 4;
  const f32x4 z4 = {0.f,0.f,0.f,0.f};
  f32x4 acc[2][2] = {z4,z4,z4,z4};

  for (int k0 = 0; k0 < 128; k0 += 64) {
    #pragma unroll
    for (int p = 0; p < 2; p++) {
      int idx = tid + p*256;
      int ko = idx & 7, mm = idx >> 3;
      As4[ko*64 + mm] = *(const uint4*)(Ab + (size_t)(row0 + mm)*128 + k0 + ko*8);
      Bs4[ko*64 + mm] = *(const uint4*)(Wb + (size_t)(col0 + mm)*128 + k0 + ko*8);
    }
    __syncthreads();
    #pragma unroll
    for (int kk = 0; kk < 2; kk++) {
      int ko = kk*4 + g;
      bf16x8 a0 = *((const bf16x8*)As4 + ko*64 + wm*32 + ql);
      bf16x8 a1 = *((const bf16x8*)As4 + ko*64 + wm*32 + 16 + ql);
      bf16x8 b0 = *((const bf16x8*)Bs4 + ko*64 + wn*32 + ql);
      bf16x8 b1 = *((const bf16x8*)Bs4 + ko*64 + wn*32 + 16 + ql);
      acc[0][0] = __builtin_amdgcn_mfma_f32_16x16x32_bf16(a0, b0, acc[0][0], 0,0,0);
      acc[0][1] = __builtin_amdgcn_mfma_f32_16x16x32_bf16(a0, b1, acc[0][1], 0,0,0);
      acc[1][0] = __builtin_amdgcn_mfma_f32_16x16x32_bf16(a1, b0, acc[1][0], 0,0,0);
      acc[1][1] = __builtin_amdgcn_mfma_f32_16x16x32_bf16(a1, b1, acc[1][1], 0,0,0);
    }
    __syncthreads();
  }
  float bvs[2];
  bvs[0] = bias[col0 + wn*32 + ql];
  bvs[1] = bias[col0 + wn*32 + 16 + ql];
  #pragma unroll
  for (int fm = 0; fm < 2; fm++)
    #pragma unroll
    for (int fn = 0; fn < 2; fn++) {
      int row = row0 + wm*32 + fm*16 + g*4;
      int col = col0 + wn*32 + fn*16 + ql;
      #pragma unroll
      for (int r = 0; r < 4; r++) {
        float v = acc[fm][fn][r] + bvs[fn];
        int kv = row + r;
        if (col < 128) {
          qb[(size_t)kv*128 + col] = f2b(v * 0.25505654708f);  // 1/sqrt(32)*log2e
        } else if (col < 256) {
          int hh = (col - 128) >> 5, d = (col - 128) & 31;
          kt[(size_t)hh*131072 + (size_t)kv*32 + d] = f2b(v);
        } else {
          int hh = (col - 256) >> 5, d = (col - 256) & 31;
          vt[(size_t)hh*131072 + (size_t)(kv >> 5)*1024 + (d >> 4)*512
             + (d & 15)*32 + kvperm(kv & 31)] = f2b(v);
        }
      }
    }
}

// ---------------------------------------------------------------------------
// Fused bf16 GEMM (N=128) + residual + LayerNorm, in-place on bf16 h.
// BM=16 rows/block -> grid 256. 4 waves, wave w = cols w*32..+31.
// ---------------------------------------------------------------------------
__global__ __launch_bounds__(256) void gemm_ln(
    const ushort* __restrict__ Ab, const ushort* __restrict__ Wb,
    const float* __restrict__ bias, ushort* __restrict__ h,
    const float* __restrict__ lng, const float* __restrict__ lnb, int K)
{
  __shared__ uint4 As4[128];    // [ko 0..7][m 0..15]
  __shared__ uint4 Bs4[1024];   // [ko 0..7][n 0..127]
  __shared__ float xs[16][132];
  int tid = threadIdx.x;
  int row0 = blockIdx.x * 16;
  int wv = tid >> 6, lane = tid & 63;
  int ql = lane & 15, g = lane >> 4;
  const f32x4 z4 = {0.f,0.f,0.f,0.f};
  f32x4 acc[2] = {z4, z4};

  for (int k0 = 0; k0 < K; k0 += 64) {
    if (tid < 128) {
      int ko = tid & 7, mm = tid >> 3;
      As4[ko*16 + mm] = *(const uint4*)(Ab + (size_t)(row0 + mm)*K + k0 + ko*8);
    }
    #pragma unroll
    for (int p = 0; p < 4; p++) {
      int idx = tid + p*256;     // 0..1023
      int ko = idx & 7, nn = idx >> 3;
      Bs4[ko*128 + nn] = *(const uint4*)(Wb + (size_t)nn*K + k0 + ko*8);
    }
    __syncthreads();
    #pragma unroll
    for (int kk = 0; kk < 2; kk++) {
      int ko = kk*4 + g;
      bf16x8 a = *((const bf16x8*)As4 + ko*16 + ql);
      #pragma unroll
      for (int fn = 0; fn < 2; fn++) {
        bf16x8 b = *((const bf16x8*)Bs4 + ko*128 + wv*32 + fn*16 + ql);
        acc[fn] = __builtin_amdgcn_mfma_f32_16x16x32_bf16(a, b, acc[fn], 0,0,0);
      }
    }
    __syncthreads();
  }
  // stage gemm+bias into LDS
  #pragma unroll
  for (int fn = 0; fn < 2; fn++) {
    int col = wv*32 + fn*16 + ql;
    float bv = bias[col];
    #pragma unroll
    for (int r = 0; r < 4; r++) xs[g*4 + r][col] = acc[fn][r] + bv;
  }
  __syncthreads();
  // residual + LN: 16 lanes per row, 8 cols each
  int rl = tid >> 4, cl = tid & 15, c0 = cl * 8;
  ushort* hrow = h + (size_t)(row0 + rl)*128;
  uint4 rv = *(const uint4*)(hrow + c0);
  float x[8];
  x[0] = xs[rl][c0+0] + b2flo(rv.x); x[1] = xs[rl][c0+1] + b2fhi(rv.x);
  x[2] = xs[rl][c0+2] + b2flo(rv.y); x[3] = xs[rl][c0+3] + b2fhi(rv.y);
  x[4] = xs[rl][c0+4] + b2flo(rv.z); x[5] = xs[rl][c0+5] + b2fhi(rv.z);
  x[6] = xs[rl][c0+6] + b2flo(rv.w); x[7] = xs[rl][c0+7] + b2fhi(rv.w);
  float s1 = 0.f, s2 = 0.f;
  #pragma unroll
  for (int i = 0; i < 8; i++) { s1 += x[i]; s2 += x[i]*x[i]; }
  #pragma unroll
  for (int st = 1; st < 16; st <<= 1) {
    s1 += __shfl_xor(s1, st); s2 += __shfl_xor(s2, st);
  }
  float mean = s1 * (1.f/128.f);
  float var  = s2 * (1.f/128.f) - mean*mean;
  float rstd = rsqrtf(var + 1e-5f);
  float o[8];
  #pragma unroll
  for (int i = 0; i < 8; i += 4) {
    float4 g4 = *(const float4*)(lng + c0 + i);
    float4 b4 = *(const float4*)(lnb + c0 + i);
    o[i+0] = (x[i+0]-mean)*rstd*g4.x + b4.x;
    o[i+1] = (x[i+1]-mean)*rstd*g4.y + b4.y;
    o[i+2] = (x[i+2]-mean)*rstd*g4.z + b4.z;
    o[i+3] = (x[i+3]-mean)*rstd*g4.w + b4.w;
  }
  uint4 ov; ov.x = pk2(o[0],o[1]); ov.y = pk2(o[2],o[3]);
  ov.z = pk2(o[4],o[5]); ov.w = pk2(o[6],o[7]);
  *(uint4*)(hrow + c0) = ov;
}

// ---------------------------------------------------------------------------
// one-shot weight fp32->bf16 conversion; fc1 re-packed to [256][128].
// ---------------------------------------------------------------------------
__global__ __launch_bounds__(256) void cvt_weights(
    const float* __restrict__ W1, const float* __restrict__ W2,
    const float* __restrict__ qkv, const float* __restrict__ o,
    const float* __restrict__ ff1, const float* __restrict__ ff2,
    const float* __restrict__ fc1, const float* __restrict__ fc1b,
    ushort* __restrict__ out, float* __restrict__ bias256)
{
  if (blockIdx.x == 608) {
    int t = threadIdx.x;
    bias256[t] = (t < 128) ? fc1b[t] : 0.f;
    return;
  }
  int i4 = (blockIdx.x*256 + threadIdx.x) * 4;
  const float* s; int loc;
  size_t dst = i4;
  if      (i4 < 131072) { s = W1;  loc = i4; }
  else if (i4 < 196608) { s = W2;  loc = i4 - 131072; }
  else if (i4 < 294912) { s = qkv; loc = i4 - 196608; }
  else if (i4 < 327680) { s = o;   loc = i4 - 294912; }
  else if (i4 < 458752) { s = ff1; loc = i4 - 327680; }
  else if (i4 < 589824) { s = ff2; loc = i4 - 458752; }
  else {
    s = fc1; loc = i4 - 589824;
    int j = loc >> 8, k2 = loc & 255;
    dst = 589824 + ((k2 >= 128) ? 16384 : 0) + j*128 + (k2 & 127);
  }
  float4 v = *(const float4*)(s + loc);
  uint2 w; w.x = pk2(v.x, v.y); w.y = pk2(v.z, v.w);
  *(uint2*)(out + dst) = w;
}

// ---------------------------------------------------------------------------
// CSR build over dst: parallel count (global atomics) + 1-block scan + fill
// ---------------------------------------------------------------------------
__global__ void zero_kernel(int* p, int n) {
  int i = blockIdx.x * blockDim.x + threadIdx.x;
  if (i < n) p[i] = 0;
}
__global__ void count_kernel(const int* __restrict__ dst, int* __restrict__ deg, int E) {
  int e = blockIdx.x * blockDim.x + threadIdx.x;
  if (e < E) atomicAdd(&deg[dst[e]], 1);
}
__global__ __launch_bounds__(1024) void scan_kernel(
    const int* __restrict__ deg, int* __restrict__ rowstart, int* __restrict__ cursor)
{
  __shared__ int sdata[1024];
  int t = threadIdx.x;
  int base = t * 4;
  int v0 = deg[base], v1 = deg[base+1], v2 = deg[base+2], v3 = deg[base+3];
  int tot = v0 + v1 + v2 + v3;
  sdata[t] = tot;
  __syncthreads();
  for (int off = 1; off < 1024; off <<= 1) {
    int x = (t >= off) ? sdata[t - off] : 0;
    __syncthreads();
    sdata[t] += x;
    __syncthreads();
  }
  int run = sdata[t] - tot;  // exclusive
  rowstart[base]   = run; cursor[base]   = run; run += v0;
  rowstart[base+1] = run; cursor[base+1] = run; run += v1;
  rowstart[base+2] = run; cursor[base+2] = run; run += v2;
  rowstart[base+3] = run; cursor[base+3] = run; run += v3;
  if (t == 1023) rowstart[4096] = run;
}
__global__ void fill_kernel(const int* __restrict__ src, const int* __restrict__ dst,
                            int* __restrict__ cursor, int* __restrict__ nbr, int E) {
  int e = blockIdx.x * blockDim.x + threadIdx.x;
  if (e < E) {
    int p = atomicAdd(&cursor[dst[e]], 1);
    nbr[p] = src[e];
  }
}

// ---------------------------------------------------------------------------
// el/er attention coefficients (bf16 h input); one wave per node.
// ---------------------------------------------------------------------------
template<int H>
__global__ __launch_bounds__(256) void elr_kernel(
    const ushort* __restrict__ hmat, const float* __restrict__ al,
    const float* __restrict__ ar, float* __restrict__ el, float* __restrict__ er)
{
  int w = threadIdx.x >> 6, lane = threadIdx.x & 63;
  int n = blockIdx.x * 4 + w;
  if constexpr (H == 4) {
    int hh = lane >> 4, f0 = (lane & 15) * 8;
    bf16x8 hv = *(const bf16x8*)(hmat + (size_t)n*512 + hh*128 + f0);
    float4 a0 = *(const float4*)(al + hh*128 + f0);
    float4 a1 = *(const float4*)(al + hh*128 + f0 + 4);
    float4 r0 = *(const float4*)(ar + hh*128 + f0);
    float4 r1 = *(const float4*)(ar + hh*128 + f0 + 4);
    float x[8];
    #pragma unroll
    for (int i = 0; i < 8; i++) x[i] = b2f((ushort)hv[i]);
    float e1 = x[0]*a0.x + x[1]*a0.y + x[2]*a0.z + x[3]*a0.w
             + x[4]*a1.x + x[5]*a1.y + x[6]*a1.z + x[7]*a1.w;
    float e2 = x[0]*r0.x + x[1]*r0.y + x[2]*r0.z + x[3]*r0.w
             + x[4]*r1.x + x[5]*r1.y + x[6]*r1.z + x[7]*r1.w;
    #pragma unroll
    for (int s = 1; s < 16; s <<= 1) { e1 += __shfl_xor(e1, s); e2 += __shfl_xor(e2, s); }
    if ((lane & 15) == 0) { el[n*4 + hh] = e1; er[n*4 + hh] = e2; }
  } else {
    int f0 = lane * 2;
    unsigned u = *(const unsigned*)(hmat + (size_t)n*128 + f0);
    float x0 = b2flo(u), x1 = b2fhi(u);
    float2 av = *(const float2*)(al + f0);
    float2 rv = *(const float2*)(ar + f0);
    float e1 = x0*av.x + x1*av.y;
    float e2 = x0*rv.x + x1*rv.y;
    #pragma unroll
    for (int s = 1; s < 64; s <<= 1) { e1 += __shfl_xor(e1, s); e2 += __shfl_xor(e2, s); }
    if (lane == 0) { el[n] = e1; er[n] = e2; }
  }
}

// ---------------------------------------------------------------------------
// GAT aggregation H=4: one wave/node, NO max tracking (scores provably small,
// softmax shift-invariant). deg<=256: single edge pass (p stored in LDS).
// ---------------------------------------------------------------------------
__global__ __launch_bounds__(256) void gat_agg4(
    const ushort* __restrict__ hsrc, const float* __restrict__ el, const float* __restrict__ er,
    const int* __restrict__ rowstart, const int* __restrict__ nbr,
    const float* __restrict__ bias, ushort* __restrict__ out)
{
  __shared__ float s_alpha[4][256][4];
  __shared__ int   s_nbr[4][256];
  int wv = threadIdx.x >> 6, lane = threadIdx.x & 63;
  int n = blockIdx.x * 4 + wv;
  int e0 = rowstart[n];
  int deg = rowstart[n+1] - e0;
  float4 ern = *(const float4*)(er + (size_t)n*4);
  int hh = lane >> 4;
  float acc[8] = {};
  if (deg > 0 && deg <= 256) {
    // single pass: p = exp(e) stored, sum accumulated
    float se0=0.f, se1=0.f, se2=0.f, se3=0.f;
    for (int i = lane; i < deg; i += 64) {
      int s = nbr[e0 + i];
      s_nbr[wv][i] = s;
      float4 ev = *(const float4*)(el + (size_t)s*4);
      float p0 = __expf(leaky(ev.x + ern.x));
      float p1 = __expf(leaky(ev.y + ern.y));
      float p2 = __expf(leaky(ev.z + ern.z));
      float p3 = __expf(leaky(ev.w + ern.w));
      s_alpha[wv][i][0] = p0; s_alpha[wv][i][1] = p1;
      s_alpha[wv][i][2] = p2; s_alpha[wv][i][3] = p3;
      se0 += p0; se1 += p1; se2 += p2; se3 += p3;
    }
    #pragma unroll
    for (int st = 1; st < 64; st <<= 1) {
      se0 += __shfl_xor(se0, st); se1 += __shfl_xor(se1, st);
      se2 += __shfl_xor(se2, st); se3 += __shfl_xor(se3, st);
    }
    float si = 1.f / ((hh == 0) ? se0 : (hh == 1) ? se1 : (hh == 2) ? se2 : se3);
    #pragma unroll 4
    for (int i = 0; i < deg; i++) {
      float a = s_alpha[wv][i][hh] * si;
      int s = s_nbr[wv][i];
      uint4 hv = *(const uint4*)(hsrc + (size_t)s*512 + lane*8);
      acc[0] += a * b2flo(hv.x); acc[1] += a * b2fhi(hv.x);
      acc[2] += a * b2flo(hv.y); acc[3] += a * b2fhi(hv.y);
      acc[4] += a * b2flo(hv.z); acc[5] += a * b2fhi(hv.z);
      acc[6] += a * b2flo(hv.w); acc[7] += a * b2fhi(hv.w);
    }
  } else if (deg > 0) {
    // fallback: 2 passes, chunked
    float se0=0.f, se1=0.f, se2=0.f, se3=0.f;
    for (int i = lane; i < deg; i += 64) {
      int s = nbr[e0 + i];
      float4 ev = *(const float4*)(el + (size_t)s*4);
      se0 += __expf(leaky(ev.x + ern.x));
      se1 += __expf(leaky(ev.y + ern.y));
      se2 += __expf(leaky(ev.z + ern.z));
      se3 += __expf(leaky(ev.w + ern.w));
    }
    #pragma unroll
    for (int st = 1; st < 64; st <<= 1) {
      se0 += __shfl_xor(se0, st); se1 += __shfl_xor(se1, st);
      se2 += __shfl_xor(se2, st); se3 += __shfl_xor(se3, st);
    }
    float si0 = 1.f/se0, si1 = 1.f/se1, si2 = 1.f/se2, si3 = 1.f/se3;
    for (int c = 0; c < deg; c += 256) {
      int cn = min(256, deg - c);
      for (int i = lane; i < cn; i += 64) {
        int s = nbr[e0 + c + i];
        s_nbr[wv][i] = s;
        float4 ev = *(const float4*)(el + (size_t)s*4);
        s_alpha[wv][i][0] = __expf(leaky(ev.x + ern.x)) * si0;
        s_alpha[wv][i][1] = __expf(leaky(ev.y + ern.y)) * si1;
        s_alpha[wv][i][2] = __expf(leaky(ev.z + ern.z)) * si2;
        s_alpha[wv][i][3] = __expf(leaky(ev.w + ern.w)) * si3;
      }
      #pragma unroll 4
      for (int i = 0; i < cn; i++) {
        float a = s_alpha[wv][i][hh];
        int s = s_nbr[wv][i];
        uint4 hv = *(const uint4*)(hsrc + (size_t)s*512 + lane*8);
        acc[0] += a * b2flo(hv.x); acc[1] += a * b2fhi(hv.x);
        acc[2] += a * b2flo(hv.y); acc[3] += a * b2fhi(hv.y);
        acc[4] += a * b2flo(hv.z); acc[5] += a * b2fhi(hv.z);
        acc[6] += a * b2flo(hv.w); acc[7] += a * b2fhi(hv.w);
      }
    }
  }
  const float* bp = bias + lane*8;
  float4 b0 = *(const float4*)(bp);
  float4 b1 = *(const float4*)(bp + 4);
  float v0 = fmaxf(acc[0]+b0.x, 0.f), v1 = fmaxf(acc[1]+b0.y, 0.f);
  float v2 = fmaxf(acc[2]+b0.z, 0.f), v3 = fmaxf(acc[3]+b0.w, 0.f);
  float v4 = fmaxf(acc[4]+b1.x, 0.f), v5 = fmaxf(acc[5]+b1.y, 0.f);
  float v6 = fmaxf(acc[6]+b1.z, 0.f), v7 = fmaxf(acc[7]+b1.w, 0.f);
  uint4 ov; ov.x = pk2(v0,v1); ov.y = pk2(v2,v3); ov.z = pk2(v4,v5); ov.w = pk2(v6,v7);
  *(uint4*)(out + (size_t)n*512 + lane*8) = ov;
}

// ---------------------------------------------------------------------------
// GAT aggregation H=1: one wave/node, no max tracking, single-pass deg<=256.
// ---------------------------------------------------------------------------
__global__ __launch_bounds__(256) void gat_agg1(
    const ushort* __restrict__ hsrc, const float* __restrict__ el, const float* __restrict__ er,
    const int* __restrict__ rowstart, const int* __restrict__ nbr,
    const float* __restrict__ bias, ushort* __restrict__ out)
{
  __shared__ float s_alpha[4][256];
  __shared__ int   s_nbr[4][256];
  int wv = threadIdx.x >> 6, lane = threadIdx.x & 63;
  int n = blockIdx.x * 4 + wv;
  int e0 = rowstart[n];
  int deg = rowstart[n+1] - e0;
  float ern = er[n];
  float a0 = 0.f, a1 = 0.f;
  if (deg > 0 && deg <= 256) {
    float se = 0.f;
    for (int i = lane; i < deg; i += 64) {
      int s = nbr[e0 + i];
      s_nbr[wv][i] = s;
      float p = __expf(leaky(el[s] + ern));
      s_alpha[wv][i] = p;
      se += p;
    }
    #pragma unroll
    for (int st = 1; st < 64; st <<= 1) se += __shfl_xor(se, st);
    float si = 1.f / se;
    #pragma unroll 4
    for (int i = 0; i < deg; i++) {
      float a = s_alpha[wv][i] * si;
      int s = s_nbr[wv][i];
      unsigned u = *(const unsigned*)(hsrc + (size_t)s*128 + lane*2);
      a0 += a * b2flo(u);
      a1 += a * b2fhi(u);
    }
  } else if (deg > 0) {
    float se = 0.f;
    for (int i = lane; i < deg; i += 64)
      se += __expf(leaky(el[nbr[e0 + i]] + ern));
    #pragma unroll
    for (int st = 1; st < 64; st <<= 1) se += __shfl_xor(se, st);
    float si = 1.f / se;
    for (int c = 0; c < deg; c += 256) {
      int cn = min(256, deg - c);
      for (int i = lane; i < cn; i += 64) {
        int s = nbr[e0 + c + i];
        s_nbr[wv][i] = s;
        s_alpha[wv][i] = __expf(leaky(el[s] + ern)) * si;
      }
      #pragma unroll 4
      for (int i = 0; i < cn; i++) {
        float a = s_alpha[wv][i];
        int s = s_nbr[wv][i];
        unsigned u = *(const unsigned*)(hsrc + (size_t)s*128 + lane*2);
        a0 += a * b2flo(u);
        a1 += a * b2fhi(u);
      }
    }
    a0 *= si; a1 *= si;
    a0 /= si; a1 /= si;   // (no-op; keep structure simple)
  }
  float v0 = a0 + bias[lane*2], v1 = a1 + bias[lane*2 + 1];
  *(unsigned*)(out + (size_t)n*128 + lane*2) = pk2(v0, v1);
}

// ---------------------------------------------------------------------------
// MFMA flash attention (unchanged)
// ---------------------------------------------------------------------------
#define LOADFRAGS(KF, VF, KV)                                              \
  {                                                                        \
    int _kv = (KV);                                                        \
    if (_kv < 1024) {                                                      \
      const ushort* _kp = kptr + (size_t)_kv * 32;                         \
      const ushort* _vp = vptr + (size_t)_kv * 32;                         \
      KF[0] = *(const bf16x8*)(_kp);                                       \
      KF[1] = *(const bf16x8*)(_kp + 512);                                 \
      KF[2] = *(const bf16x8*)(_kp + 1024);                                \
      KF[3] = *(const bf16x8*)(_kp + 1536);                                \
      VF[0] = *(const bf16x8*)(_vp);                                       \
      VF[1] = *(const bf16x8*)(_vp + 1024);                                \
      VF[2] = *(const bf16x8*)(_vp + 512);                                 \
      VF[3] = *(const bf16x8*)(_vp + 1536);                                \
    }                                                                      \
  }

#define QPASS(QF, LS, OA, OB, KF, VF)                                      \
  {                                                                        \
    f32x4 st0 = __builtin_amdgcn_mfma_f32_16x16x32_bf16(KF[0], QF, z4, 0, 0, 0); \
    f32x4 st1 = __builtin_amdgcn_mfma_f32_16x16x32_bf16(KF[1], QF, z4, 0, 0, 0); \
    f32x4 st2 = __builtin_amdgcn_mfma_f32_16x16x32_bf16(KF[2], QF, z4, 0, 0, 0); \
    f32x4 st3 = __builtin_amdgcn_mfma_f32_16x16x32_bf16(KF[3], QF, z4, 0, 0, 0); \
    float pvv[16];                                                         \
    _Pragma("unroll")                                                      \
    for (int i = 0; i < 4; i++) {                                          \
      pvv[i] = st0[i]; pvv[4+i] = st1[i]; pvv[8+i] = st2[i]; pvv[12+i] = st3[i]; \
    }                                                                      \
    _Pragma("unroll")                                                      \
    for (int i = 0; i < 16; i++) { pvv[i] = exp2f(pvv[i]); LS += pvv[i]; } \
    bf16x8 pf0 = { (short)f2b(pvv[0]),  (short)f2b(pvv[1]),  (short)f2b(pvv[2]),  (short)f2b(pvv[3]),   \
                   (short)f2b(pvv[4]),  (short)f2b(pvv[5]),  (short)f2b(pvv[6]),  (short)f2b(pvv[7]) }; \
    bf16x8 pf1 = { (short)f2b(pvv[8]),  (short)f2b(pvv[9]),  (short)f2b(pvv[10]), (short)f2b(pvv[11]),  \
                   (short)f2b(pvv[12]), (short)f2b(pvv[13]), (short)f2b(pvv[14]), (short)f2b(pvv[15]) };\
    OA = __builtin_amdgcn_mfma_f32_16x16x32_bf16(VF[0], pf0, OA, 0, 0, 0); \
    OA = __builtin_amdgcn_mfma_f32_16x16x32_bf16(VF[1], pf1, OA, 0, 0, 0); \
    OB = __builtin_amdgcn_mfma_f32_16x16x32_bf16(VF[2], pf0, OB, 0, 0, 0); \
    OB = __builtin_amdgcn_mfma_f32_16x16x32_bf16(VF[3], pf1, OB, 0, 0, 0); \
  }

#define ATTN_BODY(KF, VF, KN, VN, KV)                                      \
  {                                                                        \
    LOADFRAGS(KN, VN, (KV) + 64);                                          \
    QPASS(qf0, ls0, o00, o01, KF, VF);                                     \
    QPASS(qf1, ls1, o10, o11, KF, VF);                                     \
  }

__global__ __launch_bounds__(256) void attn_mfma(
    const ushort* __restrict__ qb,    // [4096][128] bf16, pre-scaled
    const ushort* __restrict__ kt,    // [4][256][16][32] bf16 tiles
    const ushort* __restrict__ vt,    // [4][128][2][16][32] bf16 tiles (kvperm'd)
    ushort* __restrict__ attnout)     // [4096][128] bf16
{
  int lane = threadIdx.x & 63;
  int w    = threadIdx.x >> 6;         // kv partition 0..3
  int head = blockIdx.x >> 7;
  int q0   = (blockIdx.x & 127) * 32;
  int ql = lane & 15;
  int g  = lane >> 4;
  const f32x4 z4 = {0.f, 0.f, 0.f, 0.f};
  int kvbase = w * 1024;

  bf16x8 qf0 = *(const bf16x8*)(qb + (size_t)(q0 + ql)*128      + head*32 + g*8);
  bf16x8 qf1 = *(const bf16x8*)(qb + (size_t)(q0 + 16 + ql)*128 + head*32 + g*8);
  const ushort* kptr = kt + (size_t)head*131072 + (size_t)kvbase*32 + ql*32 + g*8;
  const ushort* vptr = vt + (size_t)head*131072 + (size_t)kvbase*32 + ql*32 + g*8;

  float ls0 = 0.f, ls1 = 0.f;
  f32x4 o00 = z4, o01 = z4, o10 = z4, o11 = z4;

  bf16x8 kfA[4], vfA[4], kfB[4], vfB[4];
  LOADFRAGS(kfA, vfA, 0);
  for (int kv0 = 0; kv0 < 1024; kv0 += 128) {
    ATTN_BODY(kfA, vfA, kfB, vfB, kv0);
    ATTN_BODY(kfB, vfB, kfA, vfA, kv0 + 64);
  }

  ls0 += __shfl_xor(ls0, 16); ls0 += __shfl_xor(ls0, 32);
  ls1 += __shfl_xor(ls1, 16); ls1 += __shfl_xor(ls1, 32);

  __shared__ float so[4][32][36];
  __shared__ float sl[4][32];
  if (g == 0) { sl[w][ql] = ls0; sl[w][16 + ql] = ls1; }
  #pragma unroll
  for (int r = 0; r < 4; r++) {
    so[w][ql][g*4 + r]           = o00[r];
    so[w][ql][16 + g*4 + r]      = o01[r];
    so[w][16 + ql][g*4 + r]      = o10[r];
    so[w][16 + ql][16 + g*4 + r] = o11[r];
  }
  __syncthreads();
  int q  = threadIdx.x >> 3;         // 0..31
  int d0 = (threadIdx.x & 7) * 4;    // 0..28
  float L = 0.f, O0 = 0.f, O1 = 0.f, O2 = 0.f, O3 = 0.f;
  #pragma unroll
  for (int w2 = 0; w2 < 4; w2++) {
    L  += sl[w2][q];
    O0 += so[w2][q][d0];
    O1 += so[w2][q][d0+1];
    O2 += so[w2][q][d0+2];
    O3 += so[w2][q][d0+3];
  }
  float rl = 1.f / L;
  uint2 w2v; w2v.x = pk2(O0*rl, O1*rl); w2v.y = pk2(O2*rl, O3*rl);
  *(uint2*)(attnout + (size_t)(q0 + q)*128 + head*32 + d0) = w2v;
}

// ---------------------------------------------------------------------------
// decoder pairs: ABp [N][256] bf16 rows = [Ap | Bp]
// ---------------------------------------------------------------------------
__global__ __launch_bounds__(256) void pair_kernel(
    const ushort* __restrict__ ABp,
    const int* __restrict__ ps, const int* __restrict__ pd,
    const float* __restrict__ fc2w, const float* __restrict__ fc2b,
    float* __restrict__ out, int EP)
{
  int gw = (blockIdx.x * blockDim.x + threadIdx.x) >> 6;
  int lane = threadIdx.x & 63;
  int nw = (gridDim.x * blockDim.x) >> 6;
  float w0 = fc2w[2*lane], w1 = fc2w[2*lane + 1];
  float bb = fc2b[0];
  for (int p = gw; p < EP; p += nw) {
    int s = ps[p], d = pd[p];
    unsigned av = *(const unsigned*)(ABp + (size_t)s*256 + 2*lane);
    unsigned bv = *(const unsigned*)(ABp + (size_t)d*256 + 128 + 2*lane);
    float a0 = b2flo(av), a1 = b2fhi(av);
    float b0 = b2flo(bv), b1 = b2fhi(bv);
    float acc = fmaxf(a0 + b0, 0.f)*w0 + fmaxf(a1 + b1, 0.f)*w1;
    #pragma unroll
    for (int off = 32; off > 0; off >>= 1) acc += __shfl_down(acc, off);
    if (lane == 0) out[p] = 1.f / (1.f + __expf(-(acc + bb)));
  }
}

// ---------------------------------------------------------------------------
extern "C" void kernel_launch(void* const* d_in, const int* in_sizes, int n_in,
                              void* d_out, int out_size, void* d_ws, size_t ws_size,
                              hipStream_t stream)
{
  const float* features = (const float*)d_in[0];
  const int*   src      = (const int*)d_in[1];
  const int*   dst      = (const int*)d_in[2];
  const int*   psrc     = (const int*)d_in[3];
  const int*   pdst     = (const int*)d_in[4];
  const float* W1   = (const float*)d_in[5];
  const float* al1  = (const float*)d_in[6];
  const float* ar1  = (const float*)d_in[7];
  const float* b1   = (const float*)d_in[8];
  const float* W2   = (const float*)d_in[9];
  const float* al2  = (const float*)d_in[10];
  const float* ar2  = (const float*)d_in[11];
  const float* b2   = (const float*)d_in[12];
  const float* tw_qkv = (const float*)d_in[13];
  const float* tb_qkv = (const float*)d_in[14];
  const float* tw_o   = (const float*)d_in[15];
  const float* tb_o   = (const float*)d_in[16];
  const float* ln1_g  = (const float*)d_in[17];
  const float* ln1_b  = (const float*)d_in[18];
  const float* tw_ff1 = (const float*)d_in[19];
  const float* tb_ff1 = (const float*)d_in[20];
  const float* tw_ff2 = (const float*)d_in[21];
  const float* tb_ff2 = (const float*)d_in[22];
  const float* ln2_g  = (const float*)d_in[23];
  const float* ln2_b  = (const float*)d_in[24];
  const float* fc1_w  = (const float*)d_in[25];
  const float* fc1_b  = (const float*)d_in[26];
  const float* fc2_w  = (const float*)d_in[27];
  const float* fc2_b  = (const float*)d_in[28];
  int E  = in_sizes[1];
  int EP = in_sizes[3];

  float* ws = (float*)d_ws;
  size_t off = 0;
  auto alloc = [&](size_t n) { float* p = ws + off; off += n; return p; };
  ushort* hb    = (ushort*)alloc((size_t)NN * 64);    // [4096][128] bf16 state
  ushort* h1b   = (ushort*)alloc((size_t)NN * 256);   // [4096][512] bf16
  ushort* h2b   = (ushort*)alloc((size_t)NN * 256);   // [4096][512] bf16
  ushort* bigb  = (ushort*)alloc((size_t)NN * 256);   // [4096][512] bf16
  ushort* hgb   = (ushort*)alloc((size_t)NN * 64);    // [4096][128] bf16
  ushort* qb    = (ushort*)alloc((size_t)NN * 64);    // [4096][128] bf16
  ushort* attnb = (ushort*)alloc((size_t)NN * 64);    // [4096][128] bf16
  ushort* kt    = (ushort*)alloc((size_t)NN * 64);    // [4][256][16][32]
  ushort* vt    = (ushort*)alloc((size_t)NN * 64);    // [4][128][2][16][32]
  ushort* wbf   = (ushort*)alloc(622592/2);           // all weights bf16
  ushort* ABp   = (ushort*)alloc((size_t)NN * 128);   // [4096][256] bf16
  float*  bias256 = alloc(256);
  float*  el1   = alloc((size_t)NN * 4);
  float*  er1   = alloc((size_t)NN * 4);
  float*  el2   = alloc((size_t)NN);
  float*  er2   = alloc((size_t)NN);
  int* ibase    = (int*)(ws + off);
  int* deg      = ibase;
  int* rowstart = ibase + 4096;
  int* cursor   = rowstart + 4097;
  int* nbr      = cursor + 4096;

  // bf16 weight offsets
  const size_t oW1 = 0, oW2 = 131072, oQKV = 196608, oO = 294912,
               oFF1 = 327680, oFF2 = 458752, oFC1 = 589824;

  cvt_weights<<<609, 256, 0, stream>>>(W1, W2, tw_qkv, tw_o, tw_ff1, tw_ff2,
                                       fc1_w, fc1_b, wbf, bias256);

  // CSR build over dst (parallel count + scan + fill)
  zero_kernel<<<16, 256, 0, stream>>>(deg, 4096);
  count_kernel<<<(E + 255)/256, 256, 0, stream>>>(dst, deg, E);
  scan_kernel<<<1, 1024, 0, stream>>>(deg, rowstart, cursor);
  fill_kernel<<<(E + 255)/256, 256, 0, stream>>>(src, dst, cursor, nbr, E);

  // GAT layer 1
  gemm_mf<false,false,true,false><<<dim3(8, 64), 256, 0, stream>>>(
      features, wbf + oW1, nullptr, h1b, NN, 512, 256, 256);
  elr_kernel<4><<<1024, 256, 0, stream>>>(h1b, al1, ar1, el1, er1);
  gat_agg4<<<1024, 256, 0, stream>>>(h1b, el1, er1, rowstart, nbr, b1, h2b);

  // GAT layer 2
  gemm_mf<false,false,true,true><<<dim3(2, 64), 256, 0, stream>>>(
      h2b, wbf + oW2, nullptr, hgb, NN, 128, 512, 512);
  elr_kernel<1><<<1024, 256, 0, stream>>>(hgb, al2, ar2, el2, er2);
  gat_agg1<<<1024, 256, 0, stream>>>(hgb, el2, er2, rowstart, nbr, b2, hb);

  // Transformer encoder (2 layers)
  for (int l = 0; l < 2; l++) {
    gemm_qkv<<<dim3(6, 64), 256, 0, stream>>>(
        hb, wbf + oQKV + (size_t)l*49152, tb_qkv + l*384, qb, kt, vt);
    attn_mfma<<<512, 256, 0, stream>>>(qb, kt, vt, attnb);
    gemm_ln<<<256, 256, 0, stream>>>(
        attnb, wbf + oO + (size_t)l*16384, tb_o + l*128, hb,
        ln1_g + l*128, ln1_b + l*128, 128);
    gemm_mf<true,true,true,true><<<dim3(8, 64), 256, 0, stream>>>(
        hb, wbf + oFF1 + (size_t)l*65536, tb_ff1 + l*512, bigb, NN, 512, 128, 128);
    gemm_ln<<<256, 256, 0, stream>>>(
        bigb, wbf + oFF2 + (size_t)l*65536, tb_ff2 + l*128, hb,
        ln2_g + l*128, ln2_b + l*128, 512);
  }

  // Decoder: one N=256 gemm (re-packed fc1) -> [Ap|Bp] bf16, then pairs
  gemm_mf<true,false,true,true><<<dim3(4, 64), 256, 0, stream>>>(
      hb, wbf + oFC1, bias256, ABp, NN, 256, 128, 128);
  pair_kernel<<<1024, 256, 0, stream>>>(ABp, psrc, pdst, fc2_w, fc2_b, (float*)d_out, EP);
}

// Round 10
// 212.370 us; speedup vs baseline: 1.1402x; 1.0301x over previous
//
#include <hip/hip_runtime.h>
#include <hip/hip_bf16.h>
#include <math.h>

// Model constants (fixed by the reference)
#define NN   4096   // nodes
#define INC  256
#define HIDF 128
#define H1H  4
#define DM   128    // transformer d_model
#define THD  4      // transformer heads (head dim 32)
#define FFD  512

typedef __attribute__((ext_vector_type(8))) short bf16x8;
typedef __attribute__((ext_vector_type(4))) float f32x4;

__device__ __forceinline__ float leaky(float x){ return x > 0.f ? x : 0.2f*x; }

// fp32 -> bf16 bits via HW convert (RNE)
__device__ __forceinline__ ushort f2b(float f){
  __hip_bfloat16 h = __float2bfloat16(f);
  return __builtin_bit_cast(ushort, h);
}
__device__ __forceinline__ unsigned pk2(float a, float b){
  return (unsigned)f2b(a) | ((unsigned)f2b(b) << 16);
}
// bf16 bits -> fp32
__device__ __forceinline__ float b2f(unsigned u){ return __uint_as_float(u << 16); }
__device__ __forceinline__ float b2flo(unsigned u){ return __uint_as_float(u << 16); }
__device__ __forceinline__ float b2fhi(unsigned u){ return __uint_as_float(u & 0xffff0000u); }

// kv bit-permutation within 32-blocks: {b4,b3,b2,b1,b0} -> {b3,b2,b4,b1,b0}
__device__ __forceinline__ int kvperm(int kv){
  return (kv & ~31) | ((kv & 12) << 1) | ((kv >> 2) & 4) | (kv & 3);
}

// ---------------------------------------------------------------------------
// bf16 MFMA GEMM: C[M,N] = A[M,K] @ Wb[N,ldw](bf16)^T (+bias)(+relu)
// 64x64 tile, BK=64, 256 threads = 4 waves (2x2 of 32x32).
// ---------------------------------------------------------------------------
template<bool BIAS, bool RELU, bool OUTBF, bool ABF>
__global__ __launch_bounds__(256) void gemm_mf(
    const void* __restrict__ Av, const ushort* __restrict__ Wb,
    const float* __restrict__ bias, void* __restrict__ Cv,
    int M, int N, int K, int ldw)
{
  __shared__ uint4 As4[512];   // [ko 0..7][m 0..63] : 8 bf16 each
  __shared__ uint4 Bs4[512];
  int tid = threadIdx.x;
  int row0 = blockIdx.y * 64, col0 = blockIdx.x * 64;
  int wid = tid >> 6, lane = tid & 63;
  int wm = wid >> 1, wn = wid & 1;
  int ql = lane & 15, g = lane >> 4;
  const f32x4 z4 = {0.f,0.f,0.f,0.f};
  f32x4 acc[2][2] = {z4,z4,z4,z4};

  for (int k0 = 0; k0 < K; k0 += 64) {
    #pragma unroll
    for (int p = 0; p < 2; p++) {
      int idx = tid + p*256;         // 0..511
      int ko = idx & 7, mm = idx >> 3;
      if constexpr (ABF) {
        As4[ko*64 + mm] = *(const uint4*)((const ushort*)Av + (size_t)(row0 + mm)*K + k0 + ko*8);
      } else {
        const float* sa = (const float*)Av + (size_t)(row0 + mm)*K + k0 + ko*8;
        float4 a0 = *(const float4*)sa;
        float4 a1 = *(const float4*)(sa + 4);
        uint4 av;
        av.x = pk2(a0.x, a0.y); av.y = pk2(a0.z, a0.w);
        av.z = pk2(a1.x, a1.y); av.w = pk2(a1.z, a1.w);
        As4[ko*64 + mm] = av;
      }
      Bs4[ko*64 + mm] = *(const uint4*)(Wb + (size_t)(col0 + mm)*ldw + k0 + ko*8);
    }
    __syncthreads();
    #pragma unroll
    for (int kk = 0; kk < 2; kk++) {
      int ko = kk*4 + g;
      bf16x8 a0 = *((const bf16x8*)As4 + ko*64 + wm*32 + ql);
      bf16x8 a1 = *((const bf16x8*)As4 + ko*64 + wm*32 + 16 + ql);
      bf16x8 b0 = *((const bf16x8*)Bs4 + ko*64 + wn*32 + ql);
      bf16x8 b1 = *((const bf16x8*)Bs4 + ko*64 + wn*32 + 16 + ql);
      acc[0][0] = __builtin_amdgcn_mfma_f32_16x16x32_bf16(a0, b0, acc[0][0], 0,0,0);
      acc[0][1] = __builtin_amdgcn_mfma_f32_16x16x32_bf16(a0, b1, acc[0][1], 0,0,0);
      acc[1][0] = __builtin_amdgcn_mfma_f32_16x16x32_bf16(a1, b0, acc[1][0], 0,0,0);
      acc[1][1] = __builtin_amdgcn_mfma_f32_16x16x32_bf16(a1, b1, acc[1][1], 0,0,0);
    }
    __syncthreads();
  }
  float bvs[2] = {0.f, 0.f};
  if (BIAS) {
    bvs[0] = bias[col0 + wn*32 + ql];
    bvs[1] = bias[col0 + wn*32 + 16 + ql];
  }
  #pragma unroll
  for (int fm = 0; fm < 2; fm++)
    #pragma unroll
    for (int fn = 0; fn < 2; fn++) {
      int row = row0 + wm*32 + fm*16 + g*4;
      int col = col0 + wn*32 + fn*16 + ql;
      #pragma unroll
      for (int r = 0; r < 4; r++) {
        float v = acc[fm][fn][r];
        if (BIAS) v += bvs[fn];
        if (RELU) v = fmaxf(v, 0.f);
        if (OUTBF) ((ushort*)Cv)[(size_t)(row + r)*N + col] = f2b(v);
        else       ((float*)Cv)[(size_t)(row + r)*N + col] = v;
      }
    }
}

// ---------------------------------------------------------------------------
// qkv GEMM with fused Q-scale + K/V tile scatter.
// ---------------------------------------------------------------------------
__global__ __launch_bounds__(256) void gemm_qkv(
    const ushort* __restrict__ Ab, const ushort* __restrict__ Wb,
    const float* __restrict__ bias,
    ushort* __restrict__ qb, ushort* __restrict__ kt, ushort* __restrict__ vt)
{
  __shared__ uint4 As4[512];
  __shared__ uint4 Bs4[512];
  int tid = threadIdx.x;
  int row0 = blockIdx.y * 64, col0 = blockIdx.x * 64;
  int wid = tid >> 6, lane = tid & 63;
  int wm = wid >> 1, wn = wid & 1;
  int ql = lane & 15, g = lane >> 4;
  const f32x4 z4 = {0.f,0.f,0.f,0.f};
  f32x4 acc[2][2] = {z4,z4,z4,z4};

  for (int k0 = 0; k0 < 128; k0 += 64) {
    #pragma unroll
    for (int p = 0; p < 2; p++) {
      int idx = tid + p*256;
      int ko = idx & 7, mm = idx >> 3;
      As4[ko*64 + mm] = *(const uint4*)(Ab + (size_t)(row0 + mm)*128 + k0 + ko*8);
      Bs4[ko*64 + mm] = *(const uint4*)(Wb + (size_t)(col0 + mm)*128 + k0 + ko*8);
    }
    __syncthreads();
    #pragma unroll
    for (int kk = 0; kk < 2; kk++) {
      int ko = kk*4 + g;
      bf16x8 a0 = *((const bf16x8*)As4 + ko*64 + wm*32 + ql);
      bf16x8 a1 = *((const bf16x8*)As4 + ko*64 + wm*32 + 16 + ql);
      bf16x8 b0 = *((const bf16x8*)Bs4 + ko*64 + wn*32 + ql);
      bf16x8 b1 = *((const bf16x8*)Bs4 + ko*64 + wn*32 + 16 + ql);
      acc[0][0] = __builtin_amdgcn_mfma_f32_16x16x32_bf16(a0, b0, acc[0][0], 0,0,0);
      acc[0][1] = __builtin_amdgcn_mfma_f32_16x16x32_bf16(a0, b1, acc[0][1], 0,0,0);
      acc[1][0] = __builtin_amdgcn_mfma_f32_16x16x32_bf16(a1, b0, acc[1][0], 0,0,0);
      acc[1][1] = __builtin_amdgcn_mfma_f32_16x16x32_bf16(a1, b1, acc[1][1], 0,0,0);
    }
    __syncthreads();
  }
  float bvs[2];
  bvs[0] = bias[col0 + wn*32 + ql];
  bvs[1] = bias[col0 + wn*32 + 16 + ql];
  #pragma unroll
  for (int fm = 0; fm < 2; fm++)
    #pragma unroll
    for (int fn = 0; fn < 2; fn++) {
      int row = row0 + wm*32 + fm*16 + g*4;
      int col = col0 + wn*32 + fn*16 + ql;
      #pragma unroll
      for (int r = 0; r < 4; r++) {
        float v = acc[fm][fn][r] + bvs[fn];
        int kv = row + r;
        if (col < 128) {
          qb[(size_t)kv*128 + col] = f2b(v * 0.25505654708f);  // 1/sqrt(32)*log2e
        } else if (col < 256) {
          int hh = (col - 128) >> 5, d = (col - 128) & 31;
          kt[(size_t)hh*131072 + (size_t)kv*32 + d] = f2b(v);
        } else {
          int hh = (col - 256) >> 5, d = (col - 256) & 31;
          vt[(size_t)hh*131072 + (size_t)(kv >> 5)*1024 + (d >> 4)*512
             + (d & 15)*32 + kvperm(kv & 31)] = f2b(v);
        }
      }
    }
}

// ---------------------------------------------------------------------------
// Fused bf16 GEMM (N=128) + residual + LayerNorm, in-place on bf16 h.
// BM=16 rows/block -> grid 256. 4 waves, wave w = cols w*32..+31.
// ---------------------------------------------------------------------------
__global__ __launch_bounds__(256) void gemm_ln(
    const ushort* __restrict__ Ab, const ushort* __restrict__ Wb,
    const float* __restrict__ bias, ushort* __restrict__ h,
    const float* __restrict__ lng, const float* __restrict__ lnb, int K)
{
  __shared__ uint4 As4[128];    // [ko 0..7][m 0..15]
  __shared__ uint4 Bs4[1024];   // [ko 0..7][n 0..127]
  __shared__ float xs[16][132];
  int tid = threadIdx.x;
  int row0 = blockIdx.x * 16;
  int wv = tid >> 6, lane = tid & 63;
  int ql = lane & 15, g = lane >> 4;
  const f32x4 z4 = {0.f,0.f,0.f,0.f};
  f32x4 acc[2] = {z4, z4};

  for (int k0 = 0; k0 < K; k0 += 64) {
    if (tid < 128) {
      int ko = tid & 7, mm = tid >> 3;
      As4[ko*16 + mm] = *(const uint4*)(Ab + (size_t)(row0 + mm)*K + k0 + ko*8);
    }
    #pragma unroll
    for (int p = 0; p < 4; p++) {
      int idx = tid + p*256;     // 0..1023
      int ko = idx & 7, nn = idx >> 3;
      Bs4[ko*128 + nn] = *(const uint4*)(Wb + (size_t)nn*K + k0 + ko*8);
    }
    __syncthreads();
    #pragma unroll
    for (int kk = 0; kk < 2; kk++) {
      int ko = kk*4 + g;
      bf16x8 a = *((const bf16x8*)As4 + ko*16 + ql);
      #pragma unroll
      for (int fn = 0; fn < 2; fn++) {
        bf16x8 b = *((const bf16x8*)Bs4 + ko*128 + wv*32 + fn*16 + ql);
        acc[fn] = __builtin_amdgcn_mfma_f32_16x16x32_bf16(a, b, acc[fn], 0,0,0);
      }
    }
    __syncthreads();
  }
  // stage gemm+bias into LDS
  #pragma unroll
  for (int fn = 0; fn < 2; fn++) {
    int col = wv*32 + fn*16 + ql;
    float bv = bias[col];
    #pragma unroll
    for (int r = 0; r < 4; r++) xs[g*4 + r][col] = acc[fn][r] + bv;
  }
  __syncthreads();
  // residual + LN: 16 lanes per row, 8 cols each
  int rl = tid >> 4, cl = tid & 15, c0 = cl * 8;
  ushort* hrow = h + (size_t)(row0 + rl)*128;
  uint4 rv = *(const uint4*)(hrow + c0);
  float x[8];
  x[0] = xs[rl][c0+0] + b2flo(rv.x); x[1] = xs[rl][c0+1] + b2fhi(rv.x);
  x[2] = xs[rl][c0+2] + b2flo(rv.y); x[3] = xs[rl][c0+3] + b2fhi(rv.y);
  x[4] = xs[rl][c0+4] + b2flo(rv.z); x[5] = xs[rl][c0+5] + b2fhi(rv.z);
  x[6] = xs[rl][c0+6] + b2flo(rv.w); x[7] = xs[rl][c0+7] + b2fhi(rv.w);
  float s1 = 0.f, s2 = 0.f;
  #pragma unroll
  for (int i = 0; i < 8; i++) { s1 += x[i]; s2 += x[i]*x[i]; }
  #pragma unroll
  for (int st = 1; st < 16; st <<= 1) {
    s1 += __shfl_xor(s1, st); s2 += __shfl_xor(s2, st);
  }
  float mean = s1 * (1.f/128.f);
  float var  = s2 * (1.f/128.f) - mean*mean;
  float rstd = rsqrtf(var + 1e-5f);
  float o[8];
  #pragma unroll
  for (int i = 0; i < 8; i += 4) {
    float4 g4 = *(const float4*)(lng + c0 + i);
    float4 b4 = *(const float4*)(lnb + c0 + i);
    o[i+0] = (x[i+0]-mean)*rstd*g4.x + b4.x;
    o[i+1] = (x[i+1]-mean)*rstd*g4.y + b4.y;
    o[i+2] = (x[i+2]-mean)*rstd*g4.z + b4.z;
    o[i+3] = (x[i+3]-mean)*rstd*g4.w + b4.w;
  }
  uint4 ov; ov.x = pk2(o[0],o[1]); ov.y = pk2(o[2],o[3]);
  ov.z = pk2(o[4],o[5]); ov.w = pk2(o[6],o[7]);
  *(uint4*)(hrow + c0) = ov;
}

// ---------------------------------------------------------------------------
// one-shot weight fp32->bf16 conversion; fc1 re-packed to [256][128].
// ---------------------------------------------------------------------------
__global__ __launch_bounds__(256) void cvt_weights(
    const float* __restrict__ W1, const float* __restrict__ W2,
    const float* __restrict__ qkv, const float* __restrict__ o,
    const float* __restrict__ ff1, const float* __restrict__ ff2,
    const float* __restrict__ fc1, const float* __restrict__ fc1b,
    ushort* __restrict__ out, float* __restrict__ bias256)
{
  if (blockIdx.x == 608) {
    int t = threadIdx.x;
    bias256[t] = (t < 128) ? fc1b[t] : 0.f;
    return;
  }
  int i4 = (blockIdx.x*256 + threadIdx.x) * 4;
  const float* s; int loc;
  size_t dst = i4;
  if      (i4 < 131072) { s = W1;  loc = i4; }
  else if (i4 < 196608) { s = W2;  loc = i4 - 131072; }
  else if (i4 < 294912) { s = qkv; loc = i4 - 196608; }
  else if (i4 < 327680) { s = o;   loc = i4 - 294912; }
  else if (i4 < 458752) { s = ff1; loc = i4 - 327680; }
  else if (i4 < 589824) { s = ff2; loc = i4 - 458752; }
  else {
    s = fc1; loc = i4 - 589824;
    int j = loc >> 8, k2 = loc & 255;
    dst = 589824 + ((k2 >= 128) ? 16384 : 0) + j*128 + (k2 & 127);
  }
  float4 v = *(const float4*)(s + loc);
  uint2 w; w.x = pk2(v.x, v.y); w.y = pk2(v.z, v.w);
  *(uint2*)(out + dst) = w;
}

// ---------------------------------------------------------------------------
// features fp32 -> bf16 (one-shot)
// ---------------------------------------------------------------------------
__global__ __launch_bounds__(256) void cvt_feat(
    const float* __restrict__ f, ushort* __restrict__ o)
{
  int i = (blockIdx.x * 256 + threadIdx.x) * 4;
  float4 v = *(const float4*)(f + i);
  uint2 w; w.x = pk2(v.x, v.y); w.y = pk2(v.z, v.w);
  *(uint2*)(o + i) = w;
}

// ---------------------------------------------------------------------------
// CSR build over dst: parallel count (global atomics) + 1-block scan + fill
// ---------------------------------------------------------------------------
__global__ void count_kernel(const int* __restrict__ dst, int* __restrict__ deg, int E) {
  int e = blockIdx.x * blockDim.x + threadIdx.x;
  if (e < E) atomicAdd(&deg[dst[e]], 1);
}
__global__ __launch_bounds__(1024) void scan_kernel(
    const int* __restrict__ deg, int* __restrict__ rowstart, int* __restrict__ cursor)
{
  __shared__ int sdata[1024];
  int t = threadIdx.x;
  int base = t * 4;
  int v0 = deg[base], v1 = deg[base+1], v2 = deg[base+2], v3 = deg[base+3];
  int tot = v0 + v1 + v2 + v3;
  sdata[t] = tot;
  __syncthreads();
  for (int off = 1; off < 1024; off <<= 1) {
    int x = (t >= off) ? sdata[t - off] : 0;
    __syncthreads();
    sdata[t] += x;
    __syncthreads();
  }
  int run = sdata[t] - tot;  // exclusive
  rowstart[base]   = run; cursor[base]   = run; run += v0;
  rowstart[base+1] = run; cursor[base+1] = run; run += v1;
  rowstart[base+2] = run; cursor[base+2] = run; run += v2;
  rowstart[base+3] = run; cursor[base+3] = run; run += v3;
  if (t == 1023) rowstart[4096] = run;
}
__global__ void fill_kernel(const int* __restrict__ src, const int* __restrict__ dst,
                            int* __restrict__ cursor, int* __restrict__ nbr, int E) {
  int e = blockIdx.x * blockDim.x + threadIdx.x;
  if (e < E) {
    int p = atomicAdd(&cursor[dst[e]], 1);
    nbr[p] = src[e];
  }
}

// ---------------------------------------------------------------------------
// el/er attention coefficients (bf16 h input); one wave per node.
// ---------------------------------------------------------------------------
template<int H>
__global__ __launch_bounds__(256) void elr_kernel(
    const ushort* __restrict__ hmat, const float* __restrict__ al,
    const float* __restrict__ ar, float* __restrict__ el, float* __restrict__ er)
{
  int w = threadIdx.x >> 6, lane = threadIdx.x & 63;
  int n = blockIdx.x * 4 + w;
  if constexpr (H == 4) {
    int hh = lane >> 4, f0 = (lane & 15) * 8;
    bf16x8 hv = *(const bf16x8*)(hmat + (size_t)n*512 + hh*128 + f0);
    float4 a0 = *(const float4*)(al + hh*128 + f0);
    float4 a1 = *(const float4*)(al + hh*128 + f0 + 4);
    float4 r0 = *(const float4*)(ar + hh*128 + f0);
    float4 r1 = *(const float4*)(ar + hh*128 + f0 + 4);
    float x[8];
    #pragma unroll
    for (int i = 0; i < 8; i++) x[i] = b2f((ushort)hv[i]);
    float e1 = x[0]*a0.x + x[1]*a0.y + x[2]*a0.z + x[3]*a0.w
             + x[4]*a1.x + x[5]*a1.y + x[6]*a1.z + x[7]*a1.w;
    float e2 = x[0]*r0.x + x[1]*r0.y + x[2]*r0.z + x[3]*r0.w
             + x[4]*r1.x + x[5]*r1.y + x[6]*r1.z + x[7]*r1.w;
    #pragma unroll
    for (int s = 1; s < 16; s <<= 1) { e1 += __shfl_xor(e1, s); e2 += __shfl_xor(e2, s); }
    if ((lane & 15) == 0) { el[n*4 + hh] = e1; er[n*4 + hh] = e2; }
  } else {
    int f0 = lane * 2;
    unsigned u = *(const unsigned*)(hmat + (size_t)n*128 + f0);
    float x0 = b2flo(u), x1 = b2fhi(u);
    float2 av = *(const float2*)(al + f0);
    float2 rv = *(const float2*)(ar + f0);
    float e1 = x0*av.x + x1*av.y;
    float e2 = x0*rv.x + x1*rv.y;
    #pragma unroll
    for (int s = 1; s < 64; s <<= 1) { e1 += __shfl_xor(e1, s); e2 += __shfl_xor(e2, s); }
    if (lane == 0) { el[n] = e1; er[n] = e2; }
  }
}

// ---------------------------------------------------------------------------
// GAT aggregation H=4: one wave/node, no max tracking, single-pass deg<=256.
// ---------------------------------------------------------------------------
__global__ __launch_bounds__(256) void gat_agg4(
    const ushort* __restrict__ hsrc, const float* __restrict__ el, const float* __restrict__ er,
    const int* __restrict__ rowstart, const int* __restrict__ nbr,
    const float* __restrict__ bias, ushort* __restrict__ out)
{
  __shared__ float s_alpha[4][256][4];
  __shared__ int   s_nbr[4][256];
  int wv = threadIdx.x >> 6, lane = threadIdx.x & 63;
  int n = blockIdx.x * 4 + wv;
  int e0 = rowstart[n];
  int deg = rowstart[n+1] - e0;
  float4 ern = *(const float4*)(er + (size_t)n*4);
  int hh = lane >> 4;
  float acc[8] = {};
  if (deg > 0 && deg <= 256) {
    float se0=0.f, se1=0.f, se2=0.f, se3=0.f;
    for (int i = lane; i < deg; i += 64) {
      int s = nbr[e0 + i];
      s_nbr[wv][i] = s;
      float4 ev = *(const float4*)(el + (size_t)s*4);
      float p0 = __expf(leaky(ev.x + ern.x));
      float p1 = __expf(leaky(ev.y + ern.y));
      float p2 = __expf(leaky(ev.z + ern.z));
      float p3 = __expf(leaky(ev.w + ern.w));
      s_alpha[wv][i][0] = p0; s_alpha[wv][i][1] = p1;
      s_alpha[wv][i][2] = p2; s_alpha[wv][i][3] = p3;
      se0 += p0; se1 += p1; se2 += p2; se3 += p3;
    }
    #pragma unroll
    for (int st = 1; st < 64; st <<= 1) {
      se0 += __shfl_xor(se0, st); se1 += __shfl_xor(se1, st);
      se2 += __shfl_xor(se2, st); se3 += __shfl_xor(se3, st);
    }
    float si = 1.f / ((hh == 0) ? se0 : (hh == 1) ? se1 : (hh == 2) ? se2 : se3);
    #pragma unroll 4
    for (int i = 0; i < deg; i++) {
      float a = s_alpha[wv][i][hh] * si;
      int s = s_nbr[wv][i];
      uint4 hv = *(const uint4*)(hsrc + (size_t)s*512 + lane*8);
      acc[0] += a * b2flo(hv.x); acc[1] += a * b2fhi(hv.x);
      acc[2] += a * b2flo(hv.y); acc[3] += a * b2fhi(hv.y);
      acc[4] += a * b2flo(hv.z); acc[5] += a * b2fhi(hv.z);
      acc[6] += a * b2flo(hv.w); acc[7] += a * b2fhi(hv.w);
    }
  } else if (deg > 0) {
    float se0=0.f, se1=0.f, se2=0.f, se3=0.f;
    for (int i = lane; i < deg; i += 64) {
      int s = nbr[e0 + i];
      float4 ev = *(const float4*)(el + (size_t)s*4);
      se0 += __expf(leaky(ev.x + ern.x));
      se1 += __expf(leaky(ev.y + ern.y));
      se2 += __expf(leaky(ev.z + ern.z));
      se3 += __expf(leaky(ev.w + ern.w));
    }
    #pragma unroll
    for (int st = 1; st < 64; st <<= 1) {
      se0 += __shfl_xor(se0, st); se1 += __shfl_xor(se1, st);
      se2 += __shfl_xor(se2, st); se3 += __shfl_xor(se3, st);
    }
    float si0 = 1.f/se0, si1 = 1.f/se1, si2 = 1.f/se2, si3 = 1.f/se3;
    for (int c = 0; c < deg; c += 256) {
      int cn = min(256, deg - c);
      for (int i = lane; i < cn; i += 64) {
        int s = nbr[e0 + c + i];
        s_nbr[wv][i] = s;
        float4 ev = *(const float4*)(el + (size_t)s*4);
        s_alpha[wv][i][0] = __expf(leaky(ev.x + ern.x)) * si0;
        s_alpha[wv][i][1] = __expf(leaky(ev.y + ern.y)) * si1;
        s_alpha[wv][i][2] = __expf(leaky(ev.z + ern.z)) * si2;
        s_alpha[wv][i][3] = __expf(leaky(ev.w + ern.w)) * si3;
      }
      #pragma unroll 4
      for (int i = 0; i < cn; i++) {
        float a = s_alpha[wv][i][hh];
        int s = s_nbr[wv][i];
        uint4 hv = *(const uint4*)(hsrc + (size_t)s*512 + lane*8);
        acc[0] += a * b2flo(hv.x); acc[1] += a * b2fhi(hv.x);
        acc[2] += a * b2flo(hv.y); acc[3] += a * b2fhi(hv.y);
        acc[4] += a * b2flo(hv.z); acc[5] += a * b2fhi(hv.z);
        acc[6] += a * b2flo(hv.w); acc[7] += a * b2fhi(hv.w);
      }
    }
  }
  const float* bp = bias + lane*8;
  float4 b0 = *(const float4*)(bp);
  float4 b1 = *(const float4*)(bp + 4);
  float v0 = fmaxf(acc[0]+b0.x, 0.f), v1 = fmaxf(acc[1]+b0.y, 0.f);
  float v2 = fmaxf(acc[2]+b0.z, 0.f), v3 = fmaxf(acc[3]+b0.w, 0.f);
  float v4 = fmaxf(acc[4]+b1.x, 0.f), v5 = fmaxf(acc[5]+b1.y, 0.f);
  float v6 = fmaxf(acc[6]+b1.z, 0.f), v7 = fmaxf(acc[7]+b1.w, 0.f);
  uint4 ov; ov.x = pk2(v0,v1); ov.y = pk2(v2,v3); ov.z = pk2(v4,v5); ov.w = pk2(v6,v7);
  *(uint4*)(out + (size_t)n*512 + lane*8) = ov;
}

// ---------------------------------------------------------------------------
// GAT aggregation H=1: one wave/node, no max tracking, single-pass deg<=256.
// ---------------------------------------------------------------------------
__global__ __launch_bounds__(256) void gat_agg1(
    const ushort* __restrict__ hsrc, const float* __restrict__ el, const float* __restrict__ er,
    const int* __restrict__ rowstart, const int* __restrict__ nbr,
    const float* __restrict__ bias, ushort* __restrict__ out)
{
  __shared__ float s_alpha[4][256];
  __shared__ int   s_nbr[4][256];
  int wv = threadIdx.x >> 6, lane = threadIdx.x & 63;
  int n = blockIdx.x * 4 + wv;
  int e0 = rowstart[n];
  int deg = rowstart[n+1] - e0;
  float ern = er[n];
  float a0 = 0.f, a1 = 0.f;
  if (deg > 0 && deg <= 256) {
    float se = 0.f;
    for (int i = lane; i < deg; i += 64) {
      int s = nbr[e0 + i];
      s_nbr[wv][i] = s;
      float p = __expf(leaky(el[s] + ern));
      s_alpha[wv][i] = p;
      se += p;
    }
    #pragma unroll
    for (int st = 1; st < 64; st <<= 1) se += __shfl_xor(se, st);
    float si = 1.f / se;
    #pragma unroll 4
    for (int i = 0; i < deg; i++) {
      float a = s_alpha[wv][i] * si;
      int s = s_nbr[wv][i];
      unsigned u = *(const unsigned*)(hsrc + (size_t)s*128 + lane*2);
      a0 += a * b2flo(u);
      a1 += a * b2fhi(u);
    }
  } else if (deg > 0) {
    float se = 0.f;
    for (int i = lane; i < deg; i += 64)
      se += __expf(leaky(el[nbr[e0 + i]] + ern));
    #pragma unroll
    for (int st = 1; st < 64; st <<= 1) se += __shfl_xor(se, st);
    float si = 1.f / se;
    for (int c = 0; c < deg; c += 256) {
      int cn = min(256, deg - c);
      for (int i = lane; i < cn; i += 64) {
        int s = nbr[e0 + c + i];
        s_nbr[wv][i] = s;
        s_alpha[wv][i] = __expf(leaky(el[s] + ern)) * si;
      }
      #pragma unroll 4
      for (int i = 0; i < cn; i++) {
        float a = s_alpha[wv][i];
        int s = s_nbr[wv][i];
        unsigned u = *(const unsigned*)(hsrc + (size_t)s*128 + lane*2);
        a0 += a * b2flo(u);
        a1 += a * b2fhi(u);
      }
    }
  }
  float v0 = a0 + bias[lane*2], v1 = a1 + bias[lane*2 + 1];
  *(unsigned*)(out + (size_t)n*128 + lane*2) = pk2(v0, v1);
}

// ---------------------------------------------------------------------------
// MFMA flash attention: 8-way kv split, 512-thread blocks (4 waves/SIMD TLP).
// ---------------------------------------------------------------------------
#define LOADFRAGS(KF, VF, KV)                                              \
  {                                                                        \
    int _kv = (KV);                                                        \
    if (_kv < 512) {                                                       \
      const ushort* _kp = kptr + (size_t)_kv * 32;                         \
      const ushort* _vp = vptr + (size_t)_kv * 32;                         \
      KF[0] = *(const bf16x8*)(_kp);                                       \
      KF[1] = *(const bf16x8*)(_kp + 512);                                 \
      KF[2] = *(const bf16x8*)(_kp + 1024);                                \
      KF[3] = *(const bf16x8*)(_kp + 1536);                                \
      VF[0] = *(const bf16x8*)(_vp);                                       \
      VF[1] = *(const bf16x8*)(_vp + 1024);                                \
      VF[2] = *(const bf16x8*)(_vp + 512);                                 \
      VF[3] = *(const bf16x8*)(_vp + 1536);                                \
    }                                                                      \
  }

#define QPASS(QF, LS, OA, OB, KF, VF)                                      \
  {                                                                        \
    f32x4 st0 = __builtin_amdgcn_mfma_f32_16x16x32_bf16(KF[0], QF, z4, 0, 0, 0); \
    f32x4 st1 = __builtin_amdgcn_mfma_f32_16x16x32_bf16(KF[1], QF, z4, 0, 0, 0); \
    f32x4 st2 = __builtin_amdgcn_mfma_f32_16x16x32_bf16(KF[2], QF, z4, 0, 0, 0); \
    f32x4 st3 = __builtin_amdgcn_mfma_f32_16x16x32_bf16(KF[3], QF, z4, 0, 0, 0); \
    float pvv[16];                                                         \
    _Pragma("unroll")                                                      \
    for (int i = 0; i < 4; i++) {                                          \
      pvv[i] = st0[i]; pvv[4+i] = st1[i]; pvv[8+i] = st2[i]; pvv[12+i] = st3[i]; \
    }                                                                      \
    _Pragma("unroll")                                                      \
    for (int i = 0; i < 16; i++) { pvv[i] = exp2f(pvv[i]); LS += pvv[i]; } \
    bf16x8 pf0 = { (short)f2b(pvv[0]),  (short)f2b(pvv[1]),  (short)f2b(pvv[2]),  (short)f2b(pvv[3]),   \
                   (short)f2b(pvv[4]),  (short)f2b(pvv[5]),  (short)f2b(pvv[6]),  (short)f2b(pvv[7]) }; \
    bf16x8 pf1 = { (short)f2b(pvv[8]),  (short)f2b(pvv[9]),  (short)f2b(pvv[10]), (short)f2b(pvv[11]),  \
                   (short)f2b(pvv[12]), (short)f2b(pvv[13]), (short)f2b(pvv[14]), (short)f2b(pvv[15]) };\
    OA = __builtin_amdgcn_mfma_f32_16x16x32_bf16(VF[0], pf0, OA, 0, 0, 0); \
    OA = __builtin_amdgcn_mfma_f32_16x16x32_bf16(VF[1], pf1, OA, 0, 0, 0); \
    OB = __builtin_amdgcn_mfma_f32_16x16x32_bf16(VF[2], pf0, OB, 0, 0, 0); \
    OB = __builtin_amdgcn_mfma_f32_16x16x32_bf16(VF[3], pf1, OB, 0, 0, 0); \
  }

#define ATTN_BODY(KF, VF, KN, VN, KV)                                      \
  {                                                                        \
    LOADFRAGS(KN, VN, (KV) + 64);                                          \
    QPASS(qf0, ls0, o00, o01, KF, VF);                                     \
    QPASS(qf1, ls1, o10, o11, KF, VF);                                     \
  }

__global__ __launch_bounds__(512) void attn_mfma(
    const ushort* __restrict__ qb,    // [4096][128] bf16, pre-scaled
    const ushort* __restrict__ kt,    // [4][256][16][32] bf16 tiles
    const ushort* __restrict__ vt,    // [4][128][2][16][32] bf16 tiles (kvperm'd)
    ushort* __restrict__ attnout)     // [4096][128] bf16
{
  int lane = threadIdx.x & 63;
  int w    = threadIdx.x >> 6;         // kv partition 0..7
  int head = blockIdx.x >> 7;
  int q0   = (blockIdx.x & 127) * 32;
  int ql = lane & 15;
  int g  = lane >> 4;
  const f32x4 z4 = {0.f, 0.f, 0.f, 0.f};
  int kvbase = w * 512;

  bf16x8 qf0 = *(const bf16x8*)(qb + (size_t)(q0 + ql)*128      + head*32 + g*8);
  bf16x8 qf1 = *(const bf16x8*)(qb + (size_t)(q0 + 16 + ql)*128 + head*32 + g*8);
  const ushort* kptr = kt + (size_t)head*131072 + (size_t)kvbase*32 + ql*32 + g*8;
  const ushort* vptr = vt + (size_t)head*131072 + (size_t)kvbase*32 + ql*32 + g*8;

  float ls0 = 0.f, ls1 = 0.f;
  f32x4 o00 = z4, o01 = z4, o10 = z4, o11 = z4;

  bf16x8 kfA[4], vfA[4], kfB[4], vfB[4];
  LOADFRAGS(kfA, vfA, 0);
  for (int kv0 = 0; kv0 < 512; kv0 += 128) {
    ATTN_BODY(kfA, vfA, kfB, vfB, kv0);
    ATTN_BODY(kfB, vfB, kfA, vfA, kv0 + 64);
  }

  ls0 += __shfl_xor(ls0, 16); ls0 += __shfl_xor(ls0, 32);
  ls1 += __shfl_xor(ls1, 16); ls1 += __shfl_xor(ls1, 32);

  __shared__ float so[8][32][36];
  __shared__ float sl[8][32];
  if (g == 0) { sl[w][ql] = ls0; sl[w][16 + ql] = ls1; }
  #pragma unroll
  for (int r = 0; r < 4; r++) {
    so[w][ql][g*4 + r]           = o00[r];
    so[w][ql][16 + g*4 + r]      = o01[r];
    so[w][16 + ql][g*4 + r]      = o10[r];
    so[w][16 + ql][16 + g*4 + r] = o11[r];
  }
  __syncthreads();
  int q  = threadIdx.x >> 4;         // 0..31
  int d0 = (threadIdx.x & 15) * 2;   // 0..30
  float L = 0.f, O0 = 0.f, O1 = 0.f;
  #pragma unroll
  for (int w2 = 0; w2 < 8; w2++) {
    L  += sl[w2][q];
    O0 += so[w2][q][d0];
    O1 += so[w2][q][d0+1];
  }
  float rl = 1.f / L;
  *(unsigned*)(attnout + (size_t)(q0 + q)*128 + head*32 + d0) = pk2(O0*rl, O1*rl);
}

// ---------------------------------------------------------------------------
// decoder pairs: ABp [N][256] bf16 rows = [Ap | Bp]; 2 pairs per iteration.
// ---------------------------------------------------------------------------
__global__ __launch_bounds__(256) void pair_kernel(
    const ushort* __restrict__ ABp,
    const int* __restrict__ ps, const int* __restrict__ pd,
    const float* __restrict__ fc2w, const float* __restrict__ fc2b,
    float* __restrict__ out, int EP)
{
  int gw = (blockIdx.x * blockDim.x + threadIdx.x) >> 6;
  int lane = threadIdx.x & 63;
  int nw = (gridDim.x * blockDim.x) >> 6;
  float w0 = fc2w[2*lane], w1 = fc2w[2*lane + 1];
  float bb = fc2b[0];
  for (int p = gw*2; p < EP; p += nw*2) {
    int sA = ps[p], dA = pd[p];
    bool hasB = (p + 1 < EP);
    int sB = hasB ? ps[p+1] : sA;
    int dB = hasB ? pd[p+1] : dA;
    unsigned avA = *(const unsigned*)(ABp + (size_t)sA*256 + 2*lane);
    unsigned bvA = *(const unsigned*)(ABp + (size_t)dA*256 + 128 + 2*lane);
    unsigned avB = *(const unsigned*)(ABp + (size_t)sB*256 + 2*lane);
    unsigned bvB = *(const unsigned*)(ABp + (size_t)dB*256 + 128 + 2*lane);
    float accA = fmaxf(b2flo(avA) + b2flo(bvA), 0.f)*w0
               + fmaxf(b2fhi(avA) + b2fhi(bvA), 0.f)*w1;
    float accB = fmaxf(b2flo(avB) + b2flo(bvB), 0.f)*w0
               + fmaxf(b2fhi(avB) + b2fhi(bvB), 0.f)*w1;
    #pragma unroll
    for (int off = 32; off > 0; off >>= 1) {
      accA += __shfl_down(accA, off);
      accB += __shfl_down(accB, off);
    }
    if (lane == 0) {
      out[p] = 1.f / (1.f + __expf(-(accA + bb)));
      if (hasB) out[p+1] = 1.f / (1.f + __expf(-(accB + bb)));
    }
  }
}

// ---------------------------------------------------------------------------
extern "C" void kernel_launch(void* const* d_in, const int* in_sizes, int n_in,
                              void* d_out, int out_size, void* d_ws, size_t ws_size,
                              hipStream_t stream)
{
  const float* features = (const float*)d_in[0];
  const int*   src      = (const int*)d_in[1];
  const int*   dst      = (const int*)d_in[2];
  const int*   psrc     = (const int*)d_in[3];
  const int*   pdst     = (const int*)d_in[4];
  const float* W1   = (const float*)d_in[5];
  const float* al1  = (const float*)d_in[6];
  const float* ar1  = (const float*)d_in[7];
  const float* b1   = (const float*)d_in[8];
  const float* W2   = (const float*)d_in[9];
  const float* al2  = (const float*)d_in[10];
  const float* ar2  = (const float*)d_in[11];
  const float* b2   = (const float*)d_in[12];
  const float* tw_qkv = (const float*)d_in[13];
  const float* tb_qkv = (const float*)d_in[14];
  const float* tw_o   = (const float*)d_in[15];
  const float* tb_o   = (const float*)d_in[16];
  const float* ln1_g  = (const float*)d_in[17];
  const float* ln1_b  = (const float*)d_in[18];
  const float* tw_ff1 = (const float*)d_in[19];
  const float* tb_ff1 = (const float*)d_in[20];
  const float* tw_ff2 = (const float*)d_in[21];
  const float* tb_ff2 = (const float*)d_in[22];
  const float* ln2_g  = (const float*)d_in[23];
  const float* ln2_b  = (const float*)d_in[24];
  const float* fc1_w  = (const float*)d_in[25];
  const float* fc1_b  = (const float*)d_in[26];
  const float* fc2_w  = (const float*)d_in[27];
  const float* fc2_b  = (const float*)d_in[28];
  int E  = in_sizes[1];
  int EP = in_sizes[3];

  float* ws = (float*)d_ws;
  size_t off = 0;
  auto alloc = [&](size_t n) { float* p = ws + off; off += n; return p; };
  ushort* hb    = (ushort*)alloc((size_t)NN * 64);    // [4096][128] bf16 state
  ushort* featb = (ushort*)alloc((size_t)NN * 128);   // [4096][256] bf16
  ushort* h1b   = (ushort*)alloc((size_t)NN * 256);   // [4096][512] bf16
  ushort* h2b   = (ushort*)alloc((size_t)NN * 256);   // [4096][512] bf16
  ushort* bigb  = (ushort*)alloc((size_t)NN * 256);   // [4096][512] bf16
  ushort* hgb   = (ushort*)alloc((size_t)NN * 64);    // [4096][128] bf16
  ushort* qb    = (ushort*)alloc((size_t)NN * 64);    // [4096][128] bf16
  ushort* attnb = (ushort*)alloc((size_t)NN * 64);    // [4096][128] bf16
  ushort* kt    = (ushort*)alloc((size_t)NN * 64);    // [4][256][16][32]
  ushort* vt    = (ushort*)alloc((size_t)NN * 64);    // [4][128][2][16][32]
  ushort* wbf   = (ushort*)alloc(622592/2);           // all weights bf16
  ushort* ABp   = (ushort*)alloc((size_t)NN * 128);   // [4096][256] bf16
  float*  bias256 = alloc(256);
  float*  el1   = alloc((size_t)NN * 4);
  float*  er1   = alloc((size_t)NN * 4);
  float*  el2   = alloc((size_t)NN);
  float*  er2   = alloc((size_t)NN);
  int* ibase    = (int*)(ws + off);
  int* deg      = ibase;
  int* rowstart = ibase + 4096;
  int* cursor   = rowstart + 4097;
  int* nbr      = cursor + 4096;

  // bf16 weight offsets
  const size_t oW1 = 0, oW2 = 131072, oQKV = 196608, oO = 294912,
               oFF1 = 327680, oFF2 = 458752, oFC1 = 589824;

  cvt_weights<<<609, 256, 0, stream>>>(W1, W2, tw_qkv, tw_o, tw_ff1, tw_ff2,
                                       fc1_w, fc1_b, wbf, bias256);
  cvt_feat<<<1024, 256, 0, stream>>>(features, featb);

  // CSR build over dst (parallel count + scan + fill)
  hipMemsetAsync(deg, 0, 4096 * sizeof(int), stream);
  count_kernel<<<(E + 255)/256, 256, 0, stream>>>(dst, deg, E);
  scan_kernel<<<1, 1024, 0, stream>>>(deg, rowstart, cursor);
  fill_kernel<<<(E + 255)/256, 256, 0, stream>>>(src, dst, cursor, nbr, E);

  // GAT layer 1
  gemm_mf<false,false,true,true><<<dim3(8, 64), 256, 0, stream>>>(
      featb, wbf + oW1, nullptr, h1b, NN, 512, 256, 256);
  elr_kernel<4><<<1024, 256, 0, stream>>>(h1b, al1, ar1, el1, er1);
  gat_agg4<<<1024, 256, 0, stream>>>(h1b, el1, er1, rowstart, nbr, b1, h2b);

  // GAT layer 2
  gemm_mf<false,false,true,true><<<dim3(2, 64), 256, 0, stream>>>(
      h2b, wbf + oW2, nullptr, hgb, NN, 128, 512, 512);
  elr_kernel<1><<<1024, 256, 0, stream>>>(hgb, al2, ar2, el2, er2);
  gat_agg1<<<1024, 256, 0, stream>>>(hgb, el2, er2, rowstart, nbr, b2, hb);

  // Transformer encoder (2 layers)
  for (int l = 0; l < 2; l++) {
    gemm_qkv<<<dim3(6, 64), 256, 0, stream>>>(
        hb, wbf + oQKV + (size_t)l*49152, tb_qkv + l*384, qb, kt, vt);
    attn_mfma<<<512, 512, 0, stream>>>(qb, kt, vt, attnb);
    gemm_ln<<<256, 256, 0, stream>>>(
        attnb, wbf + oO + (size_t)l*16384, tb_o + l*128, hb,
        ln1_g + l*128, ln1_b + l*128, 128);
    gemm_mf<true,true,true,true><<<dim3(8, 64), 256, 0, stream>>>(
        hb, wbf + oFF1 + (size_t)l*65536, tb_ff1 + l*512, bigb, NN, 512, 128, 128);
    gemm_ln<<<256, 256, 0, stream>>>(
        bigb, wbf + oFF2 + (size_t)l*65536, tb_ff2 + l*128, hb,
        ln2_g + l*128, ln2_b + l*128, 512);
  }

  // Decoder: one N=256 gemm (re-packed fc1) -> [Ap|Bp] bf16, then pairs
  gemm_mf<true,false,true,true><<<dim3(4, 64), 256, 0, stream>>>(
      hb, wbf + oFC1, bias256, ABp, NN, 256, 128, 128);
  pair_kernel<<<1024, 256, 0, stream>>>(ABp, psrc, pdst, fc2_w, fc2_b, (float*)d_out, EP);
}

// Round 11
// 200.407 us; speedup vs baseline: 1.2083x; 1.0597x over previous
//
#include <hip/hip_runtime.h>
#include <hip/hip_bf16.h>
#include <math.h>

// Model constants (fixed by the reference)
#define NN   4096   // nodes
#define INC  256
#define HIDF 128
#define H1H  4
#define DM   128    // transformer d_model
#define THD  4      // transformer heads (head dim 32)
#define FFD  512

typedef __attribute__((ext_vector_type(8))) short bf16x8;
typedef __attribute__((ext_vector_type(4))) float f32x4;

__device__ __forceinline__ float leaky(float x){ return x > 0.f ? x : 0.2f*x; }

// fp32 -> bf16 bits via HW convert (RNE)
__device__ __forceinline__ ushort f2b(float f){
  __hip_bfloat16 h = __float2bfloat16(f);
  return __builtin_bit_cast(ushort, h);
}
__device__ __forceinline__ unsigned pk2(float a, float b){
  return (unsigned)f2b(a) | ((unsigned)f2b(b) << 16);
}
// bf16 bits -> fp32
__device__ __forceinline__ float b2f(unsigned u){ return __uint_as_float(u << 16); }
__device__ __forceinline__ float b2flo(unsigned u){ return __uint_as_float(u << 16); }
__device__ __forceinline__ float b2fhi(unsigned u){ return __uint_as_float(u & 0xffff0000u); }

// kv bit-permutation within 32-blocks: {b4,b3,b2,b1,b0} -> {b3,b2,b4,b1,b0}
__device__ __forceinline__ int kvperm(int kv){
  return (kv & ~31) | ((kv & 12) << 1) | ((kv >> 2) & 4) | (kv & 3);
}

// ---------------------------------------------------------------------------
// bf16 MFMA GEMM: C[M,N] = A[M,K] @ Wb[N,ldw](bf16)^T (+bias)(+relu)
// 64x64 tile, BK=64, 256 threads = 4 waves (2x2 of 32x32).
// ---------------------------------------------------------------------------
template<bool BIAS, bool RELU, bool OUTBF, bool ABF>
__global__ __launch_bounds__(256) void gemm_mf(
    const void* __restrict__ Av, const ushort* __restrict__ Wb,
    const float* __restrict__ bias, void* __restrict__ Cv,
    int M, int N, int K, int ldw)
{
  __shared__ uint4 As4[512];   // [ko 0..7][m 0..63] : 8 bf16 each
  __shared__ uint4 Bs4[512];
  int tid = threadIdx.x;
  int row0 = blockIdx.y * 64, col0 = blockIdx.x * 64;
  int wid = tid >> 6, lane = tid & 63;
  int wm = wid >> 1, wn = wid & 1;
  int ql = lane & 15, g = lane >> 4;
  const f32x4 z4 = {0.f,0.f,0.f,0.f};
  f32x4 acc[2][2] = {z4,z4,z4,z4};

  for (int k0 = 0; k0 < K; k0 += 64) {
    #pragma unroll
    for (int p = 0; p < 2; p++) {
      int idx = tid + p*256;         // 0..511
      int ko = idx & 7, mm = idx >> 3;
      if constexpr (ABF) {
        As4[ko*64 + mm] = *(const uint4*)((const ushort*)Av + (size_t)(row0 + mm)*K + k0 + ko*8);
      } else {
        const float* sa = (const float*)Av + (size_t)(row0 + mm)*K + k0 + ko*8;
        float4 a0 = *(const float4*)sa;
        float4 a1 = *(const float4*)(sa + 4);
        uint4 av;
        av.x = pk2(a0.x, a0.y); av.y = pk2(a0.z, a0.w);
        av.z = pk2(a1.x, a1.y); av.w = pk2(a1.z, a1.w);
        As4[ko*64 + mm] = av;
      }
      Bs4[ko*64 + mm] = *(const uint4*)(Wb + (size_t)(col0 + mm)*ldw + k0 + ko*8);
    }
    __syncthreads();
    #pragma unroll
    for (int kk = 0; kk < 2; kk++) {
      int ko = kk*4 + g;
      bf16x8 a0 = *((const bf16x8*)As4 + ko*64 + wm*32 + ql);
      bf16x8 a1 = *((const bf16x8*)As4 + ko*64 + wm*32 + 16 + ql);
      bf16x8 b0 = *((const bf16x8*)Bs4 + ko*64 + wn*32 + ql);
      bf16x8 b1 = *((const bf16x8*)Bs4 + ko*64 + wn*32 + 16 + ql);
      acc[0][0] = __builtin_amdgcn_mfma_f32_16x16x32_bf16(a0, b0, acc[0][0], 0,0,0);
      acc[0][1] = __builtin_amdgcn_mfma_f32_16x16x32_bf16(a0, b1, acc[0][1], 0,0,0);
      acc[1][0] = __builtin_amdgcn_mfma_f32_16x16x32_bf16(a1, b0, acc[1][0], 0,0,0);
      acc[1][1] = __builtin_amdgcn_mfma_f32_16x16x32_bf16(a1, b1, acc[1][1], 0,0,0);
    }
    __syncthreads();
  }
  float bvs[2] = {0.f, 0.f};
  if (BIAS) {
    bvs[0] = bias[col0 + wn*32 + ql];
    bvs[1] = bias[col0 + wn*32 + 16 + ql];
  }
  #pragma unroll
  for (int fm = 0; fm < 2; fm++)
    #pragma unroll
    for (int fn = 0; fn < 2; fn++) {
      int row = row0 + wm*32 + fm*16 + g*4;
      int col = col0 + wn*32 + fn*16 + ql;
      #pragma unroll
      for (int r = 0; r < 4; r++) {
        float v = acc[fm][fn][r];
        if (BIAS) v += bvs[fn];
        if (RELU) v = fmaxf(v, 0.f);
        if (OUTBF) ((ushort*)Cv)[(size_t)(row + r)*N + col] = f2b(v);
        else       ((float*)Cv)[(size_t)(row + r)*N + col] = v;
      }
    }
}

// ---------------------------------------------------------------------------
// qkv GEMM with fused Q-scale + K/V tile scatter.
// ---------------------------------------------------------------------------
__global__ __launch_bounds__(256) void gemm_qkv(
    const ushort* __restrict__ Ab, const ushort* __restrict__ Wb,
    const float* __restrict__ bias,
    ushort* __restrict__ qb, ushort* __restrict__ kt, ushort* __restrict__ vt)
{
  __shared__ uint4 As4[512];
  __shared__ uint4 Bs4[512];
  int tid = threadIdx.x;
  int row0 = blockIdx.y * 64, col0 = blockIdx.x * 64;
  int wid = tid >> 6, lane = tid & 63;
  int wm = wid >> 1, wn = wid & 1;
  int ql = lane & 15, g = lane >> 4;
  const f32x4 z4 = {0.f,0.f,0.f,0.f};
  f32x4 acc[2][2] = {z4,z4,z4,z4};

  for (int k0 = 0; k0 < 128; k0 += 64) {
    #pragma unroll
    for (int p = 0; p < 2; p++) {
      int idx = tid + p*256;
      int ko = idx & 7, mm = idx >> 3;
      As4[ko*64 + mm] = *(const uint4*)(Ab + (size_t)(row0 + mm)*128 + k0 + ko*8);
      Bs4[ko*64 + mm] = *(const uint4*)(Wb + (size_t)(col0 + mm)*128 + k0 + ko*8);
    }
    __syncthreads();
    #pragma unroll
    for (int kk = 0; kk < 2; kk++) {
      int ko = kk*4 + g;
      bf16x8 a0 = *((const bf16x8*)As4 + ko*64 + wm*32 + ql);
      bf16x8 a1 = *((const bf16x8*)As4 + ko*64 + wm*32 + 16 + ql);
      bf16x8 b0 = *((const bf16x8*)Bs4 + ko*64 + wn*32 + ql);
      bf16x8 b1 = *((const bf16x8*)Bs4 + ko*64 + wn*32 + 16 + ql);
      acc[0][0] = __builtin_amdgcn_mfma_f32_16x16x32_bf16(a0, b0, acc[0][0], 0,0,0);
      acc[0][1] = __builtin_amdgcn_mfma_f32_16x16x32_bf16(a0, b1, acc[0][1], 0,0,0);
      acc[1][0] = __builtin_amdgcn_mfma_f32_16x16x32_bf16(a1, b0, acc[1][0], 0,0,0);
      acc[1][1] = __builtin_amdgcn_mfma_f32_16x16x32_bf16(a1, b1, acc[1][1], 0,0,0);
    }
    __syncthreads();
  }
  float bvs[2];
  bvs[0] = bias[col0 + wn*32 + ql];
  bvs[1] = bias[col0 + wn*32 + 16 + ql];
  #pragma unroll
  for (int fm = 0; fm < 2; fm++)
    #pragma unroll
    for (int fn = 0; fn < 2; fn++) {
      int row = row0 + wm*32 + fm*16 + g*4;
      int col = col0 + wn*32 + fn*16 + ql;
      #pragma unroll
      for (int r = 0; r < 4; r++) {
        float v = acc[fm][fn][r] + bvs[fn];
        int kv = row + r;
        if (col < 128) {
          qb[(size_t)kv*128 + col] = f2b(v * 0.25505654708f);  // 1/sqrt(32)*log2e
        } else if (col < 256) {
          int hh = (col - 128) >> 5, d = (col - 128) & 31;
          kt[(size_t)hh*131072 + (size_t)kv*32 + d] = f2b(v);
        } else {
          int hh = (col - 256) >> 5, d = (col - 256) & 31;
          vt[(size_t)hh*131072 + (size_t)(kv >> 5)*1024 + (d >> 4)*512
             + (d & 15)*32 + kvperm(kv & 31)] = f2b(v);
        }
      }
    }
}

// ---------------------------------------------------------------------------
// Fused bf16 GEMM (N=128) + residual + LayerNorm, in-place on bf16 h.
// BM=16 rows/block -> grid 256. 4 waves, wave w = cols w*32..+31.
// ---------------------------------------------------------------------------
__global__ __launch_bounds__(256) void gemm_ln(
    const ushort* __restrict__ Ab, const ushort* __restrict__ Wb,
    const float* __restrict__ bias, ushort* __restrict__ h,
    const float* __restrict__ lng, const float* __restrict__ lnb, int K)
{
  __shared__ uint4 As4[128];    // [ko 0..7][m 0..15]
  __shared__ uint4 Bs4[1024];   // [ko 0..7][n 0..127]
  __shared__ float xs[16][132];
  int tid = threadIdx.x;
  int row0 = blockIdx.x * 16;
  int wv = tid >> 6, lane = tid & 63;
  int ql = lane & 15, g = lane >> 4;
  const f32x4 z4 = {0.f,0.f,0.f,0.f};
  f32x4 acc[2] = {z4, z4};

  for (int k0 = 0; k0 < K; k0 += 64) {
    if (tid < 128) {
      int ko = tid & 7, mm = tid >> 3;
      As4[ko*16 + mm] = *(const uint4*)(Ab + (size_t)(row0 + mm)*K + k0 + ko*8);
    }
    #pragma unroll
    for (int p = 0; p < 4; p++) {
      int idx = tid + p*256;     // 0..1023
      int ko = idx & 7, nn = idx >> 3;
      Bs4[ko*128 + nn] = *(const uint4*)(Wb + (size_t)nn*K + k0 + ko*8);
    }
    __syncthreads();
    #pragma unroll
    for (int kk = 0; kk < 2; kk++) {
      int ko = kk*4 + g;
      bf16x8 a = *((const bf16x8*)As4 + ko*16 + ql);
      #pragma unroll
      for (int fn = 0; fn < 2; fn++) {
        bf16x8 b = *((const bf16x8*)Bs4 + ko*128 + wv*32 + fn*16 + ql);
        acc[fn] = __builtin_amdgcn_mfma_f32_16x16x32_bf16(a, b, acc[fn], 0,0,0);
      }
    }
    __syncthreads();
  }
  // stage gemm+bias into LDS
  #pragma unroll
  for (int fn = 0; fn < 2; fn++) {
    int col = wv*32 + fn*16 + ql;
    float bv = bias[col];
    #pragma unroll
    for (int r = 0; r < 4; r++) xs[g*4 + r][col] = acc[fn][r] + bv;
  }
  __syncthreads();
  // residual + LN: 16 lanes per row, 8 cols each
  int rl = tid >> 4, cl = tid & 15, c0 = cl * 8;
  ushort* hrow = h + (size_t)(row0 + rl)*128;
  uint4 rv = *(const uint4*)(hrow + c0);
  float x[8];
  x[0] = xs[rl][c0+0] + b2flo(rv.x); x[1] = xs[rl][c0+1] + b2fhi(rv.x);
  x[2] = xs[rl][c0+2] + b2flo(rv.y); x[3] = xs[rl][c0+3] + b2fhi(rv.y);
  x[4] = xs[rl][c0+4] + b2flo(rv.z); x[5] = xs[rl][c0+5] + b2fhi(rv.z);
  x[6] = xs[rl][c0+6] + b2flo(rv.w); x[7] = xs[rl][c0+7] + b2fhi(rv.w);
  float s1 = 0.f, s2 = 0.f;
  #pragma unroll
  for (int i = 0; i < 8; i++) { s1 += x[i]; s2 += x[i]*x[i]; }
  #pragma unroll
  for (int st = 1; st < 16; st <<= 1) {
    s1 += __shfl_xor(s1, st); s2 += __shfl_xor(s2, st);
  }
  float mean = s1 * (1.f/128.f);
  float var  = s2 * (1.f/128.f) - mean*mean;
  float rstd = rsqrtf(var + 1e-5f);
  float o[8];
  #pragma unroll
  for (int i = 0; i < 8; i += 4) {
    float4 g4 = *(const float4*)(lng + c0 + i);
    float4 b4 = *(const float4*)(lnb + c0 + i);
    o[i+0] = (x[i+0]-mean)*rstd*g4.x + b4.x;
    o[i+1] = (x[i+1]-mean)*rstd*g4.y + b4.y;
    o[i+2] = (x[i+2]-mean)*rstd*g4.z + b4.z;
    o[i+3] = (x[i+3]-mean)*rstd*g4.w + b4.w;
  }
  uint4 ov; ov.x = pk2(o[0],o[1]); ov.y = pk2(o[2],o[3]);
  ov.z = pk2(o[4],o[5]); ov.w = pk2(o[6],o[7]);
  *(uint4*)(hrow + c0) = ov;
}

// ---------------------------------------------------------------------------
// GAT2 GEMM (N=128 full-width per block) + fused el2/er2 epilogue.
// hg = h2b @ W2^T (no bias); el2[n] = hg[n]·al2, er2[n] = hg[n]·ar2.
// BM=16 rows/block -> grid 256.
// ---------------------------------------------------------------------------
__global__ __launch_bounds__(256) void gemm_hg_elr(
    const ushort* __restrict__ Ab, const ushort* __restrict__ Wb,
    const float* __restrict__ al, const float* __restrict__ ar,
    ushort* __restrict__ hg, float* __restrict__ el, float* __restrict__ er)
{
  __shared__ uint4 As4[128];    // [ko 0..7][m 0..15]
  __shared__ uint4 Bs4[1024];   // [ko 0..7][n 0..127]
  __shared__ float xs[16][132];
  int tid = threadIdx.x;
  int row0 = blockIdx.x * 16;
  int wv = tid >> 6, lane = tid & 63;
  int ql = lane & 15, g = lane >> 4;
  const f32x4 z4 = {0.f,0.f,0.f,0.f};
  f32x4 acc[2] = {z4, z4};

  for (int k0 = 0; k0 < 512; k0 += 64) {
    if (tid < 128) {
      int ko = tid & 7, mm = tid >> 3;
      As4[ko*16 + mm] = *(const uint4*)(Ab + (size_t)(row0 + mm)*512 + k0 + ko*8);
    }
    #pragma unroll
    for (int p = 0; p < 4; p++) {
      int idx = tid + p*256;
      int ko = idx & 7, nn = idx >> 3;
      Bs4[ko*128 + nn] = *(const uint4*)(Wb + (size_t)nn*512 + k0 + ko*8);
    }
    __syncthreads();
    #pragma unroll
    for (int kk = 0; kk < 2; kk++) {
      int ko = kk*4 + g;
      bf16x8 a = *((const bf16x8*)As4 + ko*16 + ql);
      #pragma unroll
      for (int fn = 0; fn < 2; fn++) {
        bf16x8 b = *((const bf16x8*)Bs4 + ko*128 + wv*32 + fn*16 + ql);
        acc[fn] = __builtin_amdgcn_mfma_f32_16x16x32_bf16(a, b, acc[fn], 0,0,0);
      }
    }
    __syncthreads();
  }
  #pragma unroll
  for (int fn = 0; fn < 2; fn++) {
    int col = wv*32 + fn*16 + ql;
    #pragma unroll
    for (int r = 0; r < 4; r++) xs[g*4 + r][col] = acc[fn][r];
  }
  __syncthreads();
  // epilogue: write hg bf16 + reduce el/er per row (16 lanes/row, 8 cols each)
  int rl = tid >> 4, cl = tid & 15, c0 = cl * 8;
  float e1 = 0.f, e2 = 0.f;
  float x[8];
  #pragma unroll
  for (int i = 0; i < 8; i += 4) {
    float4 a4 = *(const float4*)(al + c0 + i);
    float4 r4 = *(const float4*)(ar + c0 + i);
    x[i+0] = xs[rl][c0+i+0]; x[i+1] = xs[rl][c0+i+1];
    x[i+2] = xs[rl][c0+i+2]; x[i+3] = xs[rl][c0+i+3];
    e1 += x[i+0]*a4.x + x[i+1]*a4.y + x[i+2]*a4.z + x[i+3]*a4.w;
    e2 += x[i+0]*r4.x + x[i+1]*r4.y + x[i+2]*r4.z + x[i+3]*r4.w;
  }
  uint4 ov; ov.x = pk2(x[0],x[1]); ov.y = pk2(x[2],x[3]);
  ov.z = pk2(x[4],x[5]); ov.w = pk2(x[6],x[7]);
  *(uint4*)(hg + (size_t)(row0 + rl)*128 + c0) = ov;
  #pragma unroll
  for (int st = 1; st < 16; st <<= 1) {
    e1 += __shfl_xor(e1, st); e2 += __shfl_xor(e2, st);
  }
  if (cl == 0) { el[row0 + rl] = e1; er[row0 + rl] = e2; }
}

// ---------------------------------------------------------------------------
// one-shot conversion: weights (blocks 0..607), bias256 (608),
// features fp32->bf16 (blocks 609..1632). fc1 re-packed to [256][128].
// ---------------------------------------------------------------------------
__global__ __launch_bounds__(256) void cvt_all(
    const float* __restrict__ W1, const float* __restrict__ W2,
    const float* __restrict__ qkv, const float* __restrict__ o,
    const float* __restrict__ ff1, const float* __restrict__ ff2,
    const float* __restrict__ fc1, const float* __restrict__ fc1b,
    const float* __restrict__ feat,
    ushort* __restrict__ out, float* __restrict__ bias256,
    ushort* __restrict__ featb)
{
  int b = blockIdx.x;
  if (b == 608) {
    int t = threadIdx.x;
    bias256[t] = (t < 128) ? fc1b[t] : 0.f;
    return;
  }
  if (b >= 609) {
    int i = ((b - 609)*256 + threadIdx.x) * 4;
    float4 v = *(const float4*)(feat + i);
    uint2 w; w.x = pk2(v.x, v.y); w.y = pk2(v.z, v.w);
    *(uint2*)(featb + i) = w;
    return;
  }
  int i4 = (b*256 + threadIdx.x) * 4;
  const float* s; int loc;
  size_t dst = i4;
  if      (i4 < 131072) { s = W1;  loc = i4; }
  else if (i4 < 196608) { s = W2;  loc = i4 - 131072; }
  else if (i4 < 294912) { s = qkv; loc = i4 - 196608; }
  else if (i4 < 327680) { s = o;   loc = i4 - 294912; }
  else if (i4 < 458752) { s = ff1; loc = i4 - 327680; }
  else if (i4 < 589824) { s = ff2; loc = i4 - 458752; }
  else {
    s = fc1; loc = i4 - 589824;
    int j = loc >> 8, k2 = loc & 255;
    dst = 589824 + ((k2 >= 128) ? 16384 : 0) + j*128 + (k2 & 127);
  }
  float4 v = *(const float4*)(s + loc);
  uint2 w; w.x = pk2(v.x, v.y); w.y = pk2(v.z, v.w);
  *(uint2*)(out + dst) = w;
}

// ---------------------------------------------------------------------------
// CSR build over dst: parallel count (global atomics) + 1-block scan + fill
// ---------------------------------------------------------------------------
__global__ void count_kernel(const int* __restrict__ dst, int* __restrict__ deg, int E) {
  int e = blockIdx.x * blockDim.x + threadIdx.x;
  if (e < E) atomicAdd(&deg[dst[e]], 1);
}
__global__ __launch_bounds__(1024) void scan_kernel(
    const int* __restrict__ deg, int* __restrict__ rowstart, int* __restrict__ cursor)
{
  __shared__ int sdata[1024];
  int t = threadIdx.x;
  int base = t * 4;
  int v0 = deg[base], v1 = deg[base+1], v2 = deg[base+2], v3 = deg[base+3];
  int tot = v0 + v1 + v2 + v3;
  sdata[t] = tot;
  __syncthreads();
  for (int off = 1; off < 1024; off <<= 1) {
    int x = (t >= off) ? sdata[t - off] : 0;
    __syncthreads();
    sdata[t] += x;
    __syncthreads();
  }
  int run = sdata[t] - tot;  // exclusive
  rowstart[base]   = run; cursor[base]   = run; run += v0;
  rowstart[base+1] = run; cursor[base+1] = run; run += v1;
  rowstart[base+2] = run; cursor[base+2] = run; run += v2;
  rowstart[base+3] = run; cursor[base+3] = run; run += v3;
  if (t == 1023) rowstart[4096] = run;
}
__global__ void fill_kernel(const int* __restrict__ src, const int* __restrict__ dst,
                            int* __restrict__ cursor, int* __restrict__ nbr, int E) {
  int e = blockIdx.x * blockDim.x + threadIdx.x;
  if (e < E) {
    int p = atomicAdd(&cursor[dst[e]], 1);
    nbr[p] = src[e];
  }
}

// ---------------------------------------------------------------------------
// el/er attention coefficients for GAT1 (H=4, bf16 h input); one wave/node.
// ---------------------------------------------------------------------------
__global__ __launch_bounds__(256) void elr4_kernel(
    const ushort* __restrict__ hmat, const float* __restrict__ al,
    const float* __restrict__ ar, float* __restrict__ el, float* __restrict__ er)
{
  int w = threadIdx.x >> 6, lane = threadIdx.x & 63;
  int n = blockIdx.x * 4 + w;
  int hh = lane >> 4, f0 = (lane & 15) * 8;
  bf16x8 hv = *(const bf16x8*)(hmat + (size_t)n*512 + hh*128 + f0);
  float4 a0 = *(const float4*)(al + hh*128 + f0);
  float4 a1 = *(const float4*)(al + hh*128 + f0 + 4);
  float4 r0 = *(const float4*)(ar + hh*128 + f0);
  float4 r1 = *(const float4*)(ar + hh*128 + f0 + 4);
  float x[8];
  #pragma unroll
  for (int i = 0; i < 8; i++) x[i] = b2f((ushort)hv[i]);
  float e1 = x[0]*a0.x + x[1]*a0.y + x[2]*a0.z + x[3]*a0.w
           + x[4]*a1.x + x[5]*a1.y + x[6]*a1.z + x[7]*a1.w;
  float e2 = x[0]*r0.x + x[1]*r0.y + x[2]*r0.z + x[3]*r0.w
           + x[4]*r1.x + x[5]*r1.y + x[6]*r1.z + x[7]*r1.w;
  #pragma unroll
  for (int s = 1; s < 16; s <<= 1) { e1 += __shfl_xor(e1, s); e2 += __shfl_xor(e2, s); }
  if ((lane & 15) == 0) { el[n*4 + hh] = e1; er[n*4 + hh] = e2; }
}

// ---------------------------------------------------------------------------
// GAT aggregation H=4: one wave/node, no max tracking, single-pass deg<=256.
// ---------------------------------------------------------------------------
__global__ __launch_bounds__(256) void gat_agg4(
    const ushort* __restrict__ hsrc, const float* __restrict__ el, const float* __restrict__ er,
    const int* __restrict__ rowstart, const int* __restrict__ nbr,
    const float* __restrict__ bias, ushort* __restrict__ out)
{
  __shared__ float s_alpha[4][256][4];
  __shared__ int   s_nbr[4][256];
  int wv = threadIdx.x >> 6, lane = threadIdx.x & 63;
  int n = blockIdx.x * 4 + wv;
  int e0 = rowstart[n];
  int deg = rowstart[n+1] - e0;
  float4 ern = *(const float4*)(er + (size_t)n*4);
  int hh = lane >> 4;
  float acc[8] = {};
  if (deg > 0 && deg <= 256) {
    float se0=0.f, se1=0.f, se2=0.f, se3=0.f;
    for (int i = lane; i < deg; i += 64) {
      int s = nbr[e0 + i];
      s_nbr[wv][i] = s;
      float4 ev = *(const float4*)(el + (size_t)s*4);
      float p0 = __expf(leaky(ev.x + ern.x));
      float p1 = __expf(leaky(ev.y + ern.y));
      float p2 = __expf(leaky(ev.z + ern.z));
      float p3 = __expf(leaky(ev.w + ern.w));
      s_alpha[wv][i][0] = p0; s_alpha[wv][i][1] = p1;
      s_alpha[wv][i][2] = p2; s_alpha[wv][i][3] = p3;
      se0 += p0; se1 += p1; se2 += p2; se3 += p3;
    }
    #pragma unroll
    for (int st = 1; st < 64; st <<= 1) {
      se0 += __shfl_xor(se0, st); se1 += __shfl_xor(se1, st);
      se2 += __shfl_xor(se2, st); se3 += __shfl_xor(se3, st);
    }
    float si = 1.f / ((hh == 0) ? se0 : (hh == 1) ? se1 : (hh == 2) ? se2 : se3);
    #pragma unroll 4
    for (int i = 0; i < deg; i++) {
      float a = s_alpha[wv][i][hh] * si;
      int s = s_nbr[wv][i];
      uint4 hv = *(const uint4*)(hsrc + (size_t)s*512 + lane*8);
      acc[0] += a * b2flo(hv.x); acc[1] += a * b2fhi(hv.x);
      acc[2] += a * b2flo(hv.y); acc[3] += a * b2fhi(hv.y);
      acc[4] += a * b2flo(hv.z); acc[5] += a * b2fhi(hv.z);
      acc[6] += a * b2flo(hv.w); acc[7] += a * b2fhi(hv.w);
    }
  } else if (deg > 0) {
    float se0=0.f, se1=0.f, se2=0.f, se3=0.f;
    for (int i = lane; i < deg; i += 64) {
      int s = nbr[e0 + i];
      float4 ev = *(const float4*)(el + (size_t)s*4);
      se0 += __expf(leaky(ev.x + ern.x));
      se1 += __expf(leaky(ev.y + ern.y));
      se2 += __expf(leaky(ev.z + ern.z));
      se3 += __expf(leaky(ev.w + ern.w));
    }
    #pragma unroll
    for (int st = 1; st < 64; st <<= 1) {
      se0 += __shfl_xor(se0, st); se1 += __shfl_xor(se1, st);
      se2 += __shfl_xor(se2, st); se3 += __shfl_xor(se3, st);
    }
    float si0 = 1.f/se0, si1 = 1.f/se1, si2 = 1.f/se2, si3 = 1.f/se3;
    for (int c = 0; c < deg; c += 256) {
      int cn = min(256, deg - c);
      for (int i = lane; i < cn; i += 64) {
        int s = nbr[e0 + c + i];
        s_nbr[wv][i] = s;
        float4 ev = *(const float4*)(el + (size_t)s*4);
        s_alpha[wv][i][0] = __expf(leaky(ev.x + ern.x)) * si0;
        s_alpha[wv][i][1] = __expf(leaky(ev.y + ern.y)) * si1;
        s_alpha[wv][i][2] = __expf(leaky(ev.z + ern.z)) * si2;
        s_alpha[wv][i][3] = __expf(leaky(ev.w + ern.w)) * si3;
      }
      #pragma unroll 4
      for (int i = 0; i < cn; i++) {
        float a = s_alpha[wv][i][hh];
        int s = s_nbr[wv][i];
        uint4 hv = *(const uint4*)(hsrc + (size_t)s*512 + lane*8);
        acc[0] += a * b2flo(hv.x); acc[1] += a * b2fhi(hv.x);
        acc[2] += a * b2flo(hv.y); acc[3] += a * b2fhi(hv.y);
        acc[4] += a * b2flo(hv.z); acc[5] += a * b2fhi(hv.z);
        acc[6] += a * b2flo(hv.w); acc[7] += a * b2fhi(hv.w);
      }
    }
  }
  const float* bp = bias + lane*8;
  float4 b0 = *(const float4*)(bp);
  float4 b1 = *(const float4*)(bp + 4);
  float v0 = fmaxf(acc[0]+b0.x, 0.f), v1 = fmaxf(acc[1]+b0.y, 0.f);
  float v2 = fmaxf(acc[2]+b0.z, 0.f), v3 = fmaxf(acc[3]+b0.w, 0.f);
  float v4 = fmaxf(acc[4]+b1.x, 0.f), v5 = fmaxf(acc[5]+b1.y, 0.f);
  float v6 = fmaxf(acc[6]+b1.z, 0.f), v7 = fmaxf(acc[7]+b1.w, 0.f);
  uint4 ov; ov.x = pk2(v0,v1); ov.y = pk2(v2,v3); ov.z = pk2(v4,v5); ov.w = pk2(v6,v7);
  *(uint4*)(out + (size_t)n*512 + lane*8) = ov;
}

// ---------------------------------------------------------------------------
// GAT aggregation H=1: one wave/node, no max tracking, single-pass deg<=256.
// ---------------------------------------------------------------------------
__global__ __launch_bounds__(256) void gat_agg1(
    const ushort* __restrict__ hsrc, const float* __restrict__ el, const float* __restrict__ er,
    const int* __restrict__ rowstart, const int* __restrict__ nbr,
    const float* __restrict__ bias, ushort* __restrict__ out)
{
  __shared__ float s_alpha[4][256];
  __shared__ int   s_nbr[4][256];
  int wv = threadIdx.x >> 6, lane = threadIdx.x & 63;
  int n = blockIdx.x * 4 + wv;
  int e0 = rowstart[n];
  int deg = rowstart[n+1] - e0;
  float ern = er[n];
  float a0 = 0.f, a1 = 0.f;
  if (deg > 0 && deg <= 256) {
    float se = 0.f;
    for (int i = lane; i < deg; i += 64) {
      int s = nbr[e0 + i];
      s_nbr[wv][i] = s;
      float p = __expf(leaky(el[s] + ern));
      s_alpha[wv][i] = p;
      se += p;
    }
    #pragma unroll
    for (int st = 1; st < 64; st <<= 1) se += __shfl_xor(se, st);
    float si = 1.f / se;
    #pragma unroll 4
    for (int i = 0; i < deg; i++) {
      float a = s_alpha[wv][i] * si;
      int s = s_nbr[wv][i];
      unsigned u = *(const unsigned*)(hsrc + (size_t)s*128 + lane*2);
      a0 += a * b2flo(u);
      a1 += a * b2fhi(u);
    }
  } else if (deg > 0) {
    float se = 0.f;
    for (int i = lane; i < deg; i += 64)
      se += __expf(leaky(el[nbr[e0 + i]] + ern));
    #pragma unroll
    for (int st = 1; st < 64; st <<= 1) se += __shfl_xor(se, st);
    float si = 1.f / se;
    for (int c = 0; c < deg; c += 256) {
      int cn = min(256, deg - c);
      for (int i = lane; i < cn; i += 64) {
        int s = nbr[e0 + c + i];
        s_nbr[wv][i] = s;
        s_alpha[wv][i] = __expf(leaky(el[s] + ern)) * si;
      }
      #pragma unroll 4
      for (int i = 0; i < cn; i++) {
        float a = s_alpha[wv][i];
        int s = s_nbr[wv][i];
        unsigned u = *(const unsigned*)(hsrc + (size_t)s*128 + lane*2);
        a0 += a * b2flo(u);
        a1 += a * b2fhi(u);
      }
    }
  }
  float v0 = a0 + bias[lane*2], v1 = a1 + bias[lane*2 + 1];
  *(unsigned*)(out + (size_t)n*128 + lane*2) = pk2(v0, v1);
}

// ---------------------------------------------------------------------------
// MFMA flash attention: 8-way kv split, 512-thread blocks (4 waves/SIMD TLP).
// ---------------------------------------------------------------------------
#define LOADFRAGS(KF, VF, KV)                                              \
  {                                                                        \
    int _kv = (KV);                                                        \
    if (_kv < 512) {                                                       \
      const ushort* _kp = kptr + (size_t)_kv * 32;                         \
      const ushort* _vp = vptr + (size_t)_kv * 32;                         \
      KF[0] = *(const bf16x8*)(_kp);                                       \
      KF[1] = *(const bf16x8*)(_kp + 512);                                 \
      KF[2] = *(const bf16x8*)(_kp + 1024);                                \
      KF[3] = *(const bf16x8*)(_kp + 1536);                                \
      VF[0] = *(const bf16x8*)(_vp);                                       \
      VF[1] = *(const bf16x8*)(_vp + 1024);                                \
      VF[2] = *(const bf16x8*)(_vp + 512);                                 \
      VF[3] = *(const bf16x8*)(_vp + 1536);                                \
    }                                                                      \
  }

#define QPASS(QF, LS, OA, OB, KF, VF)                                      \
  {                                                                        \
    f32x4 st0 = __builtin_amdgcn_mfma_f32_16x16x32_bf16(KF[0], QF, z4, 0, 0, 0); \
    f32x4 st1 = __builtin_amdgcn_mfma_f32_16x16x32_bf16(KF[1], QF, z4, 0, 0, 0); \
    f32x4 st2 = __builtin_amdgcn_mfma_f32_16x16x32_bf16(KF[2], QF, z4, 0, 0, 0); \
    f32x4 st3 = __builtin_amdgcn_mfma_f32_16x16x32_bf16(KF[3], QF, z4, 0, 0, 0); \
    float pvv[16];                                                         \
    _Pragma("unroll")                                                      \
    for (int i = 0; i < 4; i++) {                                          \
      pvv[i] = st0[i]; pvv[4+i] = st1[i]; pvv[8+i] = st2[i]; pvv[12+i] = st3[i]; \
    }                                                                      \
    _Pragma("unroll")                                                      \
    for (int i = 0; i < 16; i++) { pvv[i] = exp2f(pvv[i]); LS += pvv[i]; } \
    bf16x8 pf0 = { (short)f2b(pvv[0]),  (short)f2b(pvv[1]),  (short)f2b(pvv[2]),  (short)f2b(pvv[3]),   \
                   (short)f2b(pvv[4]),  (short)f2b(pvv[5]),  (short)f2b(pvv[6]),  (short)f2b(pvv[7]) }; \
    bf16x8 pf1 = { (short)f2b(pvv[8]),  (short)f2b(pvv[9]),  (short)f2b(pvv[10]), (short)f2b(pvv[11]),  \
                   (short)f2b(pvv[12]), (short)f2b(pvv[13]), (short)f2b(pvv[14]), (short)f2b(pvv[15]) };\
    OA = __builtin_amdgcn_mfma_f32_16x16x32_bf16(VF[0], pf0, OA, 0, 0, 0); \
    OA = __builtin_amdgcn_mfma_f32_16x16x32_bf16(VF[1], pf1, OA, 0, 0, 0); \
    OB = __builtin_amdgcn_mfma_f32_16x16x32_bf16(VF[2], pf0, OB, 0, 0, 0); \
    OB = __builtin_amdgcn_mfma_f32_16x16x32_bf16(VF[3], pf1, OB, 0, 0, 0); \
  }

#define ATTN_BODY(KF, VF, KN, VN, KV)                                      \
  {                                                                        \
    LOADFRAGS(KN, VN, (KV) + 64);                                          \
    QPASS(qf0, ls0, o00, o01, KF, VF);                                     \
    QPASS(qf1, ls1, o10, o11, KF, VF);                                     \
  }

__global__ __launch_bounds__(512) void attn_mfma(
    const ushort* __restrict__ qb,    // [4096][128] bf16, pre-scaled
    const ushort* __restrict__ kt,    // [4][256][16][32] bf16 tiles
    const ushort* __restrict__ vt,    // [4][128][2][16][32] bf16 tiles (kvperm'd)
    ushort* __restrict__ attnout)     // [4096][128] bf16
{
  int lane = threadIdx.x & 63;
  int w    = threadIdx.x >> 6;         // kv partition 0..7
  int head = blockIdx.x >> 7;
  int q0   = (blockIdx.x & 127) * 32;
  int ql = lane & 15;
  int g  = lane >> 4;
  const f32x4 z4 = {0.f, 0.f, 0.f, 0.f};
  int kvbase = w * 512;

  bf16x8 qf0 = *(const bf16x8*)(qb + (size_t)(q0 + ql)*128      + head*32 + g*8);
  bf16x8 qf1 = *(const bf16x8*)(qb + (size_t)(q0 + 16 + ql)*128 + head*32 + g*8);
  const ushort* kptr = kt + (size_t)head*131072 + (size_t)kvbase*32 + ql*32 + g*8;
  const ushort* vptr = vt + (size_t)head*131072 + (size_t)kvbase*32 + ql*32 + g*8;

  float ls0 = 0.f, ls1 = 0.f;
  f32x4 o00 = z4, o01 = z4, o10 = z4, o11 = z4;

  bf16x8 kfA[4], vfA[4], kfB[4], vfB[4];
  LOADFRAGS(kfA, vfA, 0);
  for (int kv0 = 0; kv0 < 512; kv0 += 128) {
    ATTN_BODY(kfA, vfA, kfB, vfB, kv0);
    ATTN_BODY(kfB, vfB, kfA, vfA, kv0 + 64);
  }

  ls0 += __shfl_xor(ls0, 16); ls0 += __shfl_xor(ls0, 32);
  ls1 += __shfl_xor(ls1, 16); ls1 += __shfl_xor(ls1, 32);

  __shared__ float so[8][32][36];
  __shared__ float sl[8][32];
  if (g == 0) { sl[w][ql] = ls0; sl[w][16 + ql] = ls1; }
  #pragma unroll
  for (int r = 0; r < 4; r++) {
    so[w][ql][g*4 + r]           = o00[r];
    so[w][ql][16 + g*4 + r]      = o01[r];
    so[w][16 + ql][g*4 + r]      = o10[r];
    so[w][16 + ql][16 + g*4 + r] = o11[r];
  }
  __syncthreads();
  int q  = threadIdx.x >> 4;         // 0..31
  int d0 = (threadIdx.x & 15) * 2;   // 0..30
  float L = 0.f, O0 = 0.f, O1 = 0.f;
  #pragma unroll
  for (int w2 = 0; w2 < 8; w2++) {
    L  += sl[w2][q];
    O0 += so[w2][q][d0];
    O1 += so[w2][q][d0+1];
  }
  float rl = 1.f / L;
  *(unsigned*)(attnout + (size_t)(q0 + q)*128 + head*32 + d0) = pk2(O0*rl, O1*rl);
}

// ---------------------------------------------------------------------------
// decoder pairs: ABp [N][256] bf16 rows = [Ap | Bp]; 4 pairs per iteration.
// ---------------------------------------------------------------------------
__global__ __launch_bounds__(256) void pair_kernel(
    const ushort* __restrict__ ABp,
    const int* __restrict__ ps, const int* __restrict__ pd,
    const float* __restrict__ fc2w, const float* __restrict__ fc2b,
    float* __restrict__ out, int EP)
{
  int gw = (blockIdx.x * blockDim.x + threadIdx.x) >> 6;
  int lane = threadIdx.x & 63;
  int nw = (gridDim.x * blockDim.x) >> 6;
  float w0 = fc2w[2*lane], w1 = fc2w[2*lane + 1];
  float bb = fc2b[0];
  for (int p = gw*4; p < EP; p += nw*4) {
    float acc[4];
    #pragma unroll
    for (int k = 0; k < 4; k++) {
      int pp = (p + k < EP) ? (p + k) : (EP - 1);
      int s = ps[pp], d = pd[pp];
      unsigned av = *(const unsigned*)(ABp + (size_t)s*256 + 2*lane);
      unsigned bv = *(const unsigned*)(ABp + (size_t)d*256 + 128 + 2*lane);
      acc[k] = fmaxf(b2flo(av) + b2flo(bv), 0.f)*w0
             + fmaxf(b2fhi(av) + b2fhi(bv), 0.f)*w1;
    }
    #pragma unroll
    for (int off = 32; off > 0; off >>= 1) {
      #pragma unroll
      for (int k = 0; k < 4; k++) acc[k] += __shfl_down(acc[k], off);
    }
    if (lane == 0) {
      #pragma unroll
      for (int k = 0; k < 4; k++)
        if (p + k < EP) out[p + k] = 1.f / (1.f + __expf(-(acc[k] + bb)));
    }
  }
}

// ---------------------------------------------------------------------------
extern "C" void kernel_launch(void* const* d_in, const int* in_sizes, int n_in,
                              void* d_out, int out_size, void* d_ws, size_t ws_size,
                              hipStream_t stream)
{
  const float* features = (const float*)d_in[0];
  const int*   src      = (const int*)d_in[1];
  const int*   dst      = (const int*)d_in[2];
  const int*   psrc     = (const int*)d_in[3];
  const int*   pdst     = (const int*)d_in[4];
  const float* W1   = (const float*)d_in[5];
  const float* al1  = (const float*)d_in[6];
  const float* ar1  = (const float*)d_in[7];
  const float* b1   = (const float*)d_in[8];
  const float* W2   = (const float*)d_in[9];
  const float* al2  = (const float*)d_in[10];
  const float* ar2  = (const float*)d_in[11];
  const float* b2   = (const float*)d_in[12];
  const float* tw_qkv = (const float*)d_in[13];
  const float* tb_qkv = (const float*)d_in[14];
  const float* tw_o   = (const float*)d_in[15];
  const float* tb_o   = (const float*)d_in[16];
  const float* ln1_g  = (const float*)d_in[17];
  const float* ln1_b  = (const float*)d_in[18];
  const float* tw_ff1 = (const float*)d_in[19];
  const float* tb_ff1 = (const float*)d_in[20];
  const float* tw_ff2 = (const float*)d_in[21];
  const float* tb_ff2 = (const float*)d_in[22];
  const float* ln2_g  = (const float*)d_in[23];
  const float* ln2_b  = (const float*)d_in[24];
  const float* fc1_w  = (const float*)d_in[25];
  const float* fc1_b  = (const float*)d_in[26];
  const float* fc2_w  = (const float*)d_in[27];
  const float* fc2_b  = (const float*)d_in[28];
  int E  = in_sizes[1];
  int EP = in_sizes[3];

  float* ws = (float*)d_ws;
  size_t off = 0;
  auto alloc = [&](size_t n) { float* p = ws + off; off += n; return p; };
  ushort* hb    = (ushort*)alloc((size_t)NN * 64);    // [4096][128] bf16 state
  ushort* featb = (ushort*)alloc((size_t)NN * 128);   // [4096][256] bf16
  ushort* h1b   = (ushort*)alloc((size_t)NN * 256);   // [4096][512] bf16
  ushort* h2b   = (ushort*)alloc((size_t)NN * 256);   // [4096][512] bf16
  ushort* bigb  = (ushort*)alloc((size_t)NN * 256);   // [4096][512] bf16
  ushort* hgb   = (ushort*)alloc((size_t)NN * 64);    // [4096][128] bf16
  ushort* qb    = (ushort*)alloc((size_t)NN * 64);    // [4096][128] bf16
  ushort* attnb = (ushort*)alloc((size_t)NN * 64);    // [4096][128] bf16
  ushort* kt    = (ushort*)alloc((size_t)NN * 64);    // [4][256][16][32]
  ushort* vt    = (ushort*)alloc((size_t)NN * 64);    // [4][128][2][16][32]
  ushort* wbf   = (ushort*)alloc(622592/2);           // all weights bf16
  ushort* ABp   = (ushort*)alloc((size_t)NN * 128);   // [4096][256] bf16
  float*  bias256 = alloc(256);
  float*  el1   = alloc((size_t)NN * 4);
  float*  er1   = alloc((size_t)NN * 4);
  float*  el2   = alloc((size_t)NN);
  float*  er2   = alloc((size_t)NN);
  int* ibase    = (int*)(ws + off);
  int* deg      = ibase;
  int* rowstart = ibase + 4096;
  int* cursor   = rowstart + 4097;
  int* nbr      = cursor + 4096;

  // bf16 weight offsets
  const size_t oW1 = 0, oW2 = 131072, oQKV = 196608, oO = 294912,
               oFF1 = 327680, oFF2 = 458752, oFC1 = 589824;

  cvt_all<<<1633, 256, 0, stream>>>(W1, W2, tw_qkv, tw_o, tw_ff1, tw_ff2,
                                    fc1_w, fc1_b, features, wbf, bias256, featb);

  // CSR build over dst (parallel count + scan + fill)
  hipMemsetAsync(deg, 0, 4096 * sizeof(int), stream);
  count_kernel<<<(E + 255)/256, 256, 0, stream>>>(dst, deg, E);
  scan_kernel<<<1, 1024, 0, stream>>>(deg, rowstart, cursor);
  fill_kernel<<<(E + 255)/256, 256, 0, stream>>>(src, dst, cursor, nbr, E);

  // GAT layer 1
  gemm_mf<false,false,true,true><<<dim3(8, 64), 256, 0, stream>>>(
      featb, wbf + oW1, nullptr, h1b, NN, 512, 256, 256);
  elr4_kernel<<<1024, 256, 0, stream>>>(h1b, al1, ar1, el1, er1);
  gat_agg4<<<1024, 256, 0, stream>>>(h1b, el1, er1, rowstart, nbr, b1, h2b);

  // GAT layer 2: full-width gemm + fused el/er epilogue
  gemm_hg_elr<<<256, 256, 0, stream>>>(h2b, wbf + oW2, al2, ar2, hgb, el2, er2);
  gat_agg1<<<1024, 256, 0, stream>>>(hgb, el2, er2, rowstart, nbr, b2, hb);

  // Transformer encoder (2 layers)
  for (int l = 0; l < 2; l++) {
    gemm_qkv<<<dim3(6, 64), 256, 0, stream>>>(
        hb, wbf + oQKV + (size_t)l*49152, tb_qkv + l*384, qb, kt, vt);
    attn_mfma<<<512, 512, 0, stream>>>(qb, kt, vt, attnb);
    gemm_ln<<<256, 256, 0, stream>>>(
        attnb, wbf + oO + (size_t)l*16384, tb_o + l*128, hb,
        ln1_g + l*128, ln1_b + l*128, 128);
    gemm_mf<true,true,true,true><<<dim3(8, 64), 256, 0, stream>>>(
        hb, wbf + oFF1 + (size_t)l*65536, tb_ff1 + l*512, bigb, NN, 512, 128, 128);
    gemm_ln<<<256, 256, 0, stream>>>(
        bigb, wbf + oFF2 + (size_t)l*65536, tb_ff2 + l*128, hb,
        ln2_g + l*128, ln2_b + l*128, 512);
  }

  // Decoder: one N=256 gemm (re-packed fc1) -> [Ap|Bp] bf16, then pairs
  gemm_mf<true,false,true,true><<<dim3(4, 64), 256, 0, stream>>>(
      hb, wbf + oFC1, bias256, ABp, NN, 256, 128, 128);
  pair_kernel<<<1024, 256, 0, stream>>>(ABp, psrc, pdst, fc2_w, fc2_b, (float*)d_out, EP);
}

// Round 12
// 200.202 us; speedup vs baseline: 1.2095x; 1.0010x over previous
//
#include <hip/hip_runtime.h>
#include <hip/hip_bf16.h>
#include <math.h>

// Model constants (fixed by the reference)
#define NN   4096   // nodes
#define INC  256
#define HIDF 128
#define H1H  4
#define DM   128    // transformer d_model
#define THD  4      // transformer heads (head dim 32)
#define FFD  512

typedef __attribute__((ext_vector_type(8))) short bf16x8;
typedef __attribute__((ext_vector_type(4))) float f32x4;

__device__ __forceinline__ float leaky(float x){ return x > 0.f ? x : 0.2f*x; }

// fp32 -> bf16 bits via HW convert (RNE)
__device__ __forceinline__ ushort f2b(float f){
  __hip_bfloat16 h = __float2bfloat16(f);
  return __builtin_bit_cast(ushort, h);
}
__device__ __forceinline__ unsigned pk2(float a, float b){
  return (unsigned)f2b(a) | ((unsigned)f2b(b) << 16);
}
// bf16 bits -> fp32
__device__ __forceinline__ float b2f(unsigned u){ return __uint_as_float(u << 16); }
__device__ __forceinline__ float b2flo(unsigned u){ return __uint_as_float(u << 16); }
__device__ __forceinline__ float b2fhi(unsigned u){ return __uint_as_float(u & 0xffff0000u); }

// kv bit-permutation within 32-blocks: {b4,b3,b2,b1,b0} -> {b3,b2,b4,b1,b0}
__device__ __forceinline__ int kvperm(int kv){
  return (kv & ~31) | ((kv & 12) << 1) | ((kv >> 2) & 4) | (kv & 3);
}

// ---------------------------------------------------------------------------
// bf16 MFMA GEMM: C[M,N] = A[M,K] @ Wb[N,ldw](bf16)^T (+bias)(+relu)
// 64x64 tile, BK=64, 256 threads = 4 waves (2x2 of 32x32).
// ---------------------------------------------------------------------------
template<bool BIAS, bool RELU, bool OUTBF, bool ABF>
__global__ __launch_bounds__(256) void gemm_mf(
    const void* __restrict__ Av, const ushort* __restrict__ Wb,
    const float* __restrict__ bias, void* __restrict__ Cv,
    int M, int N, int K, int ldw)
{
  __shared__ uint4 As4[512];   // [ko 0..7][m 0..63] : 8 bf16 each
  __shared__ uint4 Bs4[512];
  int tid = threadIdx.x;
  int row0 = blockIdx.y * 64, col0 = blockIdx.x * 64;
  int wid = tid >> 6, lane = tid & 63;
  int wm = wid >> 1, wn = wid & 1;
  int ql = lane & 15, g = lane >> 4;
  const f32x4 z4 = {0.f,0.f,0.f,0.f};
  f32x4 acc[2][2] = {z4,z4,z4,z4};

  for (int k0 = 0; k0 < K; k0 += 64) {
    #pragma unroll
    for (int p = 0; p < 2; p++) {
      int idx = tid + p*256;         // 0..511
      int ko = idx & 7, mm = idx >> 3;
      if constexpr (ABF) {
        As4[ko*64 + mm] = *(const uint4*)((const ushort*)Av + (size_t)(row0 + mm)*K + k0 + ko*8);
      } else {
        const float* sa = (const float*)Av + (size_t)(row0 + mm)*K + k0 + ko*8;
        float4 a0 = *(const float4*)sa;
        float4 a1 = *(const float4*)(sa + 4);
        uint4 av;
        av.x = pk2(a0.x, a0.y); av.y = pk2(a0.z, a0.w);
        av.z = pk2(a1.x, a1.y); av.w = pk2(a1.z, a1.w);
        As4[ko*64 + mm] = av;
      }
      Bs4[ko*64 + mm] = *(const uint4*)(Wb + (size_t)(col0 + mm)*ldw + k0 + ko*8);
    }
    __syncthreads();
    #pragma unroll
    for (int kk = 0; kk < 2; kk++) {
      int ko = kk*4 + g;
      bf16x8 a0 = *((const bf16x8*)As4 + ko*64 + wm*32 + ql);
      bf16x8 a1 = *((const bf16x8*)As4 + ko*64 + wm*32 + 16 + ql);
      bf16x8 b0 = *((const bf16x8*)Bs4 + ko*64 + wn*32 + ql);
      bf16x8 b1 = *((const bf16x8*)Bs4 + ko*64 + wn*32 + 16 + ql);
      acc[0][0] = __builtin_amdgcn_mfma_f32_16x16x32_bf16(a0, b0, acc[0][0], 0,0,0);
      acc[0][1] = __builtin_amdgcn_mfma_f32_16x16x32_bf16(a0, b1, acc[0][1], 0,0,0);
      acc[1][0] = __builtin_amdgcn_mfma_f32_16x16x32_bf16(a1, b0, acc[1][0], 0,0,0);
      acc[1][1] = __builtin_amdgcn_mfma_f32_16x16x32_bf16(a1, b1, acc[1][1], 0,0,0);
    }
    __syncthreads();
  }
  float bvs[2] = {0.f, 0.f};
  if (BIAS) {
    bvs[0] = bias[col0 + wn*32 + ql];
    bvs[1] = bias[col0 + wn*32 + 16 + ql];
  }
  #pragma unroll
  for (int fm = 0; fm < 2; fm++)
    #pragma unroll
    for (int fn = 0; fn < 2; fn++) {
      int row = row0 + wm*32 + fm*16 + g*4;
      int col = col0 + wn*32 + fn*16 + ql;
      #pragma unroll
      for (int r = 0; r < 4; r++) {
        float v = acc[fm][fn][r];
        if (BIAS) v += bvs[fn];
        if (RELU) v = fmaxf(v, 0.f);
        if (OUTBF) ((ushort*)Cv)[(size_t)(row + r)*N + col] = f2b(v);
        else       ((float*)Cv)[(size_t)(row + r)*N + col] = v;
      }
    }
}

// ---------------------------------------------------------------------------
// qkv GEMM with fused Q-scale + K/V tile scatter.
// ---------------------------------------------------------------------------
__global__ __launch_bounds__(256) void gemm_qkv(
    const ushort* __restrict__ Ab, const ushort* __restrict__ Wb,
    const float* __restrict__ bias,
    ushort* __restrict__ qb, ushort* __restrict__ kt, ushort* __restrict__ vt)
{
  __shared__ uint4 As4[512];
  __shared__ uint4 Bs4[512];
  int tid = threadIdx.x;
  int row0 = blockIdx.y * 64, col0 = blockIdx.x * 64;
  int wid = tid >> 6, lane = tid & 63;
  int wm = wid >> 1, wn = wid & 1;
  int ql = lane & 15, g = lane >> 4;
  const f32x4 z4 = {0.f,0.f,0.f,0.f};
  f32x4 acc[2][2] = {z4,z4,z4,z4};

  for (int k0 = 0; k0 < 128; k0 += 64) {
    #pragma unroll
    for (int p = 0; p < 2; p++) {
      int idx = tid + p*256;
      int ko = idx & 7, mm = idx >> 3;
      As4[ko*64 + mm] = *(const uint4*)(Ab + (size_t)(row0 + mm)*128 + k0 + ko*8);
      Bs4[ko*64 + mm] = *(const uint4*)(Wb + (size_t)(col0 + mm)*128 + k0 + ko*8);
    }
    __syncthreads();
    #pragma unroll
    for (int kk = 0; kk < 2; kk++) {
      int ko = kk*4 + g;
      bf16x8 a0 = *((const bf16x8*)As4 + ko*64 + wm*32 + ql);
      bf16x8 a1 = *((const bf16x8*)As4 + ko*64 + wm*32 + 16 + ql);
      bf16x8 b0 = *((const bf16x8*)Bs4 + ko*64 + wn*32 + ql);
      bf16x8 b1 = *((const bf16x8*)Bs4 + ko*64 + wn*32 + 16 + ql);
      acc[0][0] = __builtin_amdgcn_mfma_f32_16x16x32_bf16(a0, b0, acc[0][0], 0,0,0);
      acc[0][1] = __builtin_amdgcn_mfma_f32_16x16x32_bf16(a0, b1, acc[0][1], 0,0,0);
      acc[1][0] = __builtin_amdgcn_mfma_f32_16x16x32_bf16(a1, b0, acc[1][0], 0,0,0);
      acc[1][1] = __builtin_amdgcn_mfma_f32_16x16x32_bf16(a1, b1, acc[1][1], 0,0,0);
    }
    __syncthreads();
  }
  float bvs[2];
  bvs[0] = bias[col0 + wn*32 + ql];
  bvs[1] = bias[col0 + wn*32 + 16 + ql];
  #pragma unroll
  for (int fm = 0; fm < 2; fm++)
    #pragma unroll
    for (int fn = 0; fn < 2; fn++) {
      int row = row0 + wm*32 + fm*16 + g*4;
      int col = col0 + wn*32 + fn*16 + ql;
      #pragma unroll
      for (int r = 0; r < 4; r++) {
        float v = acc[fm][fn][r] + bvs[fn];
        int kv = row + r;
        if (col < 128) {
          qb[(size_t)kv*128 + col] = f2b(v * 0.25505654708f);  // 1/sqrt(32)*log2e
        } else if (col < 256) {
          int hh = (col - 128) >> 5, d = (col - 128) & 31;
          kt[(size_t)hh*131072 + (size_t)kv*32 + d] = f2b(v);
        } else {
          int hh = (col - 256) >> 5, d = (col - 256) & 31;
          vt[(size_t)hh*131072 + (size_t)(kv >> 5)*1024 + (d >> 4)*512
             + (d & 15)*32 + kvperm(kv & 31)] = f2b(v);
        }
      }
    }
}

// ---------------------------------------------------------------------------
// Fused bf16 GEMM (N=128) + residual + LayerNorm (in-place bf16 h).
// DEC=true: additionally compute ABp[row][256] = LN(h) @ fc1re^T + bias256
// (decoder factorized fc1), and skip the h write (dead afterwards).
// BM=16 rows/block -> grid 256. 4 waves.
// ---------------------------------------------------------------------------
template<bool DEC>
__global__ __launch_bounds__(256) void gemm_ln(
    const ushort* __restrict__ Ab, const ushort* __restrict__ Wb,
    const float* __restrict__ bias, ushort* __restrict__ h,
    const float* __restrict__ lng, const float* __restrict__ lnb, int K,
    const ushort* __restrict__ Wdec, const float* __restrict__ bias256,
    ushort* __restrict__ ABp)
{
  __shared__ uint4 As4[128];    // [ko 0..7][m 0..15]
  __shared__ uint4 Bs4[1024];   // [ko 0..7][n 0..127] ; reused for DEC staging
  __shared__ float xs[16][132];
  __shared__ ushort xsb[16][136];  // DEC: LN'd rows in bf16 (padded)
  int tid = threadIdx.x;
  int row0 = blockIdx.x * 16;
  int wv = tid >> 6, lane = tid & 63;
  int ql = lane & 15, g = lane >> 4;
  const f32x4 z4 = {0.f,0.f,0.f,0.f};
  f32x4 acc[2] = {z4, z4};

  for (int k0 = 0; k0 < K; k0 += 64) {
    if (tid < 128) {
      int ko = tid & 7, mm = tid >> 3;
      As4[ko*16 + mm] = *(const uint4*)(Ab + (size_t)(row0 + mm)*K + k0 + ko*8);
    }
    #pragma unroll
    for (int p = 0; p < 4; p++) {
      int idx = tid + p*256;     // 0..1023
      int ko = idx & 7, nn = idx >> 3;
      Bs4[ko*128 + nn] = *(const uint4*)(Wb + (size_t)nn*K + k0 + ko*8);
    }
    __syncthreads();
    #pragma unroll
    for (int kk = 0; kk < 2; kk++) {
      int ko = kk*4 + g;
      bf16x8 a = *((const bf16x8*)As4 + ko*16 + ql);
      #pragma unroll
      for (int fn = 0; fn < 2; fn++) {
        bf16x8 b = *((const bf16x8*)Bs4 + ko*128 + wv*32 + fn*16 + ql);
        acc[fn] = __builtin_amdgcn_mfma_f32_16x16x32_bf16(a, b, acc[fn], 0,0,0);
      }
    }
    __syncthreads();
  }
  // stage gemm+bias into LDS
  #pragma unroll
  for (int fn = 0; fn < 2; fn++) {
    int col = wv*32 + fn*16 + ql;
    float bv = bias[col];
    #pragma unroll
    for (int r = 0; r < 4; r++) xs[g*4 + r][col] = acc[fn][r] + bv;
  }
  __syncthreads();
  // residual + LN: 16 lanes per row, 8 cols each
  int rl = tid >> 4, cl = tid & 15, c0 = cl * 8;
  ushort* hrow = h + (size_t)(row0 + rl)*128;
  uint4 rv = *(const uint4*)(hrow + c0);
  float x[8];
  x[0] = xs[rl][c0+0] + b2flo(rv.x); x[1] = xs[rl][c0+1] + b2fhi(rv.x);
  x[2] = xs[rl][c0+2] + b2flo(rv.y); x[3] = xs[rl][c0+3] + b2fhi(rv.y);
  x[4] = xs[rl][c0+4] + b2flo(rv.z); x[5] = xs[rl][c0+5] + b2fhi(rv.z);
  x[6] = xs[rl][c0+6] + b2flo(rv.w); x[7] = xs[rl][c0+7] + b2fhi(rv.w);
  float s1 = 0.f, s2 = 0.f;
  #pragma unroll
  for (int i = 0; i < 8; i++) { s1 += x[i]; s2 += x[i]*x[i]; }
  #pragma unroll
  for (int st = 1; st < 16; st <<= 1) {
    s1 += __shfl_xor(s1, st); s2 += __shfl_xor(s2, st);
  }
  float mean = s1 * (1.f/128.f);
  float var  = s2 * (1.f/128.f) - mean*mean;
  float rstd = rsqrtf(var + 1e-5f);
  float o[8];
  #pragma unroll
  for (int i = 0; i < 8; i += 4) {
    float4 g4 = *(const float4*)(lng + c0 + i);
    float4 b4 = *(const float4*)(lnb + c0 + i);
    o[i+0] = (x[i+0]-mean)*rstd*g4.x + b4.x;
    o[i+1] = (x[i+1]-mean)*rstd*g4.y + b4.y;
    o[i+2] = (x[i+2]-mean)*rstd*g4.z + b4.z;
    o[i+3] = (x[i+3]-mean)*rstd*g4.w + b4.w;
  }
  uint4 ov; ov.x = pk2(o[0],o[1]); ov.y = pk2(o[2],o[3]);
  ov.z = pk2(o[4],o[5]); ov.w = pk2(o[6],o[7]);
  if constexpr (!DEC) {
    *(uint4*)(hrow + c0) = ov;
  } else {
    // stash LN'd bf16 rows for the decoder GEMM
    *(uint4*)(&xsb[rl][c0]) = ov;
    __syncthreads();
    f32x4 acc2[4] = {z4, z4, z4, z4};
    for (int kk = 0; kk < 4; kk++) {
      // stage fc1re chunk [256 out-cols][k = kk*32..+31] into Bs4 (XOR swizzled)
      #pragma unroll
      for (int p = 0; p < 4; p++) {
        int idx = tid + p*256;        // 0..1023
        int ko = idx & 3, row = idx >> 2;
        Bs4[ko*256 + (row ^ (ko << 2))] =
            *(const uint4*)(Wdec + (size_t)row*128 + kk*32 + ko*8);
      }
      __syncthreads();
      bf16x8 a = *(const bf16x8*)(&xsb[ql][kk*32 + g*8]);
      #pragma unroll
      for (int fn = 0; fn < 4; fn++) {
        int col = wv*64 + fn*16 + ql;
        bf16x8 b = *((const bf16x8*)Bs4 + g*256 + (col ^ (g << 2)));
        acc2[fn] = __builtin_amdgcn_mfma_f32_16x16x32_bf16(a, b, acc2[fn], 0,0,0);
      }
      __syncthreads();
    }
    #pragma unroll
    for (int fn = 0; fn < 4; fn++) {
      int col = wv*64 + fn*16 + ql;
      float bv = bias256[col];
      #pragma unroll
      for (int r = 0; r < 4; r++)
        ABp[(size_t)(row0 + g*4 + r)*256 + col] = f2b(acc2[fn][r] + bv);
    }
  }
}

// ---------------------------------------------------------------------------
// GAT2 GEMM (N=128 full-width per block) + fused el2/er2 epilogue.
// ---------------------------------------------------------------------------
__global__ __launch_bounds__(256) void gemm_hg_elr(
    const ushort* __restrict__ Ab, const ushort* __restrict__ Wb,
    const float* __restrict__ al, const float* __restrict__ ar,
    ushort* __restrict__ hg, float* __restrict__ el, float* __restrict__ er)
{
  __shared__ uint4 As4[128];    // [ko 0..7][m 0..15]
  __shared__ uint4 Bs4[1024];   // [ko 0..7][n 0..127]
  __shared__ float xs[16][132];
  int tid = threadIdx.x;
  int row0 = blockIdx.x * 16;
  int wv = tid >> 6, lane = tid & 63;
  int ql = lane & 15, g = lane >> 4;
  const f32x4 z4 = {0.f,0.f,0.f,0.f};
  f32x4 acc[2] = {z4, z4};

  for (int k0 = 0; k0 < 512; k0 += 64) {
    if (tid < 128) {
      int ko = tid & 7, mm = tid >> 3;
      As4[ko*16 + mm] = *(const uint4*)(Ab + (size_t)(row0 + mm)*512 + k0 + ko*8);
    }
    #pragma unroll
    for (int p = 0; p < 4; p++) {
      int idx = tid + p*256;
      int ko = idx & 7, nn = idx >> 3;
      Bs4[ko*128 + nn] = *(const uint4*)(Wb + (size_t)nn*512 + k0 + ko*8);
    }
    __syncthreads();
    #pragma unroll
    for (int kk = 0; kk < 2; kk++) {
      int ko = kk*4 + g;
      bf16x8 a = *((const bf16x8*)As4 + ko*16 + ql);
      #pragma unroll
      for (int fn = 0; fn < 2; fn++) {
        bf16x8 b = *((const bf16x8*)Bs4 + ko*128 + wv*32 + fn*16 + ql);
        acc[fn] = __builtin_amdgcn_mfma_f32_16x16x32_bf16(a, b, acc[fn], 0,0,0);
      }
    }
    __syncthreads();
  }
  #pragma unroll
  for (int fn = 0; fn < 2; fn++) {
    int col = wv*32 + fn*16 + ql;
    #pragma unroll
    for (int r = 0; r < 4; r++) xs[g*4 + r][col] = acc[fn][r];
  }
  __syncthreads();
  int rl = tid >> 4, cl = tid & 15, c0 = cl * 8;
  float e1 = 0.f, e2 = 0.f;
  float x[8];
  #pragma unroll
  for (int i = 0; i < 8; i += 4) {
    float4 a4 = *(const float4*)(al + c0 + i);
    float4 r4 = *(const float4*)(ar + c0 + i);
    x[i+0] = xs[rl][c0+i+0]; x[i+1] = xs[rl][c0+i+1];
    x[i+2] = xs[rl][c0+i+2]; x[i+3] = xs[rl][c0+i+3];
    e1 += x[i+0]*a4.x + x[i+1]*a4.y + x[i+2]*a4.z + x[i+3]*a4.w;
    e2 += x[i+0]*r4.x + x[i+1]*r4.y + x[i+2]*r4.z + x[i+3]*r4.w;
  }
  uint4 ov; ov.x = pk2(x[0],x[1]); ov.y = pk2(x[2],x[3]);
  ov.z = pk2(x[4],x[5]); ov.w = pk2(x[6],x[7]);
  *(uint4*)(hg + (size_t)(row0 + rl)*128 + c0) = ov;
  #pragma unroll
  for (int st = 1; st < 16; st <<= 1) {
    e1 += __shfl_xor(e1, st); e2 += __shfl_xor(e2, st);
  }
  if (cl == 0) { el[row0 + rl] = e1; er[row0 + rl] = e2; }
}

// ---------------------------------------------------------------------------
// one-shot conversion + edge-degree count:
// blocks 0..607: weights; 608: bias256; 609..1632: features; 1633..2144: count.
// (deg must be zeroed by a memset enqueued BEFORE this kernel.)
// ---------------------------------------------------------------------------
__global__ __launch_bounds__(256) void cvt_all(
    const float* __restrict__ W1, const float* __restrict__ W2,
    const float* __restrict__ qkv, const float* __restrict__ o,
    const float* __restrict__ ff1, const float* __restrict__ ff2,
    const float* __restrict__ fc1, const float* __restrict__ fc1b,
    const float* __restrict__ feat,
    ushort* __restrict__ out, float* __restrict__ bias256,
    ushort* __restrict__ featb,
    const int* __restrict__ dst, int* __restrict__ deg, int E)
{
  int b = blockIdx.x;
  if (b >= 1633) {
    int e = (b - 1633)*256 + threadIdx.x;
    if (e < E) atomicAdd(&deg[dst[e]], 1);
    return;
  }
  if (b == 608) {
    int t = threadIdx.x;
    bias256[t] = (t < 128) ? fc1b[t] : 0.f;
    return;
  }
  if (b >= 609) {
    int i = ((b - 609)*256 + threadIdx.x) * 4;
    float4 v = *(const float4*)(feat + i);
    uint2 w; w.x = pk2(v.x, v.y); w.y = pk2(v.z, v.w);
    *(uint2*)(featb + i) = w;
    return;
  }
  int i4 = (b*256 + threadIdx.x) * 4;
  const float* s; int loc;
  size_t dstoff = i4;
  if      (i4 < 131072) { s = W1;  loc = i4; }
  else if (i4 < 196608) { s = W2;  loc = i4 - 131072; }
  else if (i4 < 294912) { s = qkv; loc = i4 - 196608; }
  else if (i4 < 327680) { s = o;   loc = i4 - 294912; }
  else if (i4 < 458752) { s = ff1; loc = i4 - 327680; }
  else if (i4 < 589824) { s = ff2; loc = i4 - 458752; }
  else {
    s = fc1; loc = i4 - 589824;
    int j = loc >> 8, k2 = loc & 255;
    dstoff = 589824 + ((k2 >= 128) ? 16384 : 0) + j*128 + (k2 & 127);
  }
  float4 v = *(const float4*)(s + loc);
  uint2 w; w.x = pk2(v.x, v.y); w.y = pk2(v.z, v.w);
  *(uint2*)(out + dstoff) = w;
}

// ---------------------------------------------------------------------------
// CSR: 1-block scan + fill
// ---------------------------------------------------------------------------
__global__ __launch_bounds__(1024) void scan_kernel(
    const int* __restrict__ deg, int* __restrict__ rowstart, int* __restrict__ cursor)
{
  __shared__ int sdata[1024];
  int t = threadIdx.x;
  int base = t * 4;
  int v0 = deg[base], v1 = deg[base+1], v2 = deg[base+2], v3 = deg[base+3];
  int tot = v0 + v1 + v2 + v3;
  sdata[t] = tot;
  __syncthreads();
  for (int off = 1; off < 1024; off <<= 1) {
    int x = (t >= off) ? sdata[t - off] : 0;
    __syncthreads();
    sdata[t] += x;
    __syncthreads();
  }
  int run = sdata[t] - tot;  // exclusive
  rowstart[base]   = run; cursor[base]   = run; run += v0;
  rowstart[base+1] = run; cursor[base+1] = run; run += v1;
  rowstart[base+2] = run; cursor[base+2] = run; run += v2;
  rowstart[base+3] = run; cursor[base+3] = run; run += v3;
  if (t == 1023) rowstart[4096] = run;
}
__global__ void fill_kernel(const int* __restrict__ src, const int* __restrict__ dst,
                            int* __restrict__ cursor, int* __restrict__ nbr, int E) {
  int e = blockIdx.x * blockDim.x + threadIdx.x;
  if (e < E) {
    int p = atomicAdd(&cursor[dst[e]], 1);
    nbr[p] = src[e];
  }
}

// ---------------------------------------------------------------------------
// el/er attention coefficients for GAT1 (H=4, bf16 h input); one wave/node.
// ---------------------------------------------------------------------------
__global__ __launch_bounds__(256) void elr4_kernel(
    const ushort* __restrict__ hmat, const float* __restrict__ al,
    const float* __restrict__ ar, float* __restrict__ el, float* __restrict__ er)
{
  int w = threadIdx.x >> 6, lane = threadIdx.x & 63;
  int n = blockIdx.x * 4 + w;
  int hh = lane >> 4, f0 = (lane & 15) * 8;
  bf16x8 hv = *(const bf16x8*)(hmat + (size_t)n*512 + hh*128 + f0);
  float4 a0 = *(const float4*)(al + hh*128 + f0);
  float4 a1 = *(const float4*)(al + hh*128 + f0 + 4);
  float4 r0 = *(const float4*)(ar + hh*128 + f0);
  float4 r1 = *(const float4*)(ar + hh*128 + f0 + 4);
  float x[8];
  #pragma unroll
  for (int i = 0; i < 8; i++) x[i] = b2f((ushort)hv[i]);
  float e1 = x[0]*a0.x + x[1]*a0.y + x[2]*a0.z + x[3]*a0.w
           + x[4]*a1.x + x[5]*a1.y + x[6]*a1.z + x[7]*a1.w;
  float e2 = x[0]*r0.x + x[1]*r0.y + x[2]*r0.z + x[3]*r0.w
           + x[4]*r1.x + x[5]*r1.y + x[6]*r1.z + x[7]*r1.w;
  #pragma unroll
  for (int s = 1; s < 16; s <<= 1) { e1 += __shfl_xor(e1, s); e2 += __shfl_xor(e2, s); }
  if ((lane & 15) == 0) { el[n*4 + hh] = e1; er[n*4 + hh] = e2; }
}

// ---------------------------------------------------------------------------
// GAT aggregation H=4: one wave/node, no max tracking, single-pass deg<=256.
// ---------------------------------------------------------------------------
__global__ __launch_bounds__(256) void gat_agg4(
    const ushort* __restrict__ hsrc, const float* __restrict__ el, const float* __restrict__ er,
    const int* __restrict__ rowstart, const int* __restrict__ nbr,
    const float* __restrict__ bias, ushort* __restrict__ out)
{
  __shared__ float s_alpha[4][256][4];
  __shared__ int   s_nbr[4][256];
  int wv = threadIdx.x >> 6, lane = threadIdx.x & 63;
  int n = blockIdx.x * 4 + wv;
  int e0 = rowstart[n];
  int deg = rowstart[n+1] - e0;
  float4 ern = *(const float4*)(er + (size_t)n*4);
  int hh = lane >> 4;
  float acc[8] = {};
  if (deg > 0 && deg <= 256) {
    float se0=0.f, se1=0.f, se2=0.f, se3=0.f;
    for (int i = lane; i < deg; i += 64) {
      int s = nbr[e0 + i];
      s_nbr[wv][i] = s;
      float4 ev = *(const float4*)(el + (size_t)s*4);
      float p0 = __expf(leaky(ev.x + ern.x));
      float p1 = __expf(leaky(ev.y + ern.y));
      float p2 = __expf(leaky(ev.z + ern.z));
      float p3 = __expf(leaky(ev.w + ern.w));
      s_alpha[wv][i][0] = p0; s_alpha[wv][i][1] = p1;
      s_alpha[wv][i][2] = p2; s_alpha[wv][i][3] = p3;
      se0 += p0; se1 += p1; se2 += p2; se3 += p3;
    }
    #pragma unroll
    for (int st = 1; st < 64; st <<= 1) {
      se0 += __shfl_xor(se0, st); se1 += __shfl_xor(se1, st);
      se2 += __shfl_xor(se2, st); se3 += __shfl_xor(se3, st);
    }
    float si = 1.f / ((hh == 0) ? se0 : (hh == 1) ? se1 : (hh == 2) ? se2 : se3);
    #pragma unroll 4
    for (int i = 0; i < deg; i++) {
      float a = s_alpha[wv][i][hh] * si;
      int s = s_nbr[wv][i];
      uint4 hv = *(const uint4*)(hsrc + (size_t)s*512 + lane*8);
      acc[0] += a * b2flo(hv.x); acc[1] += a * b2fhi(hv.x);
      acc[2] += a * b2flo(hv.y); acc[3] += a * b2fhi(hv.y);
      acc[4] += a * b2flo(hv.z); acc[5] += a * b2fhi(hv.z);
      acc[6] += a * b2flo(hv.w); acc[7] += a * b2fhi(hv.w);
    }
  } else if (deg > 0) {
    float se0=0.f, se1=0.f, se2=0.f, se3=0.f;
    for (int i = lane; i < deg; i += 64) {
      int s = nbr[e0 + i];
      float4 ev = *(const float4*)(el + (size_t)s*4);
      se0 += __expf(leaky(ev.x + ern.x));
      se1 += __expf(leaky(ev.y + ern.y));
      se2 += __expf(leaky(ev.z + ern.z));
      se3 += __expf(leaky(ev.w + ern.w));
    }
    #pragma unroll
    for (int st = 1; st < 64; st <<= 1) {
      se0 += __shfl_xor(se0, st); se1 += __shfl_xor(se1, st);
      se2 += __shfl_xor(se2, st); se3 += __shfl_xor(se3, st);
    }
    float si0 = 1.f/se0, si1 = 1.f/se1, si2 = 1.f/se2, si3 = 1.f/se3;
    for (int c = 0; c < deg; c += 256) {
      int cn = min(256, deg - c);
      for (int i = lane; i < cn; i += 64) {
        int s = nbr[e0 + c + i];
        s_nbr[wv][i] = s;
        float4 ev = *(const float4*)(el + (size_t)s*4);
        s_alpha[wv][i][0] = __expf(leaky(ev.x + ern.x)) * si0;
        s_alpha[wv][i][1] = __expf(leaky(ev.y + ern.y)) * si1;
        s_alpha[wv][i][2] = __expf(leaky(ev.z + ern.z)) * si2;
        s_alpha[wv][i][3] = __expf(leaky(ev.w + ern.w)) * si3;
      }
      #pragma unroll 4
      for (int i = 0; i < cn; i++) {
        float a = s_alpha[wv][i][hh];
        int s = s_nbr[wv][i];
        uint4 hv = *(const uint4*)(hsrc + (size_t)s*512 + lane*8);
        acc[0] += a * b2flo(hv.x); acc[1] += a * b2fhi(hv.x);
        acc[2] += a * b2flo(hv.y); acc[3] += a * b2fhi(hv.y);
        acc[4] += a * b2flo(hv.z); acc[5] += a * b2fhi(hv.z);
        acc[6] += a * b2flo(hv.w); acc[7] += a * b2fhi(hv.w);
      }
    }
  }
  const float* bp = bias + lane*8;
  float4 b0 = *(const float4*)(bp);
  float4 b1 = *(const float4*)(bp + 4);
  float v0 = fmaxf(acc[0]+b0.x, 0.f), v1 = fmaxf(acc[1]+b0.y, 0.f);
  float v2 = fmaxf(acc[2]+b0.z, 0.f), v3 = fmaxf(acc[3]+b0.w, 0.f);
  float v4 = fmaxf(acc[4]+b1.x, 0.f), v5 = fmaxf(acc[5]+b1.y, 0.f);
  float v6 = fmaxf(acc[6]+b1.z, 0.f), v7 = fmaxf(acc[7]+b1.w, 0.f);
  uint4 ov; ov.x = pk2(v0,v1); ov.y = pk2(v2,v3); ov.z = pk2(v4,v5); ov.w = pk2(v6,v7);
  *(uint4*)(out + (size_t)n*512 + lane*8) = ov;
}

// ---------------------------------------------------------------------------
// GAT aggregation H=1: one wave/node, no max tracking, single-pass deg<=256.
// ---------------------------------------------------------------------------
__global__ __launch_bounds__(256) void gat_agg1(
    const ushort* __restrict__ hsrc, const float* __restrict__ el, const float* __restrict__ er,
    const int* __restrict__ rowstart, const int* __restrict__ nbr,
    const float* __restrict__ bias, ushort* __restrict__ out)
{
  __shared__ float s_alpha[4][256];
  __shared__ int   s_nbr[4][256];
  int wv = threadIdx.x >> 6, lane = threadIdx.x & 63;
  int n = blockIdx.x * 4 + wv;
  int e0 = rowstart[n];
  int deg = rowstart[n+1] - e0;
  float ern = er[n];
  float a0 = 0.f, a1 = 0.f;
  if (deg > 0 && deg <= 256) {
    float se = 0.f;
    for (int i = lane; i < deg; i += 64) {
      int s = nbr[e0 + i];
      s_nbr[wv][i] = s;
      float p = __expf(leaky(el[s] + ern));
      s_alpha[wv][i] = p;
      se += p;
    }
    #pragma unroll
    for (int st = 1; st < 64; st <<= 1) se += __shfl_xor(se, st);
    float si = 1.f / se;
    #pragma unroll 4
    for (int i = 0; i < deg; i++) {
      float a = s_alpha[wv][i] * si;
      int s = s_nbr[wv][i];
      unsigned u = *(const unsigned*)(hsrc + (size_t)s*128 + lane*2);
      a0 += a * b2flo(u);
      a1 += a * b2fhi(u);
    }
  } else if (deg > 0) {
    float se = 0.f;
    for (int i = lane; i < deg; i += 64)
      se += __expf(leaky(el[nbr[e0 + i]] + ern));
    #pragma unroll
    for (int st = 1; st < 64; st <<= 1) se += __shfl_xor(se, st);
    float si = 1.f / se;
    for (int c = 0; c < deg; c += 256) {
      int cn = min(256, deg - c);
      for (int i = lane; i < cn; i += 64) {
        int s = nbr[e0 + c + i];
        s_nbr[wv][i] = s;
        s_alpha[wv][i] = __expf(leaky(el[s] + ern)) * si;
      }
      #pragma unroll 4
      for (int i = 0; i < cn; i++) {
        float a = s_alpha[wv][i];
        int s = s_nbr[wv][i];
        unsigned u = *(const unsigned*)(hsrc + (size_t)s*128 + lane*2);
        a0 += a * b2flo(u);
        a1 += a * b2fhi(u);
      }
    }
  }
  float v0 = a0 + bias[lane*2], v1 = a1 + bias[lane*2 + 1];
  *(unsigned*)(out + (size_t)n*128 + lane*2) = pk2(v0, v1);
}

// ---------------------------------------------------------------------------
// MFMA flash attention: 8-way kv split, 512-thread blocks (4 waves/SIMD TLP).
// ---------------------------------------------------------------------------
#define LOADFRAGS(KF, VF, KV)                                              \
  {                                                                        \
    int _kv = (KV);                                                        \
    if (_kv < 512) {                                                       \
      const ushort* _kp = kptr + (size_t)_kv * 32;                         \
      const ushort* _vp = vptr + (size_t)_kv * 32;                         \
      KF[0] = *(const bf16x8*)(_kp);                                       \
      KF[1] = *(const bf16x8*)(_kp + 512);                                 \
      KF[2] = *(const bf16x8*)(_kp + 1024);                                \
      KF[3] = *(const bf16x8*)(_kp + 1536);                                \
      VF[0] = *(const bf16x8*)(_vp);                                       \
      VF[1] = *(const bf16x8*)(_vp + 1024);                                \
      VF[2] = *(const bf16x8*)(_vp + 512);                                 \
      VF[3] = *(const bf16x8*)(_vp + 1536);                                \
    }                                                                      \
  }

#define QPASS(QF, LS, OA, OB, KF, VF)                                      \
  {                                                                        \
    f32x4 st0 = __builtin_amdgcn_mfma_f32_16x16x32_bf16(KF[0], QF, z4, 0, 0, 0); \
    f32x4 st1 = __builtin_amdgcn_mfma_f32_16x16x32_bf16(KF[1], QF, z4, 0, 0, 0); \
    f32x4 st2 = __builtin_amdgcn_mfma_f32_16x16x32_bf16(KF[2], QF, z4, 0, 0, 0); \
    f32x4 st3 = __builtin_amdgcn_mfma_f32_16x16x32_bf16(KF[3], QF, z4, 0, 0, 0); \
    float pvv[16];                                                         \
    _Pragma("unroll")                                                      \
    for (int i = 0; i < 4; i++) {                                          \
      pvv[i] = st0[i]; pvv[4+i] = st1[i]; pvv[8+i] = st2[i]; pvv[12+i] = st3[i]; \
    }                                                                      \
    _Pragma("unroll")                                                      \
    for (int i = 0; i < 16; i++) { pvv[i] = exp2f(pvv[i]); LS += pvv[i]; } \
    bf16x8 pf0 = { (short)f2b(pvv[0]),  (short)f2b(pvv[1]),  (short)f2b(pvv[2]),  (short)f2b(pvv[3]),   \
                   (short)f2b(pvv[4]),  (short)f2b(pvv[5]),  (short)f2b(pvv[6]),  (short)f2b(pvv[7]) }; \
    bf16x8 pf1 = { (short)f2b(pvv[8]),  (short)f2b(pvv[9]),  (short)f2b(pvv[10]), (short)f2b(pvv[11]),  \
                   (short)f2b(pvv[12]), (short)f2b(pvv[13]), (short)f2b(pvv[14]), (short)f2b(pvv[15]) };\
    OA = __builtin_amdgcn_mfma_f32_16x16x32_bf16(VF[0], pf0, OA, 0, 0, 0); \
    OA = __builtin_amdgcn_mfma_f32_16x16x32_bf16(VF[1], pf1, OA, 0, 0, 0); \
    OB = __builtin_amdgcn_mfma_f32_16x16x32_bf16(VF[2], pf0, OB, 0, 0, 0); \
    OB = __builtin_amdgcn_mfma_f32_16x16x32_bf16(VF[3], pf1, OB, 0, 0, 0); \
  }

#define ATTN_BODY(KF, VF, KN, VN, KV)                                      \
  {                                                                        \
    LOADFRAGS(KN, VN, (KV) + 64);                                          \
    QPASS(qf0, ls0, o00, o01, KF, VF);                                     \
    QPASS(qf1, ls1, o10, o11, KF, VF);                                     \
  }

__global__ __launch_bounds__(512) void attn_mfma(
    const ushort* __restrict__ qb,    // [4096][128] bf16, pre-scaled
    const ushort* __restrict__ kt,    // [4][256][16][32] bf16 tiles
    const ushort* __restrict__ vt,    // [4][128][2][16][32] bf16 tiles (kvperm'd)
    ushort* __restrict__ attnout)     // [4096][128] bf16
{
  int lane = threadIdx.x & 63;
  int w    = threadIdx.x >> 6;         // kv partition 0..7
  int head = blockIdx.x >> 7;
  int q0   = (blockIdx.x & 127) * 32;
  int ql = lane & 15;
  int g  = lane >> 4;
  const f32x4 z4 = {0.f, 0.f, 0.f, 0.f};
  int kvbase = w * 512;

  bf16x8 qf0 = *(const bf16x8*)(qb + (size_t)(q0 + ql)*128      + head*32 + g*8);
  bf16x8 qf1 = *(const bf16x8*)(qb + (size_t)(q0 + 16 + ql)*128 + head*32 + g*8);
  const ushort* kptr = kt + (size_t)head*131072 + (size_t)kvbase*32 + ql*32 + g*8;
  const ushort* vptr = vt + (size_t)head*131072 + (size_t)kvbase*32 + ql*32 + g*8;

  float ls0 = 0.f, ls1 = 0.f;
  f32x4 o00 = z4, o01 = z4, o10 = z4, o11 = z4;

  bf16x8 kfA[4], vfA[4], kfB[4], vfB[4];
  LOADFRAGS(kfA, vfA, 0);
  for (int kv0 = 0; kv0 < 512; kv0 += 128) {
    ATTN_BODY(kfA, vfA, kfB, vfB, kv0);
    ATTN_BODY(kfB, vfB, kfA, vfA, kv0 + 64);
  }

  ls0 += __shfl_xor(ls0, 16); ls0 += __shfl_xor(ls0, 32);
  ls1 += __shfl_xor(ls1, 16); ls1 += __shfl_xor(ls1, 32);

  __shared__ float so[8][32][36];
  __shared__ float sl[8][32];
  if (g == 0) { sl[w][ql] = ls0; sl[w][16 + ql] = ls1; }
  #pragma unroll
  for (int r = 0; r < 4; r++) {
    so[w][ql][g*4 + r]           = o00[r];
    so[w][ql][16 + g*4 + r]      = o01[r];
    so[w][16 + ql][g*4 + r]      = o10[r];
    so[w][16 + ql][16 + g*4 + r] = o11[r];
  }
  __syncthreads();
  int q  = threadIdx.x >> 4;         // 0..31
  int d0 = (threadIdx.x & 15) * 2;   // 0..30
  float L = 0.f, O0 = 0.f, O1 = 0.f;
  #pragma unroll
  for (int w2 = 0; w2 < 8; w2++) {
    L  += sl[w2][q];
    O0 += so[w2][q][d0];
    O1 += so[w2][q][d0+1];
  }
  float rl = 1.f / L;
  *(unsigned*)(attnout + (size_t)(q0 + q)*128 + head*32 + d0) = pk2(O0*rl, O1*rl);
}

// ---------------------------------------------------------------------------
// decoder pairs: ABp [N][256] bf16 rows = [Ap | Bp]; 4 pairs per iteration.
// ---------------------------------------------------------------------------
__global__ __launch_bounds__(256) void pair_kernel(
    const ushort* __restrict__ ABp,
    const int* __restrict__ ps, const int* __restrict__ pd,
    const float* __restrict__ fc2w, const float* __restrict__ fc2b,
    float* __restrict__ out, int EP)
{
  int gw = (blockIdx.x * blockDim.x + threadIdx.x) >> 6;
  int lane = threadIdx.x & 63;
  int nw = (gridDim.x * blockDim.x) >> 6;
  float w0 = fc2w[2*lane], w1 = fc2w[2*lane + 1];
  float bb = fc2b[0];
  for (int p = gw*4; p < EP; p += nw*4) {
    float acc[4];
    #pragma unroll
    for (int k = 0; k < 4; k++) {
      int pp = (p + k < EP) ? (p + k) : (EP - 1);
      int s = ps[pp], d = pd[pp];
      unsigned av = *(const unsigned*)(ABp + (size_t)s*256 + 2*lane);
      unsigned bv = *(const unsigned*)(ABp + (size_t)d*256 + 128 + 2*lane);
      acc[k] = fmaxf(b2flo(av) + b2flo(bv), 0.f)*w0
             + fmaxf(b2fhi(av) + b2fhi(bv), 0.f)*w1;
    }
    #pragma unroll
    for (int off = 32; off > 0; off >>= 1) {
      #pragma unroll
      for (int k = 0; k < 4; k++) acc[k] += __shfl_down(acc[k], off);
    }
    if (lane == 0) {
      #pragma unroll
      for (int k = 0; k < 4; k++)
        if (p + k < EP) out[p + k] = 1.f / (1.f + __expf(-(acc[k] + bb)));
    }
  }
}

// ---------------------------------------------------------------------------
extern "C" void kernel_launch(void* const* d_in, const int* in_sizes, int n_in,
                              void* d_out, int out_size, void* d_ws, size_t ws_size,
                              hipStream_t stream)
{
  const float* features = (const float*)d_in[0];
  const int*   src      = (const int*)d_in[1];
  const int*   dst      = (const int*)d_in[2];
  const int*   psrc     = (const int*)d_in[3];
  const int*   pdst     = (const int*)d_in[4];
  const float* W1   = (const float*)d_in[5];
  const float* al1  = (const float*)d_in[6];
  const float* ar1  = (const float*)d_in[7];
  const float* b1   = (const float*)d_in[8];
  const float* W2   = (const float*)d_in[9];
  const float* al2  = (const float*)d_in[10];
  const float* ar2  = (const float*)d_in[11];
  const float* b2   = (const float*)d_in[12];
  const float* tw_qkv = (const float*)d_in[13];
  const float* tb_qkv = (const float*)d_in[14];
  const float* tw_o   = (const float*)d_in[15];
  const float* tb_o   = (const float*)d_in[16];
  const float* ln1_g  = (const float*)d_in[17];
  const float* ln1_b  = (const float*)d_in[18];
  const float* tw_ff1 = (const float*)d_in[19];
  const float* tb_ff1 = (const float*)d_in[20];
  const float* tw_ff2 = (const float*)d_in[21];
  const float* tb_ff2 = (const float*)d_in[22];
  const float* ln2_g  = (const float*)d_in[23];
  const float* ln2_b  = (const float*)d_in[24];
  const float* fc1_w  = (const float*)d_in[25];
  const float* fc1_b  = (const float*)d_in[26];
  const float* fc2_w  = (const float*)d_in[27];
  const float* fc2_b  = (const float*)d_in[28];
  int E  = in_sizes[1];
  int EP = in_sizes[3];

  float* ws = (float*)d_ws;
  size_t off = 0;
  auto alloc = [&](size_t n) { float* p = ws + off; off += n; return p; };
  ushort* hb    = (ushort*)alloc((size_t)NN * 64);    // [4096][128] bf16 state
  ushort* featb = (ushort*)alloc((size_t)NN * 128);   // [4096][256] bf16
  ushort* h1b   = (ushort*)alloc((size_t)NN * 256);   // [4096][512] bf16
  ushort* h2b   = (ushort*)alloc((size_t)NN * 256);   // [4096][512] bf16
  ushort* bigb  = (ushort*)alloc((size_t)NN * 256);   // [4096][512] bf16
  ushort* hgb   = (ushort*)alloc((size_t)NN * 64);    // [4096][128] bf16
  ushort* qb    = (ushort*)alloc((size_t)NN * 64);    // [4096][128] bf16
  ushort* attnb = (ushort*)alloc((size_t)NN * 64);    // [4096][128] bf16
  ushort* kt    = (ushort*)alloc((size_t)NN * 64);    // [4][256][16][32]
  ushort* vt    = (ushort*)alloc((size_t)NN * 64);    // [4][128][2][16][32]
  ushort* wbf   = (ushort*)alloc(622592/2);           // all weights bf16
  ushort* ABp   = (ushort*)alloc((size_t)NN * 128);   // [4096][256] bf16
  float*  bias256 = alloc(256);
  float*  el1   = alloc((size_t)NN * 4);
  float*  er1   = alloc((size_t)NN * 4);
  float*  el2   = alloc((size_t)NN);
  float*  er2   = alloc((size_t)NN);
  int* ibase    = (int*)(ws + off);
  int* deg      = ibase;
  int* rowstart = ibase + 4096;
  int* cursor   = rowstart + 4097;
  int* nbr      = cursor + 4096;

  // bf16 weight offsets
  const size_t oW1 = 0, oW2 = 131072, oQKV = 196608, oO = 294912,
               oFF1 = 327680, oFF2 = 458752, oFC1 = 589824;

  // zero deg, then one mega-dispatch: weight cvt + bias256 + feature cvt + edge count
  hipMemsetAsync(deg, 0, 4096 * sizeof(int), stream);
  cvt_all<<<1633 + 512, 256, 0, stream>>>(W1, W2, tw_qkv, tw_o, tw_ff1, tw_ff2,
                                          fc1_w, fc1_b, features, wbf, bias256,
                                          featb, dst, deg, E);
  scan_kernel<<<1, 1024, 0, stream>>>(deg, rowstart, cursor);
  fill_kernel<<<(E + 255)/256, 256, 0, stream>>>(src, dst, cursor, nbr, E);

  // GAT layer 1
  gemm_mf<false,false,true,true><<<dim3(8, 64), 256, 0, stream>>>(
      featb, wbf + oW1, nullptr, h1b, NN, 512, 256, 256);
  elr4_kernel<<<1024, 256, 0, stream>>>(h1b, al1, ar1, el1, er1);
  gat_agg4<<<1024, 256, 0, stream>>>(h1b, el1, er1, rowstart, nbr, b1, h2b);

  // GAT layer 2: full-width gemm + fused el/er epilogue
  gemm_hg_elr<<<256, 256, 0, stream>>>(h2b, wbf + oW2, al2, ar2, hgb, el2, er2);
  gat_agg1<<<1024, 256, 0, stream>>>(hgb, el2, er2, rowstart, nbr, b2, hb);

  // Transformer encoder (2 layers); final LN fused with decoder fc1 gemm
  for (int l = 0; l < 2; l++) {
    gemm_qkv<<<dim3(6, 64), 256, 0, stream>>>(
        hb, wbf + oQKV + (size_t)l*49152, tb_qkv + l*384, qb, kt, vt);
    attn_mfma<<<512, 512, 0, stream>>>(qb, kt, vt, attnb);
    gemm_ln<false><<<256, 256, 0, stream>>>(
        attnb, wbf + oO + (size_t)l*16384, tb_o + l*128, hb,
        ln1_g + l*128, ln1_b + l*128, 128, nullptr, nullptr, nullptr);
    gemm_mf<true,true,true,true><<<dim3(8, 64), 256, 0, stream>>>(
        hb, wbf + oFF1 + (size_t)l*65536, tb_ff1 + l*512, bigb, NN, 512, 128, 128);
    if (l == 0) {
      gemm_ln<false><<<256, 256, 0, stream>>>(
          bigb, wbf + oFF2 + (size_t)l*65536, tb_ff2 + l*128, hb,
          ln2_g + l*128, ln2_b + l*128, 512, nullptr, nullptr, nullptr);
    } else {
      gemm_ln<true><<<256, 256, 0, stream>>>(
          bigb, wbf + oFF2 + (size_t)l*65536, tb_ff2 + l*128, hb,
          ln2_g + l*128, ln2_b + l*128, 512, wbf + oFC1, bias256, ABp);
    }
  }

  // Decoder pairs
  pair_kernel<<<1024, 256, 0, stream>>>(ABp, psrc, pdst, fc2_w, fc2_b, (float*)d_out, EP);
}